// Round 3
// baseline (3709.153 us; speedup 1.0000x reference)
//
#include <hip/hip_runtime.h>
#include <cstdint>
#include <cstddef>

// ---------- helpers ----------
__device__ __forceinline__ float sigm(float x) { return 1.f / (1.f + __expf(-x)); }

// dims: D=512, H=8, DH=64, F=2048, K=31, L=512, N=16, M=8192

// ---------- LayerNorm over 512 (fp32), one wave per row ----------
__global__ void ln512_k(const float* __restrict__ x, const float* __restrict__ g,
                        const float* __restrict__ b, float* __restrict__ out) {
    int row = blockIdx.x;
    int lane = threadIdx.x;  // 64
    const float* xr = x + (size_t)row * 512 + lane * 8;
    float4 v0 = *(const float4*)(xr);
    float4 v1 = *(const float4*)(xr + 4);
    float va[8] = {v0.x, v0.y, v0.z, v0.w, v1.x, v1.y, v1.z, v1.w};
    float s = 0.f;
#pragma unroll
    for (int t = 0; t < 8; t++) s += va[t];
#pragma unroll
    for (int o = 32; o > 0; o >>= 1) s += __shfl_xor(s, o);
    float m = s * (1.0f / 512.0f);
    float q = 0.f;
#pragma unroll
    for (int t = 0; t < 8; t++) { float d = va[t] - m; q += d * d; }
#pragma unroll
    for (int o = 32; o > 0; o >>= 1) q += __shfl_xor(q, o);
    float inv = rsqrtf(q * (1.0f / 512.0f) + 1e-5f);
    int cb = lane * 8;
    float* o = out + (size_t)row * 512 + cb;
#pragma unroll
    for (int t = 0; t < 8; t++)
        o[t] = (va[t] - m) * inv * g[cb + t] + b[cb + t];
}

// ---------- GEMM: C(M,N) = act(A(M,K) * B(N,K)^T + bias); C = add + coef*C ----------
// fp32. Tiles 64x64x16, 256 thr, 4x4 per thread.
__global__ __launch_bounds__(256) void gemm_bt_k(
    const float* __restrict__ A, const float* __restrict__ B, const float* __restrict__ bias,
    const float* __restrict__ add, float* __restrict__ C,
    int M, int Nn, int Kk, float coef, int act) {
    __shared__ float As[16][64];
    __shared__ float Bs[16][64];
    int tid = threadIdx.x;
    int tx = tid & 15, ty = tid >> 4;
    int m0 = blockIdx.y << 6, n0 = blockIdx.x << 6;
    int arow = tid >> 2, acol = (tid & 3) << 2;
    float acc[4][4] = {};
    for (int k0 = 0; k0 < Kk; k0 += 16) {
        int gr = m0 + arow;
        float4 av = make_float4(0.f, 0.f, 0.f, 0.f);
        if (gr < M) av = *(const float4*)(A + (size_t)gr * Kk + k0 + acol);
        As[acol + 0][arow] = av.x; As[acol + 1][arow] = av.y;
        As[acol + 2][arow] = av.z; As[acol + 3][arow] = av.w;
        int gbr = n0 + arow;  // Nn always multiple of 64
        float4 bv = *(const float4*)(B + (size_t)gbr * Kk + k0 + acol);
        Bs[acol + 0][arow] = bv.x; Bs[acol + 1][arow] = bv.y;
        Bs[acol + 2][arow] = bv.z; Bs[acol + 3][arow] = bv.w;
        __syncthreads();
#pragma unroll
        for (int kk = 0; kk < 16; kk++) {
            float4 a4 = *(const float4*)&As[kk][ty << 2];
            float4 b4 = *(const float4*)&Bs[kk][tx << 2];
            float ar[4] = {a4.x, a4.y, a4.z, a4.w};
            float br[4] = {b4.x, b4.y, b4.z, b4.w};
#pragma unroll
            for (int i = 0; i < 4; i++)
#pragma unroll
                for (int j = 0; j < 4; j++) acc[i][j] += ar[i] * br[j];
        }
        __syncthreads();
    }
#pragma unroll
    for (int i = 0; i < 4; i++) {
        int gr = m0 + (ty << 2) + i;
        if (gr >= M) continue;
#pragma unroll
        for (int j = 0; j < 4; j++) {
            int gc = n0 + (tx << 2) + j;
            float c = acc[i][j];
            if (bias) c += bias[gc];
            if (act == 1) c *= sigm(c);  // swish
            size_t o = (size_t)gr * Nn + gc;
            if (add) c = add[o] + coef * c;
            C[o] = c;
        }
    }
}

// ---------- repack qkv chunk (2048 tokens) -> Q (N,H,L,DH), kT (N,H,DH,L), V ----------
__global__ void repack_k(const float* __restrict__ qkv, int t0, float* __restrict__ Q,
                         float* __restrict__ KT, float* __restrict__ V) {
    int e = blockIdx.x * 256 + threadIdx.x;  // 2048*512
    int c = e & 511, tl = e >> 9;
    int t = t0 + tl, l = t >> 4, n = t & 15, h = c >> 6, d = c & 63;
    size_t base = (size_t)tl * 1536 + c;
    float q = qkv[base], k = qkv[base + 512], v = qkv[base + 1024];
    int nh = n * 8 + h;
    Q[((size_t)nh * 512 + l) * 64 + d] = q;
    KT[((size_t)nh * 64 + d) * 512 + l] = k;
    V[((size_t)nh * 512 + l) * 64 + d] = v;
}

// ---------- transpose PB (1023,512) -> PT (512,1023) ----------
__global__ void transp_p_k(const float* __restrict__ pb, float* __restrict__ pT) {
    int idx = blockIdx.x * 256 + threadIdx.x;
    if (idx >= 1023 * 512) return;
    int m = idx >> 9, c = idx & 511;
    pT[(size_t)c * 1023 + m] = pb[idx];
}

// ---------- scores: sc[z,i,j] = 0.125*((q_i+bu).k_j + (q_i+bv).p_{511-i+j}) ----------
__global__ __launch_bounds__(256) void scores_k(
    const float* __restrict__ Q, const float* __restrict__ bu, const float* __restrict__ bv,
    const float* __restrict__ KT, const float* __restrict__ PT,
    float* __restrict__ sc, int nh_base) {
    int tid = threadIdx.x;
    int j = (blockIdx.x << 8) + tid;
    int i = blockIdx.y;
    int z = blockIdx.z;
    int nh = nh_base + z, h = nh & 7;
    __shared__ float squ[64], sqv[64];
    if (tid < 64) {
        float q = Q[((size_t)nh * 512 + i) * 64 + tid];
        squ[tid] = q + bu[h * 64 + tid];
        sqv[tid] = q + bv[h * 64 + tid];
    }
    __syncthreads();
    const float* kp = KT + ((size_t)nh << 6) * 512 + j;
    const float* pp = PT + ((size_t)h << 6) * 1023 + (511 - i + j);
    float a0 = 0.f, a1 = 0.f;
#pragma unroll 4
    for (int d = 0; d < 64; d++) {
        a0 += squ[d] * kp[(size_t)d * 512];
        a1 += sqv[d] * pp[(size_t)d * 1023];
    }
    sc[(((size_t)z << 9) + i) * 512 + j] = (a0 + a1) * 0.125f;
}

// ---------- softmax over 512, one wave per row, in place (fp32) ----------
__global__ void softmax512_k(float* __restrict__ sc) {
    int row = blockIdx.x, lane = threadIdx.x;
    float* p = sc + (size_t)row * 512;
    float4 v0 = *(const float4*)(p + lane * 8);
    float4 v1 = *(const float4*)(p + lane * 8 + 4);
    float va[8] = {v0.x, v0.y, v0.z, v0.w, v1.x, v1.y, v1.z, v1.w};
    float mx = va[0];
#pragma unroll
    for (int t = 1; t < 8; t++) mx = fmaxf(mx, va[t]);
#pragma unroll
    for (int o = 32; o > 0; o >>= 1) mx = fmaxf(mx, __shfl_xor(mx, o));
    float s = 0.f;
#pragma unroll
    for (int t = 0; t < 8; t++) { va[t] = __expf(va[t] - mx); s += va[t]; }
#pragma unroll
    for (int o = 32; o > 0; o >>= 1) s += __shfl_xor(s, o);
    float inv = 1.f / s;
    float* o = p + lane * 8;
#pragma unroll
    for (int t = 0; t < 8; t++) o[t] = va[t] * inv;
}

// ---------- AV: ctx[(l*16+n)*512 + h*64+d] = sum_j attn[i,j] * v[nh,j,d] ----------
__global__ __launch_bounds__(256) void av_k(const float* __restrict__ sc,
                                            const float* __restrict__ v,
                                            float* __restrict__ ctx, int nh_base) {
    int tid = threadIdx.x;
    int d = tid & 63, il = tid >> 6;
    int i0 = blockIdx.x << 2;
    int z = blockIdx.y;
    int nh = nh_base + z, n = nh >> 3, h = nh & 7;
    __shared__ float sat[4][512];
    for (int e = tid; e < 2048; e += 256)
        sat[e >> 9][e & 511] = sc[(((size_t)z << 9) + i0 + (e >> 9)) * 512 + (e & 511)];
    __syncthreads();
    const float* vp = v + ((size_t)nh << 9) * 64 + d;
    float acc = 0.f;
#pragma unroll 4
    for (int j = 0; j < 512; j++) acc += sat[il][j] * vp[(size_t)j * 64];
    int i = i0 + il;
    ctx[((size_t)i * 16 + n) * 512 + h * 64 + d] = acc;
}

// ---------- GLU on a 2048-token chunk: (2048,1024) -> full-buffer rows ----------
__global__ void glu_k(const float* __restrict__ pw1c, float* __restrict__ g, int t0) {
    int e = blockIdx.x * 256 + threadIdx.x;  // 2048*512
    int tl = e >> 9, c = e & 511;
    float a = pw1c[(size_t)tl * 1024 + c];
    float ga = pw1c[(size_t)tl * 1024 + 512 + c];
    g[((size_t)(t0 + tl)) * 512 + c] = a * sigm(ga);
}

// ---------- depthwise conv (K=31, pad 15) + bias + BN(eval) + swish ----------
__global__ void dwconv_k(const float* __restrict__ g, const float* __restrict__ w,
                         const float* __restrict__ wb, const float* __restrict__ bng,
                         const float* __restrict__ bnb, const float* __restrict__ bnm,
                         const float* __restrict__ bnv, float* __restrict__ out) {
    int idx = blockIdx.x * 256 + threadIdx.x;  // M*512
    int c = idx & 511, t = idx >> 9, l = t >> 4, n = t & 15;
    float acc = 0.f;
#pragma unroll
    for (int k = 0; k < 31; k++) {
        int ll = l + k - 15;
        if (ll >= 0 && ll < 512)
            acc += w[c * 31 + k] * g[(((size_t)ll * 16 + n) << 9) + c];
    }
    acc += wb[c];
    float y = (acc - bnm[c]) * rsqrtf(bnv[c] + 1e-5f) * bng[c] + bnb[c];
    y = y * sigm(y);
    out[idx] = y;
}

// ---------- launch ----------
extern "C" void kernel_launch(void* const* d_in, const int* in_sizes, int n_in,
                              void* d_out, int out_size, void* d_ws, size_t ws_size,
                              hipStream_t stream) {
    const float* src      = (const float*)d_in[0];
    const float* pos_emb  = (const float*)d_in[1];
    const float* ffm_w1   = (const float*)d_in[2];
    const float* ffm_b1   = (const float*)d_in[3];
    const float* ffm_w2   = (const float*)d_in[4];
    const float* ffm_b2   = (const float*)d_in[5];
    const float* ff_w1    = (const float*)d_in[6];
    const float* ff_b1    = (const float*)d_in[7];
    const float* ff_w2    = (const float*)d_in[8];
    const float* ff_b2    = (const float*)d_in[9];
    const float* in_w     = (const float*)d_in[10];
    const float* in_b     = (const float*)d_in[11];
    const float* out_w    = (const float*)d_in[12];
    const float* out_b    = (const float*)d_in[13];
    const float* pos_w    = (const float*)d_in[14];
    const float* bu       = (const float*)d_in[15];
    const float* bv       = (const float*)d_in[16];
    const float* pw1_w    = (const float*)d_in[17];
    const float* pw1_b    = (const float*)d_in[18];
    const float* dw_w     = (const float*)d_in[19];
    const float* dw_b     = (const float*)d_in[20];
    const float* bng      = (const float*)d_in[21];
    const float* bnb      = (const float*)d_in[22];
    const float* bnm      = (const float*)d_in[23];
    const float* bnv      = (const float*)d_in[24];
    const float* pw2_w    = (const float*)d_in[25];
    const float* pw2_b    = (const float*)d_in[26];
    const float* ln_ffm_g = (const float*)d_in[27];
    const float* ln_ffm_b = (const float*)d_in[28];
    const float* ln_mha_g = (const float*)d_in[29];
    const float* ln_mha_b = (const float*)d_in[30];
    const float* ln_cv_g  = (const float*)d_in[31];
    const float* ln_cv_b  = (const float*)d_in[32];
    const float* ln_ff_g  = (const float*)d_in[33];
    const float* ln_ff_b  = (const float*)d_in[34];
    const float* ln_fin_g = (const float*)d_in[35];
    const float* ln_fin_b = (const float*)d_in[36];
    (void)in_sizes; (void)n_in; (void)out_size; (void)ws_size;

    // workspace layout (fp32 elements); total ~30.4M floats = ~122 MB
    const size_t T = 4194304;  // M*512
    float* ws  = (float*)d_ws;
    float* xA  = ws;               // residual A
    float* xB  = ws + T;           // residual B
    float* LNB = ws + 2 * T;       // LN out; reused as attn ctx
    float* CH  = ws + 3 * T;       // 16 MiB chunk region (h1 / qkv / scores / pw1)
    float* Q   = ws + 4 * T;       // q (N,H,L,DH); conv: GLU buffer
    float* KT  = ws + 5 * T;       // kT (N,H,DH,L); conv: conv-activation buffer
    float* VV  = ws + 6 * T;       // v (N,H,L,DH)
    float* PB  = ws + 7 * T;       // pos@pos_w (1023,512)
    float* PT  = ws + 7 * T + 524288;  // (512,1023)
    float* CTX = LNB;
    float* GLU = Q;
    float* CACT = KT;

    // ---- FFN macaron: xB = src + 0.5*ffn(ln(src)) ----
    ln512_k<<<8192, 64, 0, stream>>>(src, ln_ffm_g, ln_ffm_b, LNB);
    for (int c = 0; c < 4; c++) {
        size_t off = (size_t)c * 2048 * 512;
        gemm_bt_k<<<dim3(32, 32), 256, 0, stream>>>(LNB + off, ffm_w1, ffm_b1, nullptr,
                                                    CH, 2048, 2048, 512, 0.f, 1);
        gemm_bt_k<<<dim3(8, 32), 256, 0, stream>>>(CH, ffm_w2, ffm_b2, src + off,
                                                   xB + off, 2048, 512, 2048, 0.5f, 0);
    }

    // ---- attention: xA = xB + attn(ln(xB)) ----
    ln512_k<<<8192, 64, 0, stream>>>(xB, ln_mha_g, ln_mha_b, LNB);
    gemm_bt_k<<<dim3(8, 16), 256, 0, stream>>>(pos_emb, pos_w, nullptr, nullptr,
                                               PB, 1023, 512, 512, 0.f, 0);
    transp_p_k<<<2046, 256, 0, stream>>>(PB, PT);
    for (int c = 0; c < 4; c++) {
        size_t off = (size_t)c * 2048 * 512;
        gemm_bt_k<<<dim3(24, 32), 256, 0, stream>>>(LNB + off, in_w, in_b, nullptr,
                                                    CH, 2048, 1536, 512, 0.f, 0);
        repack_k<<<4096, 256, 0, stream>>>(CH, c * 2048, Q, KT, VV);
    }
    for (int zc = 0; zc < 16; zc++) {  // 8 (n,h) pairs per chunk
        int nhb = zc * 8;
        scores_k<<<dim3(2, 512, 8), 256, 0, stream>>>(Q, bu, bv, KT, PT, CH, nhb);
        softmax512_k<<<4096, 64, 0, stream>>>(CH);
        av_k<<<dim3(128, 8), 256, 0, stream>>>(CH, VV, CTX, nhb);
    }
    gemm_bt_k<<<dim3(8, 128), 256, 0, stream>>>(CTX, out_w, out_b, xB, xA,
                                                8192, 512, 512, 1.f, 0);

    // ---- conv module: xB = xA + conv(ln(xA)) ----
    ln512_k<<<8192, 64, 0, stream>>>(xA, ln_cv_g, ln_cv_b, LNB);
    for (int c = 0; c < 4; c++) {
        size_t off = (size_t)c * 2048 * 512;
        gemm_bt_k<<<dim3(16, 32), 256, 0, stream>>>(LNB + off, pw1_w, pw1_b, nullptr,
                                                    CH, 2048, 1024, 512, 0.f, 0);
        glu_k<<<4096, 256, 0, stream>>>(CH, GLU, c * 2048);
    }
    dwconv_k<<<16384, 256, 0, stream>>>(GLU, dw_w, dw_b, bng, bnb, bnm, bnv, CACT);
    gemm_bt_k<<<dim3(8, 128), 256, 0, stream>>>(CACT, pw2_w, pw2_b, xA, xB,
                                                8192, 512, 512, 1.f, 0);

    // ---- FFN 2: xA = xB + 0.5*ffn(ln(xB)) ----
    ln512_k<<<8192, 64, 0, stream>>>(xB, ln_ff_g, ln_ff_b, LNB);
    for (int c = 0; c < 4; c++) {
        size_t off = (size_t)c * 2048 * 512;
        gemm_bt_k<<<dim3(32, 32), 256, 0, stream>>>(LNB + off, ff_w1, ff_b1, nullptr,
                                                    CH, 2048, 2048, 512, 0.f, 1);
        gemm_bt_k<<<dim3(8, 32), 256, 0, stream>>>(CH, ff_w2, ff_b2, xB + off,
                                                   xA + off, 2048, 512, 2048, 0.5f, 0);
    }

    // ---- final LN -> out ----
    ln512_k<<<8192, 64, 0, stream>>>(xA, ln_fin_g, ln_fin_b, (float*)d_out);
}

// Round 4
// 1991.801 us; speedup vs baseline: 1.8622x; 1.8622x over previous
//
#include <hip/hip_runtime.h>
#include <cstdint>
#include <cstddef>

typedef unsigned short u16;
typedef __attribute__((ext_vector_type(4))) float f32x4;
typedef __attribute__((ext_vector_type(8))) short bf16x8;

// ---------- helpers ----------
__device__ __forceinline__ float sigm(float x) { return 1.f / (1.f + __expf(-x)); }
__device__ __forceinline__ float bf2f(u16 u) {
    union { unsigned int i; float f; } c; c.i = ((unsigned int)u) << 16; return c.f;
}
__device__ __forceinline__ u16 f2bf(float f) {
    union { float f; unsigned int i; } c; c.f = f;
    unsigned int x = c.i;
    x += 0x7fffu + ((x >> 16) & 1u);
    return (u16)(x >> 16);
}

// dims: D=512, H=8, DH=64, F=2048, K=31, L=512, N=16, M=8192

// ---------- cast fp32 -> bf16 ----------
__global__ void castw_k(const float* __restrict__ in, u16* __restrict__ out, int n) {
    int i = blockIdx.x * 256 + threadIdx.x;
    if (i < n) out[i] = f2bf(in[i]);
}

// ---------- LayerNorm over 512 (fp32 in), one wave per row ----------
template <bool OUTBF>
__global__ void ln512_k(const float* __restrict__ x, const float* __restrict__ g,
                        const float* __restrict__ b, void* __restrict__ outv) {
    int row = blockIdx.x;
    int lane = threadIdx.x;  // 64
    const float* xr = x + (size_t)row * 512 + lane * 8;
    float4 v0 = *(const float4*)(xr);
    float4 v1 = *(const float4*)(xr + 4);
    float va[8] = {v0.x, v0.y, v0.z, v0.w, v1.x, v1.y, v1.z, v1.w};
    float s = 0.f;
#pragma unroll
    for (int t = 0; t < 8; t++) s += va[t];
#pragma unroll
    for (int o = 32; o > 0; o >>= 1) s += __shfl_xor(s, o);
    float m = s * (1.0f / 512.0f);
    float q = 0.f;
#pragma unroll
    for (int t = 0; t < 8; t++) { float d = va[t] - m; q += d * d; }
#pragma unroll
    for (int o = 32; o > 0; o >>= 1) q += __shfl_xor(q, o);
    float inv = rsqrtf(q * (1.0f / 512.0f) + 1e-5f);
    int cb = lane * 8;
    if (OUTBF) {
        u16* o = (u16*)outv + (size_t)row * 512 + cb;
#pragma unroll
        for (int t = 0; t < 8; t++)
            o[t] = f2bf((va[t] - m) * inv * g[cb + t] + b[cb + t]);
    } else {
        float* o = (float*)outv + (size_t)row * 512 + cb;
#pragma unroll
        for (int t = 0; t < 8; t++)
            o[t] = (va[t] - m) * inv * g[cb + t] + b[cb + t];
    }
}

// ---------- MFMA GEMM: C(M,N) = act(A(M,K)*B(N,K)^T + bias); C = add + coef*C ----------
// A,B bf16; bias/add fp32; out fp32 or bf16. 128x128 tile, BK=32, 4 waves (2x2 of 64x64).
// M%128==0, N%128==0, K%32==0.
__global__ __launch_bounds__(256) void mgemm_k(
    const u16* __restrict__ A, const u16* __restrict__ B, const float* __restrict__ bias,
    const float* __restrict__ add, void* __restrict__ Cv,
    int M, int Nn, int Kk, float coef, int act, int outbf) {
    __shared__ u16 lA[128 * 32];
    __shared__ u16 lB[128 * 32];
    int tid = threadIdx.x;
    int lane = tid & 63, w = tid >> 6;
    int wm = (w >> 1) * 64, wn = (w & 1) * 64;
    int m0 = blockIdx.y << 7, n0 = blockIdx.x << 7;

    f32x4 acc[4][4];
#pragma unroll
    for (int i = 0; i < 4; i++)
#pragma unroll
        for (int j = 0; j < 4; j++) acc[i][j] = (f32x4){0.f, 0.f, 0.f, 0.f};

    int srow = tid >> 2;          // 0..63
    int scol = (tid & 3) << 3;    // 0,8,16,24
    const u16* gA = A + (size_t)(m0 + srow) * Kk + scol;
    const u16* gB = B + (size_t)(n0 + srow) * Kk + scol;
    int lso = tid * 8;            // u16 elements; byte = tid*16

    int lra = wm * 32 + (lane & 15) * 32 + (lane >> 4) * 8;
    int lrb = wn * 32 + (lane & 15) * 32 + (lane >> 4) * 8;

    for (int k0 = 0; k0 < Kk; k0 += 32) {
        __builtin_amdgcn_global_load_lds(
            (const __attribute__((address_space(1))) void*)(gA + k0),
            (__attribute__((address_space(3))) void*)(lA + lso), 16, 0, 0);
        __builtin_amdgcn_global_load_lds(
            (const __attribute__((address_space(1))) void*)(gA + (size_t)64 * Kk + k0),
            (__attribute__((address_space(3))) void*)(lA + 2048 + lso), 16, 0, 0);
        __builtin_amdgcn_global_load_lds(
            (const __attribute__((address_space(1))) void*)(gB + k0),
            (__attribute__((address_space(3))) void*)(lB + lso), 16, 0, 0);
        __builtin_amdgcn_global_load_lds(
            (const __attribute__((address_space(1))) void*)(gB + (size_t)64 * Kk + k0),
            (__attribute__((address_space(3))) void*)(lB + 2048 + lso), 16, 0, 0);
        __syncthreads();
        bf16x8 af[4], bf[4];
#pragma unroll
        for (int t = 0; t < 4; t++) {
            af[t] = *(const bf16x8*)(lA + lra + t * 16 * 32);
            bf[t] = *(const bf16x8*)(lB + lrb + t * 16 * 32);
        }
#pragma unroll
        for (int i = 0; i < 4; i++)
#pragma unroll
            for (int j = 0; j < 4; j++)
                acc[i][j] = __builtin_amdgcn_mfma_f32_16x16x32_bf16(af[i], bf[j], acc[i][j], 0, 0, 0);
        __syncthreads();
    }

    // epilogue: D[m][n], m = wm+i*16+(lane>>4)*4+r, n = wn+j*16+(lane&15)
    int rbase = (lane >> 4) * 4;
    int ncol = lane & 15;
#pragma unroll
    for (int i = 0; i < 4; i++) {
#pragma unroll
        for (int j = 0; j < 4; j++) {
            int n = n0 + wn + j * 16 + ncol;
            float bv = bias ? bias[n] : 0.f;
#pragma unroll
            for (int r = 0; r < 4; r++) {
                int m = m0 + wm + i * 16 + rbase + r;
                float c = acc[i][j][r] + bv;
                if (act == 1) c *= sigm(c);
                size_t o = (size_t)m * Nn + n;
                if (add) c = add[o] + coef * c;
                if (outbf) ((u16*)Cv)[o] = f2bf(c);
                else ((float*)Cv)[o] = c;
            }
        }
    }
}

// ---------- fp32 GEMM (for pos projection, M=1023): C = A*B^T ----------
__global__ __launch_bounds__(256) void gemm_f32_k(
    const float* __restrict__ A, const float* __restrict__ B, float* __restrict__ C,
    int M, int Nn, int Kk) {
    __shared__ float As[16][64];
    __shared__ float Bs[16][64];
    int tid = threadIdx.x;
    int tx = tid & 15, ty = tid >> 4;
    int m0 = blockIdx.y << 6, n0 = blockIdx.x << 6;
    int arow = tid >> 2, acol = (tid & 3) << 2;
    float acc[4][4] = {};
    for (int k0 = 0; k0 < Kk; k0 += 16) {
        int gr = m0 + arow;
        float4 av = make_float4(0.f, 0.f, 0.f, 0.f);
        if (gr < M) av = *(const float4*)(A + (size_t)gr * Kk + k0 + acol);
        As[acol + 0][arow] = av.x; As[acol + 1][arow] = av.y;
        As[acol + 2][arow] = av.z; As[acol + 3][arow] = av.w;
        float4 bv = *(const float4*)(B + (size_t)(n0 + arow) * Kk + k0 + acol);
        Bs[acol + 0][arow] = bv.x; Bs[acol + 1][arow] = bv.y;
        Bs[acol + 2][arow] = bv.z; Bs[acol + 3][arow] = bv.w;
        __syncthreads();
#pragma unroll
        for (int kk = 0; kk < 16; kk++) {
            float4 a4 = *(const float4*)&As[kk][ty << 2];
            float4 b4 = *(const float4*)&Bs[kk][tx << 2];
            float ar[4] = {a4.x, a4.y, a4.z, a4.w};
            float br[4] = {b4.x, b4.y, b4.z, b4.w};
#pragma unroll
            for (int i = 0; i < 4; i++)
#pragma unroll
                for (int j = 0; j < 4; j++) acc[i][j] += ar[i] * br[j];
        }
        __syncthreads();
    }
#pragma unroll
    for (int i = 0; i < 4; i++) {
        int gr = m0 + (ty << 2) + i;
        if (gr >= M) continue;
#pragma unroll
        for (int j = 0; j < 4; j++)
            C[(size_t)gr * Nn + n0 + (tx << 2) + j] = acc[i][j];
    }
}

// ---------- repack qkv (M,1536) bf16 -> Q (N,H,L,DH), kT (N,H,DH,L), V bf16 ----------
__global__ void repack_k(const u16* __restrict__ qkv, u16* __restrict__ Q,
                         u16* __restrict__ KT, u16* __restrict__ V) {
    int e = blockIdx.x * 256 + threadIdx.x;  // M*512
    int c = e & 511, t = e >> 9;
    int l = t >> 4, n = t & 15, h = c >> 6, d = c & 63;
    size_t base = (size_t)t * 1536 + c;
    u16 q = qkv[base], k = qkv[base + 512], v = qkv[base + 1024];
    int nh = n * 8 + h;
    Q[((size_t)nh * 512 + l) * 64 + d] = q;
    KT[((size_t)nh * 64 + d) * 512 + l] = k;
    V[((size_t)nh * 512 + l) * 64 + d] = v;
}

// ---------- transpose PB (1023,512) -> PT (512,1023) fp32 ----------
__global__ void transp_p_k(const float* __restrict__ pb, float* __restrict__ pT) {
    int idx = blockIdx.x * 256 + threadIdx.x;
    if (idx >= 1023 * 512) return;
    int m = idx >> 9, c = idx & 511;
    pT[(size_t)c * 1023 + m] = pb[idx];
}

// ---------- scores: sc[z,i,j] = 0.125*((q_i+bu).k_j + (q_i+bv).p_{511-i+j}) ----------
__global__ __launch_bounds__(256) void scores_k(
    const u16* __restrict__ Q, const float* __restrict__ bu, const float* __restrict__ bv,
    const u16* __restrict__ KT, const float* __restrict__ PT,
    float* __restrict__ sc, int nh_base) {
    int tid = threadIdx.x;
    int j = (blockIdx.x << 8) + tid;
    int i = blockIdx.y;
    int z = blockIdx.z;
    int nh = nh_base + z, h = nh & 7;
    __shared__ float squ[64], sqv[64];
    if (tid < 64) {
        float q = bf2f(Q[((size_t)nh * 512 + i) * 64 + tid]);
        squ[tid] = q + bu[h * 64 + tid];
        sqv[tid] = q + bv[h * 64 + tid];
    }
    __syncthreads();
    const u16* kp = KT + ((size_t)nh << 6) * 512 + j;
    const float* pp = PT + ((size_t)h << 6) * 1023 + (511 - i + j);
    float a0 = 0.f, a1 = 0.f;
#pragma unroll 4
    for (int d = 0; d < 64; d++) {
        a0 += squ[d] * bf2f(kp[(size_t)d * 512]);
        a1 += sqv[d] * pp[(size_t)d * 1023];
    }
    sc[(((size_t)z << 9) + i) * 512 + j] = (a0 + a1) * 0.125f;
}

// ---------- softmax over 512, one wave per row, in place (fp32) ----------
__global__ void softmax512_k(float* __restrict__ sc) {
    int row = blockIdx.x, lane = threadIdx.x;
    float* p = sc + (size_t)row * 512;
    float4 v0 = *(const float4*)(p + lane * 8);
    float4 v1 = *(const float4*)(p + lane * 8 + 4);
    float va[8] = {v0.x, v0.y, v0.z, v0.w, v1.x, v1.y, v1.z, v1.w};
    float mx = va[0];
#pragma unroll
    for (int t = 1; t < 8; t++) mx = fmaxf(mx, va[t]);
#pragma unroll
    for (int o = 32; o > 0; o >>= 1) mx = fmaxf(mx, __shfl_xor(mx, o));
    float s = 0.f;
#pragma unroll
    for (int t = 0; t < 8; t++) { va[t] = __expf(va[t] - mx); s += va[t]; }
#pragma unroll
    for (int o = 32; o > 0; o >>= 1) s += __shfl_xor(s, o);
    float inv = 1.f / s;
    float* o = p + lane * 8;
#pragma unroll
    for (int t = 0; t < 8; t++) o[t] = va[t] * inv;
}

// ---------- AV: ctx[(l*16+n)*512 + h*64+d] = sum_j attn[i,j]*v[nh,j,d] -> bf16 ----------
__global__ __launch_bounds__(256) void av_k(const float* __restrict__ sc,
                                            const u16* __restrict__ v,
                                            u16* __restrict__ ctx, int nh_base) {
    int tid = threadIdx.x;
    int d = tid & 63, il = tid >> 6;
    int i0 = blockIdx.x << 2;
    int z = blockIdx.y;
    int nh = nh_base + z, n = nh >> 3, h = nh & 7;
    __shared__ float sat[4][512];
    for (int e = tid; e < 2048; e += 256)
        sat[e >> 9][e & 511] = sc[(((size_t)z << 9) + i0 + (e >> 9)) * 512 + (e & 511)];
    __syncthreads();
    const u16* vp = v + ((size_t)nh << 9) * 64 + d;
    float acc = 0.f;
#pragma unroll 4
    for (int j = 0; j < 512; j++) acc += sat[il][j] * bf2f(vp[(size_t)j * 64]);
    int i = i0 + il;
    ctx[((size_t)i * 16 + n) * 512 + h * 64 + d] = f2bf(acc);
}

// ---------- GLU: (M,1024) bf16 -> (M,512) bf16 ----------
__global__ void glu_k(const u16* __restrict__ pw1o, u16* __restrict__ g) {
    int e = blockIdx.x * 256 + threadIdx.x;  // M*512
    int t = e >> 9, c = e & 511;
    float a = bf2f(pw1o[(size_t)t * 1024 + c]);
    float ga = bf2f(pw1o[(size_t)t * 1024 + 512 + c]);
    g[e] = f2bf(a * sigm(ga));
}

// ---------- depthwise conv (K=31, pad 15) + bias + BN(eval) + swish, bf16 io ----------
__global__ void dwconv_k(const u16* __restrict__ g, const float* __restrict__ w,
                         const float* __restrict__ wb, const float* __restrict__ bng,
                         const float* __restrict__ bnb, const float* __restrict__ bnm,
                         const float* __restrict__ bnv, u16* __restrict__ out) {
    int idx = blockIdx.x * 256 + threadIdx.x;  // M*512
    int c = idx & 511, t = idx >> 9, l = t >> 4, n = t & 15;
    float acc = 0.f;
#pragma unroll
    for (int k = 0; k < 31; k++) {
        int ll = l + k - 15;
        if (ll >= 0 && ll < 512)
            acc += w[c * 31 + k] * bf2f(g[(((size_t)ll * 16 + n) << 9) + c]);
    }
    acc += wb[c];
    float y = (acc - bnm[c]) * rsqrtf(bnv[c] + 1e-5f) * bng[c] + bnb[c];
    y = y * sigm(y);
    out[idx] = f2bf(y);
}

// ---------- launch ----------
extern "C" void kernel_launch(void* const* d_in, const int* in_sizes, int n_in,
                              void* d_out, int out_size, void* d_ws, size_t ws_size,
                              hipStream_t stream) {
    const float* src      = (const float*)d_in[0];
    const float* pos_emb  = (const float*)d_in[1];
    const float* ffm_w1   = (const float*)d_in[2];
    const float* ffm_b1   = (const float*)d_in[3];
    const float* ffm_w2   = (const float*)d_in[4];
    const float* ffm_b2   = (const float*)d_in[5];
    const float* ff_w1    = (const float*)d_in[6];
    const float* ff_b1    = (const float*)d_in[7];
    const float* ff_w2    = (const float*)d_in[8];
    const float* ff_b2    = (const float*)d_in[9];
    const float* in_w     = (const float*)d_in[10];
    const float* in_b     = (const float*)d_in[11];
    const float* out_w    = (const float*)d_in[12];
    const float* out_b    = (const float*)d_in[13];
    const float* pos_w    = (const float*)d_in[14];
    const float* bu       = (const float*)d_in[15];
    const float* bv       = (const float*)d_in[16];
    const float* pw1_w    = (const float*)d_in[17];
    const float* pw1_b    = (const float*)d_in[18];
    const float* dw_w     = (const float*)d_in[19];
    const float* dw_b     = (const float*)d_in[20];
    const float* bng      = (const float*)d_in[21];
    const float* bnb      = (const float*)d_in[22];
    const float* bnm      = (const float*)d_in[23];
    const float* bnv      = (const float*)d_in[24];
    const float* pw2_w    = (const float*)d_in[25];
    const float* pw2_b    = (const float*)d_in[26];
    const float* ln_ffm_g = (const float*)d_in[27];
    const float* ln_ffm_b = (const float*)d_in[28];
    const float* ln_mha_g = (const float*)d_in[29];
    const float* ln_mha_b = (const float*)d_in[30];
    const float* ln_cv_g  = (const float*)d_in[31];
    const float* ln_cv_b  = (const float*)d_in[32];
    const float* ln_ff_g  = (const float*)d_in[33];
    const float* ln_ff_b  = (const float*)d_in[34];
    const float* ln_fin_g = (const float*)d_in[35];
    const float* ln_fin_b = (const float*)d_in[36];
    (void)in_sizes; (void)n_in; (void)out_size; (void)ws_size;

    // ---- workspace layout (~119.5 MiB) ----
    const size_t MEG = 1048576;
    float* wsf = (float*)d_ws;
    float* xA = wsf;                    // 4M floats
    float* xB = wsf + 4 * MEG;          // 4M floats
    float* PB = wsf + 8 * MEG;          // 1023*512
    float* PT = wsf + 8 * MEG + 524288; // 512*1023
    float* SC = wsf + 9 * MEG;          // 2M floats (8 nh x 512 x 512)
    u16* bfa = (u16*)(wsf + 11 * MEG);
    u16* LNB = bfa;                     // 4M u16 (M x 512)
    u16* BIG = bfa + 4 * MEG;           // 16M u16 (M x 2048 max)
    u16* Q   = bfa + 20 * MEG;          // 4M
    u16* KT  = bfa + 24 * MEG;          // 4M
    u16* VV  = bfa + 28 * MEG;          // 4M
    u16* WB  = bfa + 32 * MEG;          // weight bf16 arena (5.75M u16)
    u16* w_ffm1 = WB;                   // 2048*512 = 1M
    u16* w_ffm2 = WB + 1 * MEG;         // 512*2048 = 1M
    u16* w_ff1  = WB + 2 * MEG;
    u16* w_ff2  = WB + 3 * MEG;
    u16* w_in   = WB + 4 * MEG;                // 1536*512 = 768K
    u16* w_out  = WB + 4 * MEG + 786432;       // 512*512 = 256K
    u16* w_pw1  = WB + 5 * MEG + 0;            // 1024*512 = 512K  (4M+786432+262144 = 5M+0)
    u16* w_pw2  = WB + 5 * MEG + 524288;       // 512*512 = 256K
    u16* CTX = LNB;   // reuse after qkv GEMM consumed LNB
    u16* GLU = Q;     // reuse in conv phase
    u16* CACT = KT;   // reuse in conv phase

    // ---- cast weights to bf16 ----
    castw_k<<<4096, 256, 0, stream>>>(ffm_w1, w_ffm1, 1048576);
    castw_k<<<4096, 256, 0, stream>>>(ffm_w2, w_ffm2, 1048576);
    castw_k<<<4096, 256, 0, stream>>>(ff_w1, w_ff1, 1048576);
    castw_k<<<4096, 256, 0, stream>>>(ff_w2, w_ff2, 1048576);
    castw_k<<<3072, 256, 0, stream>>>(in_w, w_in, 786432);
    castw_k<<<1024, 256, 0, stream>>>(out_w, w_out, 262144);
    castw_k<<<2048, 256, 0, stream>>>(pw1_w, w_pw1, 524288);
    castw_k<<<1024, 256, 0, stream>>>(pw2_w, w_pw2, 262144);

    // ---- FFN macaron: xB = src + 0.5*ffn(ln(src)) ----
    ln512_k<true><<<8192, 64, 0, stream>>>(src, ln_ffm_g, ln_ffm_b, LNB);
    mgemm_k<<<dim3(16, 64), 256, 0, stream>>>(LNB, w_ffm1, ffm_b1, nullptr, BIG,
                                              8192, 2048, 512, 0.f, 1, 1);
    mgemm_k<<<dim3(4, 64), 256, 0, stream>>>(BIG, w_ffm2, ffm_b2, src, xB,
                                             8192, 512, 2048, 0.5f, 0, 0);

    // ---- attention: xA = xB + attn(ln(xB)) ----
    ln512_k<true><<<8192, 64, 0, stream>>>(xB, ln_mha_g, ln_mha_b, LNB);
    gemm_f32_k<<<dim3(8, 16), 256, 0, stream>>>(pos_emb, pos_w, PB, 1023, 512, 512);
    transp_p_k<<<2046, 256, 0, stream>>>(PB, PT);
    mgemm_k<<<dim3(12, 64), 256, 0, stream>>>(LNB, w_in, in_b, nullptr, BIG,
                                              8192, 1536, 512, 0.f, 0, 1);
    repack_k<<<16384, 256, 0, stream>>>(BIG, Q, KT, VV);
    for (int zc = 0; zc < 16; zc++) {
        int nhb = zc * 8;
        scores_k<<<dim3(2, 512, 8), 256, 0, stream>>>(Q, bu, bv, KT, PT, SC, nhb);
        softmax512_k<<<4096, 64, 0, stream>>>(SC);
        av_k<<<dim3(128, 8), 256, 0, stream>>>(SC, VV, CTX, nhb);
    }
    mgemm_k<<<dim3(4, 64), 256, 0, stream>>>(CTX, w_out, out_b, xB, xA,
                                             8192, 512, 512, 1.f, 0, 0);

    // ---- conv module: xB = xA + conv(ln(xA)) ----
    ln512_k<true><<<8192, 64, 0, stream>>>(xA, ln_cv_g, ln_cv_b, LNB);
    mgemm_k<<<dim3(8, 64), 256, 0, stream>>>(LNB, w_pw1, pw1_b, nullptr, BIG,
                                             8192, 1024, 512, 0.f, 0, 1);
    glu_k<<<16384, 256, 0, stream>>>(BIG, GLU);
    dwconv_k<<<16384, 256, 0, stream>>>(GLU, dw_w, dw_b, bng, bnb, bnm, bnv, CACT);
    mgemm_k<<<dim3(4, 64), 256, 0, stream>>>(CACT, w_pw2, pw2_b, xA, xB,
                                             8192, 512, 512, 1.f, 0, 0);

    // ---- FFN 2: xA = xB + 0.5*ffn(ln(xB)) ----
    ln512_k<true><<<8192, 64, 0, stream>>>(xB, ln_ff_g, ln_ff_b, LNB);
    mgemm_k<<<dim3(16, 64), 256, 0, stream>>>(LNB, w_ff1, ff_b1, nullptr, BIG,
                                              8192, 2048, 512, 0.f, 1, 1);
    mgemm_k<<<dim3(4, 64), 256, 0, stream>>>(BIG, w_ff2, ff_b2, xB, xA,
                                             8192, 512, 2048, 0.5f, 0, 0);

    // ---- final LN -> fp32 out ----
    ln512_k<false><<<8192, 64, 0, stream>>>(xA, ln_fin_g, ln_fin_b, (float*)d_out);
}

// Round 6
// 1001.146 us; speedup vs baseline: 3.7049x; 1.9895x over previous
//
#include <hip/hip_runtime.h>
#include <cstdint>
#include <cstddef>

typedef unsigned short u16;
typedef __attribute__((ext_vector_type(4))) float f32x4;
typedef __attribute__((ext_vector_type(8))) short bf16x8;

// ---------- helpers ----------
__device__ __forceinline__ float sigm(float x) { return 1.f / (1.f + __expf(-x)); }
__device__ __forceinline__ float bf2f(u16 u) {
    union { unsigned int i; float f; } c; c.i = ((unsigned int)u) << 16; return c.f;
}
__device__ __forceinline__ u16 f2bf(float f) {
    union { float f; unsigned int i; } c; c.f = f;
    unsigned int x = c.i;
    x += 0x7fffu + ((x >> 16) & 1u);
    return (u16)(x >> 16);
}
// fragment row helper: row t*16+(lane&15), k-offset (lane>>4)*8, row stride 32 (u16)
__device__ __forceinline__ int frag_off(int lane, int t) {
    return (t * 16 + (lane & 15)) * 32 + (lane >> 4) * 8;
}

// dims: D=512, H=8, DH=64, F=2048, K=31, L=512, N=16, M=8192

// ---------- cast fp32 -> bf16 ----------
__global__ void castw_k(const float* __restrict__ in, u16* __restrict__ out, int n) {
    int i = blockIdx.x * 256 + threadIdx.x;
    if (i < n) out[i] = f2bf(in[i]);
}

// ---------- LayerNorm over 512 (fp32 in), one wave per row ----------
template <bool OUTBF>
__global__ void ln512_k(const float* __restrict__ x, const float* __restrict__ g,
                        const float* __restrict__ b, void* __restrict__ outv) {
    int row = blockIdx.x;
    int lane = threadIdx.x;  // 64
    const float* xr = x + (size_t)row * 512 + lane * 8;
    float4 v0 = *(const float4*)(xr);
    float4 v1 = *(const float4*)(xr + 4);
    float va[8] = {v0.x, v0.y, v0.z, v0.w, v1.x, v1.y, v1.z, v1.w};
    float s = 0.f;
#pragma unroll
    for (int t = 0; t < 8; t++) s += va[t];
#pragma unroll
    for (int o = 32; o > 0; o >>= 1) s += __shfl_xor(s, o);
    float m = s * (1.0f / 512.0f);
    float q = 0.f;
#pragma unroll
    for (int t = 0; t < 8; t++) { float d = va[t] - m; q += d * d; }
#pragma unroll
    for (int o = 32; o > 0; o >>= 1) q += __shfl_xor(q, o);
    float inv = rsqrtf(q * (1.0f / 512.0f) + 1e-5f);
    int cb = lane * 8;
    if (OUTBF) {
        u16* o = (u16*)outv + (size_t)row * 512 + cb;
#pragma unroll
        for (int t = 0; t < 8; t++)
            o[t] = f2bf((va[t] - m) * inv * g[cb + t] + b[cb + t]);
    } else {
        float* o = (float*)outv + (size_t)row * 512 + cb;
#pragma unroll
        for (int t = 0; t < 8; t++)
            o[t] = (va[t] - m) * inv * g[cb + t] + b[cb + t];
    }
}

// ---------- MFMA GEMM: C(M,N) = act(A(M,K)*B(N,K)^T + bias); C = add + coef*C ----------
__global__ __launch_bounds__(256) void mgemm_k(
    const u16* __restrict__ A, const u16* __restrict__ B, const float* __restrict__ bias,
    const float* __restrict__ add, void* __restrict__ Cv,
    int M, int Nn, int Kk, float coef, int act, int outbf) {
    __shared__ u16 lA[128 * 32];
    __shared__ u16 lB[128 * 32];
    int tid = threadIdx.x;
    int lane = tid & 63, w = tid >> 6;
    int wm = (w >> 1) * 64, wn = (w & 1) * 64;
    int m0 = blockIdx.y << 7, n0 = blockIdx.x << 7;

    f32x4 acc[4][4];
#pragma unroll
    for (int i = 0; i < 4; i++)
#pragma unroll
        for (int j = 0; j < 4; j++) acc[i][j] = (f32x4){0.f, 0.f, 0.f, 0.f};

    int srow = tid >> 2;
    int scol = (tid & 3) << 3;
    const u16* gA = A + (size_t)(m0 + srow) * Kk + scol;
    const u16* gB = B + (size_t)(n0 + srow) * Kk + scol;
    int lso = tid * 8;

    int lra = wm * 32 + (lane & 15) * 32 + (lane >> 4) * 8;
    int lrb = wn * 32 + (lane & 15) * 32 + (lane >> 4) * 8;

    for (int k0 = 0; k0 < Kk; k0 += 32) {
        __builtin_amdgcn_global_load_lds(
            (const __attribute__((address_space(1))) void*)(gA + k0),
            (__attribute__((address_space(3))) void*)(lA + lso), 16, 0, 0);
        __builtin_amdgcn_global_load_lds(
            (const __attribute__((address_space(1))) void*)(gA + (size_t)64 * Kk + k0),
            (__attribute__((address_space(3))) void*)(lA + 2048 + lso), 16, 0, 0);
        __builtin_amdgcn_global_load_lds(
            (const __attribute__((address_space(1))) void*)(gB + k0),
            (__attribute__((address_space(3))) void*)(lB + lso), 16, 0, 0);
        __builtin_amdgcn_global_load_lds(
            (const __attribute__((address_space(1))) void*)(gB + (size_t)64 * Kk + k0),
            (__attribute__((address_space(3))) void*)(lB + 2048 + lso), 16, 0, 0);
        __syncthreads();
        bf16x8 af[4], bf[4];
#pragma unroll
        for (int t = 0; t < 4; t++) {
            af[t] = *(const bf16x8*)(lA + lra + t * 16 * 32);
            bf[t] = *(const bf16x8*)(lB + lrb + t * 16 * 32);
        }
#pragma unroll
        for (int i = 0; i < 4; i++)
#pragma unroll
            for (int j = 0; j < 4; j++)
                acc[i][j] = __builtin_amdgcn_mfma_f32_16x16x32_bf16(af[i], bf[j], acc[i][j], 0, 0, 0);
        __syncthreads();
    }

    int rbase = (lane >> 4) * 4;
    int ncol = lane & 15;
#pragma unroll
    for (int i = 0; i < 4; i++) {
#pragma unroll
        for (int j = 0; j < 4; j++) {
            int n = n0 + wn + j * 16 + ncol;
            float bv = bias ? bias[n] : 0.f;
#pragma unroll
            for (int r = 0; r < 4; r++) {
                int m = m0 + wm + i * 16 + rbase + r;
                float c = acc[i][j][r] + bv;
                if (act == 1) c *= sigm(c);
                size_t o = (size_t)m * Nn + n;
                if (add) c = add[o] + coef * c;
                if (outbf) ((u16*)Cv)[o] = f2bf(c);
                else ((float*)Cv)[o] = c;
            }
        }
    }
}

// ---------- batched MFMA scores GEMM. SHIFT=0: SC[z][m][n] = QU[nh].K[nh]^T ----------
// SHIFT=1: bd = QV[nh](512x64) . Pb[h](1024x64)^T; SC[z][i][m-511+i] += bd[i][m]
template <int SHIFT>
__global__ __launch_bounds__(256) void bscore_k(
    const u16* __restrict__ Abuf, const u16* __restrict__ Bbuf,
    float* __restrict__ SC, int nh_base) {
    __shared__ u16 lA[128 * 32];
    __shared__ u16 lB[128 * 32];
    int tid = threadIdx.x;
    int lane = tid & 63, w = tid >> 6;
    int wm = (w >> 1) * 64, wn = (w & 1) * 64;
    int m0 = blockIdx.y << 7, n0 = blockIdx.x << 7;
    int z = blockIdx.z;
    int nh = nh_base + z, h = nh & 7;
    const int Kk = 64;
    const u16* A = Abuf + ((size_t)nh << 15);  // nh*512*64
    const u16* B = SHIFT ? (Bbuf + ((size_t)h << 16))    // h*1024*64
                         : (Bbuf + ((size_t)nh << 15));
    float* SCz = SC + ((size_t)z << 18);  // z*512*512

    f32x4 acc[4][4];
#pragma unroll
    for (int i = 0; i < 4; i++)
#pragma unroll
        for (int j = 0; j < 4; j++) acc[i][j] = (f32x4){0.f, 0.f, 0.f, 0.f};

    int srow = tid >> 2;
    int scol = (tid & 3) << 3;
    const u16* gA = A + (size_t)(m0 + srow) * Kk + scol;
    const u16* gB = B + (size_t)(n0 + srow) * Kk + scol;
    int lso = tid * 8;
    int lra = wm * 32 + (lane & 15) * 32 + (lane >> 4) * 8;
    int lrb = wn * 32 + (lane & 15) * 32 + (lane >> 4) * 8;

    for (int k0 = 0; k0 < Kk; k0 += 32) {
        __builtin_amdgcn_global_load_lds(
            (const __attribute__((address_space(1))) void*)(gA + k0),
            (__attribute__((address_space(3))) void*)(lA + lso), 16, 0, 0);
        __builtin_amdgcn_global_load_lds(
            (const __attribute__((address_space(1))) void*)(gA + (size_t)64 * Kk + k0),
            (__attribute__((address_space(3))) void*)(lA + 2048 + lso), 16, 0, 0);
        __builtin_amdgcn_global_load_lds(
            (const __attribute__((address_space(1))) void*)(gB + k0),
            (__attribute__((address_space(3))) void*)(lB + lso), 16, 0, 0);
        __builtin_amdgcn_global_load_lds(
            (const __attribute__((address_space(1))) void*)(gB + (size_t)64 * Kk + k0),
            (__attribute__((address_space(3))) void*)(lB + 2048 + lso), 16, 0, 0);
        __syncthreads();
        bf16x8 af[4], bf[4];
#pragma unroll
        for (int t = 0; t < 4; t++) {
            af[t] = *(const bf16x8*)(lA + lra + t * 16 * 32);
            bf[t] = *(const bf16x8*)(lB + lrb + t * 16 * 32);
        }
#pragma unroll
        for (int i = 0; i < 4; i++)
#pragma unroll
            for (int j = 0; j < 4; j++)
                acc[i][j] = __builtin_amdgcn_mfma_f32_16x16x32_bf16(af[i], bf[j], acc[i][j], 0, 0, 0);
        __syncthreads();
    }

    int rbase = (lane >> 4) * 4;
    int ncol = lane & 15;
#pragma unroll
    for (int i = 0; i < 4; i++) {
#pragma unroll
        for (int j = 0; j < 4; j++) {
            int n = n0 + wn + j * 16 + ncol;
#pragma unroll
            for (int r = 0; r < 4; r++) {
                int m = m0 + wm + i * 16 + rbase + r;
                if (SHIFT) {
                    int jj = n - 511 + m;
                    if (jj >= 0 && jj < 512)
                        SCz[(size_t)m * 512 + jj] += acc[i][j][r];
                } else {
                    SCz[(size_t)m * 512 + n] = acc[i][j][r];
                }
            }
        }
    }
}

// ---------- softmax over 512 with 0.125 scale, fp32 in -> bf16 out ----------
__global__ void softmax512_k(const float* __restrict__ sc, u16* __restrict__ attn) {
    int row = blockIdx.x, lane = threadIdx.x;
    const float* p = sc + (size_t)row * 512;
    float4 v0 = *(const float4*)(p + lane * 8);
    float4 v1 = *(const float4*)(p + lane * 8 + 4);
    float va[8] = {v0.x, v0.y, v0.z, v0.w, v1.x, v1.y, v1.z, v1.w};
#pragma unroll
    for (int t = 0; t < 8; t++) va[t] *= 0.125f;
    float mx = va[0];
#pragma unroll
    for (int t = 1; t < 8; t++) mx = fmaxf(mx, va[t]);
#pragma unroll
    for (int o = 32; o > 0; o >>= 1) mx = fmaxf(mx, __shfl_xor(mx, o));
    float s = 0.f;
#pragma unroll
    for (int t = 0; t < 8; t++) { va[t] = __expf(va[t] - mx); s += va[t]; }
#pragma unroll
    for (int o = 32; o > 0; o >>= 1) s += __shfl_xor(s, o);
    float inv = 1.f / s;
    u16* o = attn + (size_t)row * 512 + lane * 8;
#pragma unroll
    for (int t = 0; t < 8; t++) o[t] = f2bf(va[t] * inv);
}

// ---------- batched MFMA AV: ctx rows = attn[z](512x512) . VT[nh](64x512)^T ----------
// one wave per 64x64 tile; grid (8, 16)
__global__ __launch_bounds__(64) void bav_k(const u16* __restrict__ ATTN,
                                            const u16* __restrict__ VT,
                                            u16* __restrict__ ctx, int nh_base) {
    __shared__ u16 lA[64 * 32];
    __shared__ u16 lB[64 * 32];
    int lane = threadIdx.x;
    int m0 = blockIdx.x << 6;
    int z = blockIdx.y;
    int nh = nh_base + z, n = nh >> 3, h = nh & 7;
    const u16* A = ATTN + ((size_t)z << 18) + (size_t)m0 * 512;  // rows m0..m0+63, stride 512
    const u16* B = VT + ((size_t)nh << 15);                      // 64 rows (d), stride 512

    f32x4 acc[4][4];
#pragma unroll
    for (int i = 0; i < 4; i++)
#pragma unroll
        for (int j = 0; j < 4; j++) acc[i][j] = (f32x4){0.f, 0.f, 0.f, 0.f};

    int srow = lane >> 2;        // 0..15
    int scol = (lane & 3) << 3;  // 0,8,16,24
    int lra = (lane & 15) * 32 + (lane >> 4) * 8;

    for (int k0 = 0; k0 < 512; k0 += 32) {
#pragma unroll
        for (int t = 0; t < 4; t++) {
            __builtin_amdgcn_global_load_lds(
                (const __attribute__((address_space(1))) void*)(A + (size_t)(t * 16 + srow) * 512 + k0 + scol),
                (__attribute__((address_space(3))) void*)(lA + t * 512 + lane * 8), 16, 0, 0);
            __builtin_amdgcn_global_load_lds(
                (const __attribute__((address_space(1))) void*)(B + (size_t)(t * 16 + srow) * 512 + k0 + scol),
                (__attribute__((address_space(3))) void*)(lB + t * 512 + lane * 8), 16, 0, 0);
        }
        __syncthreads();
        bf16x8 af[4], bf[4];
#pragma unroll
        for (int t = 0; t < 4; t++) {
            af[t] = *(const bf16x8*)(lA + lra + t * 16 * 32);
            bf[t] = *(const bf16x8*)(lB + frag_off(lane, t));
        }
#pragma unroll
        for (int i = 0; i < 4; i++)
#pragma unroll
            for (int j = 0; j < 4; j++)
                acc[i][j] = __builtin_amdgcn_mfma_f32_16x16x32_bf16(af[i], bf[j], acc[i][j], 0, 0, 0);
        __syncthreads();
    }

    int rbase = (lane >> 4) * 4;
    int ncol = lane & 15;
#pragma unroll
    for (int i = 0; i < 4; i++) {
#pragma unroll
        for (int j = 0; j < 4; j++) {
            int d = j * 16 + ncol;
#pragma unroll
            for (int r = 0; r < 4; r++) {
                int l = m0 + i * 16 + rbase + r;
                ctx[((size_t)(l * 16 + n)) * 512 + h * 64 + d] = f2bf(acc[i][j][r]);
            }
        }
    }
}

// ---------- fp32 GEMM (pos projection, M=1023): C = A*B^T ----------
__global__ __launch_bounds__(256) void gemm_f32_k(
    const float* __restrict__ A, const float* __restrict__ B, float* __restrict__ C,
    int M, int Nn, int Kk) {
    __shared__ float As[16][64];
    __shared__ float Bs[16][64];
    int tid = threadIdx.x;
    int tx = tid & 15, ty = tid >> 4;
    int m0 = blockIdx.y << 6, n0 = blockIdx.x << 6;
    int arow = tid >> 2, acol = (tid & 3) << 2;
    float acc[4][4] = {};
    for (int k0 = 0; k0 < Kk; k0 += 16) {
        int gr = m0 + arow;
        float4 av = make_float4(0.f, 0.f, 0.f, 0.f);
        if (gr < M) av = *(const float4*)(A + (size_t)gr * Kk + k0 + acol);
        As[acol + 0][arow] = av.x; As[acol + 1][arow] = av.y;
        As[acol + 2][arow] = av.z; As[acol + 3][arow] = av.w;
        float4 bv = *(const float4*)(B + (size_t)(n0 + arow) * Kk + k0 + acol);
        Bs[acol + 0][arow] = bv.x; Bs[acol + 1][arow] = bv.y;
        Bs[acol + 2][arow] = bv.z; Bs[acol + 3][arow] = bv.w;
        __syncthreads();
#pragma unroll
        for (int kk = 0; kk < 16; kk++) {
            float4 a4 = *(const float4*)&As[kk][ty << 2];
            float4 b4 = *(const float4*)&Bs[kk][tx << 2];
            float ar[4] = {a4.x, a4.y, a4.z, a4.w};
            float br[4] = {b4.x, b4.y, b4.z, b4.w};
#pragma unroll
            for (int i = 0; i < 4; i++)
#pragma unroll
                for (int j = 0; j < 4; j++) acc[i][j] += ar[i] * br[j];
        }
        __syncthreads();
    }
#pragma unroll
    for (int i = 0; i < 4; i++) {
        int gr = m0 + (ty << 2) + i;
        if (gr >= M) continue;
#pragma unroll
        for (int j = 0; j < 4; j++)
            C[(size_t)gr * Nn + n0 + (tx << 2) + j] = acc[i][j];
    }
}

// ---------- cast/reshape PB (1023,512) fp32 -> Pbf (h,1024,64) bf16 ----------
__global__ void pbcast_k(const float* __restrict__ pb, u16* __restrict__ pbbf) {
    int idx = blockIdx.x * 256 + threadIdx.x;
    if (idx >= 1023 * 512) return;
    int m = idx >> 9, c = idx & 511, h = c >> 6, d = c & 63;
    pbbf[((size_t)(h * 1024 + m) << 6) + d] = f2bf(pb[idx]);
}

// ---------- repack qkv (M,1536) bf16 -> QU/QV (nh,512,64)+bias, K (nh,512,64), VT (nh,64,512) ----------
__global__ void repack_k(const u16* __restrict__ qkv, const float* __restrict__ bu,
                         const float* __restrict__ bv, u16* __restrict__ QU,
                         u16* __restrict__ QV, u16* __restrict__ Kb, u16* __restrict__ VT) {
    int e = blockIdx.x * 256 + threadIdx.x;  // M*512
    int c = e & 511, t = e >> 9;
    int l = t >> 4, n = t & 15, h = c >> 6, d = c & 63;
    size_t base = (size_t)t * 1536 + c;
    float q = bf2f(qkv[base]);
    u16 k = qkv[base + 512], v = qkv[base + 1024];
    int nh = n * 8 + h;
    size_t o = ((size_t)nh * 512 + l) * 64 + d;
    QU[o] = f2bf(q + bu[h * 64 + d]);
    QV[o] = f2bf(q + bv[h * 64 + d]);
    Kb[o] = k;
    VT[((size_t)nh * 64 + d) * 512 + l] = v;
}

// ---------- GLU: (M,1024) bf16 -> (M,512) bf16 ----------
__global__ void glu_k(const u16* __restrict__ pw1o, u16* __restrict__ g) {
    int e = blockIdx.x * 256 + threadIdx.x;  // M*512
    int t = e >> 9, c = e & 511;
    float a = bf2f(pw1o[(size_t)t * 1024 + c]);
    float ga = bf2f(pw1o[(size_t)t * 1024 + 512 + c]);
    g[e] = f2bf(a * sigm(ga));
}

// ---------- depthwise conv: sliding window, 16 outputs per thread ----------
__global__ __launch_bounds__(256) void dwconv_k(
    const u16* __restrict__ g, const float* __restrict__ w, const float* __restrict__ wb,
    const float* __restrict__ bng, const float* __restrict__ bnb, const float* __restrict__ bnm,
    const float* __restrict__ bnv, u16* __restrict__ out) {
    int idx = blockIdx.x * 256 + threadIdx.x;  // 262144 threads
    int c = idx & 511;
    int t = idx >> 9;            // 0..511
    int n = t & 15, l0 = (t >> 4) << 4;
    float win[46];
#pragma unroll
    for (int q = 0; q < 46; q++) {
        int ll = l0 - 15 + q;
        win[q] = (ll >= 0 && ll < 512) ? bf2f(g[((size_t)(ll * 16 + n) << 9) + c]) : 0.f;
    }
    float wgt[31];
#pragma unroll
    for (int k = 0; k < 31; k++) wgt[k] = w[c * 31 + k];
    float ivg = rsqrtf(bnv[c] + 1e-5f) * bng[c];
    float mc = bnm[c], bc = bnb[c], wbc = wb[c];
#pragma unroll
    for (int r = 0; r < 16; r++) {
        float acc = 0.f;
#pragma unroll
        for (int k = 0; k < 31; k++) acc += wgt[k] * win[r + k];
        acc += wbc;
        float y = (acc - mc) * ivg + bc;
        y = y * sigm(y);
        out[((size_t)((l0 + r) * 16 + n) << 9) + c] = f2bf(y);
    }
}

// ---------- launch ----------
extern "C" void kernel_launch(void* const* d_in, const int* in_sizes, int n_in,
                              void* d_out, int out_size, void* d_ws, size_t ws_size,
                              hipStream_t stream) {
    const float* src      = (const float*)d_in[0];
    const float* pos_emb  = (const float*)d_in[1];
    const float* ffm_w1   = (const float*)d_in[2];
    const float* ffm_b1   = (const float*)d_in[3];
    const float* ffm_w2   = (const float*)d_in[4];
    const float* ffm_b2   = (const float*)d_in[5];
    const float* ff_w1    = (const float*)d_in[6];
    const float* ff_b1    = (const float*)d_in[7];
    const float* ff_w2    = (const float*)d_in[8];
    const float* ff_b2    = (const float*)d_in[9];
    const float* in_w     = (const float*)d_in[10];
    const float* in_b     = (const float*)d_in[11];
    const float* out_w    = (const float*)d_in[12];
    const float* out_b    = (const float*)d_in[13];
    const float* pos_w    = (const float*)d_in[14];
    const float* bu       = (const float*)d_in[15];
    const float* bv       = (const float*)d_in[16];
    const float* pw1_w    = (const float*)d_in[17];
    const float* pw1_b    = (const float*)d_in[18];
    const float* dw_w     = (const float*)d_in[19];
    const float* dw_b     = (const float*)d_in[20];
    const float* bng      = (const float*)d_in[21];
    const float* bnb      = (const float*)d_in[22];
    const float* bnm      = (const float*)d_in[23];
    const float* bnv      = (const float*)d_in[24];
    const float* pw2_w    = (const float*)d_in[25];
    const float* pw2_b    = (const float*)d_in[26];
    const float* ln_ffm_g = (const float*)d_in[27];
    const float* ln_ffm_b = (const float*)d_in[28];
    const float* ln_mha_g = (const float*)d_in[29];
    const float* ln_mha_b = (const float*)d_in[30];
    const float* ln_cv_g  = (const float*)d_in[31];
    const float* ln_cv_b  = (const float*)d_in[32];
    const float* ln_ff_g  = (const float*)d_in[33];
    const float* ln_ff_b  = (const float*)d_in[34];
    const float* ln_fin_g = (const float*)d_in[35];
    const float* ln_fin_b = (const float*)d_in[36];
    (void)in_sizes; (void)n_in; (void)out_size; (void)ws_size;

    // ---- workspace layout in u16 units; total 59.25M u16 = 118.5 MiB ----
    const size_t MEG = 1048576;
    u16* U = (u16*)d_ws;
    float* xA = (float*)U;                    // 8M u16
    float* xB = (float*)(U + 8 * MEG);        // 8M
    float* PB = (float*)(U + 16 * MEG);       // 1M u16 (1023*512 f)
    u16* LNB = U + 17 * MEG;                  // 4M
    u16* BIG = U + 21 * MEG;                  // 16M  (qkv 12M; SC 8M + ATTN 4M)
    u16* QU  = U + 37 * MEG;                  // 4M
    u16* QV  = U + 41 * MEG;                  // 4M
    u16* Kb  = U + 45 * MEG;                  // 4M
    u16* VT  = U + 49 * MEG;                  // 4M
    u16* Pbf = U + 53 * MEG;                  // 512K (8*1024*64)
    u16* WB  = U + 53 * MEG + 524288;         // 5.75M weights
    u16* w_ffm1 = WB;
    u16* w_ffm2 = WB + 1 * MEG;
    u16* w_ff1  = WB + 2 * MEG;
    u16* w_ff2  = WB + 3 * MEG;
    u16* w_in   = WB + 4 * MEG;
    u16* w_out  = WB + 4 * MEG + 786432;
    u16* w_pw1  = WB + 5 * MEG;
    u16* w_pw2  = WB + 5 * MEG + 524288;
    float* SC = (float*)BIG;                  // chunk: 16nh x 512 x 512 fp32
    u16* ATTN = BIG + 8 * MEG;                // chunk: 16nh x 512 x 512 bf16
    u16* CTX = LNB;
    u16* GLU = QU;
    u16* CACT = QV;

    // ---- cast weights to bf16 ----
    castw_k<<<4096, 256, 0, stream>>>(ffm_w1, w_ffm1, 1048576);
    castw_k<<<4096, 256, 0, stream>>>(ffm_w2, w_ffm2, 1048576);
    castw_k<<<4096, 256, 0, stream>>>(ff_w1, w_ff1, 1048576);
    castw_k<<<4096, 256, 0, stream>>>(ff_w2, w_ff2, 1048576);
    castw_k<<<3072, 256, 0, stream>>>(in_w, w_in, 786432);
    castw_k<<<1024, 256, 0, stream>>>(out_w, w_out, 262144);
    castw_k<<<2048, 256, 0, stream>>>(pw1_w, w_pw1, 524288);
    castw_k<<<1024, 256, 0, stream>>>(pw2_w, w_pw2, 262144);

    // ---- FFN macaron: xB = src + 0.5*ffn(ln(src)) ----
    ln512_k<true><<<8192, 64, 0, stream>>>(src, ln_ffm_g, ln_ffm_b, LNB);
    mgemm_k<<<dim3(16, 64), 256, 0, stream>>>(LNB, w_ffm1, ffm_b1, nullptr, BIG,
                                              8192, 2048, 512, 0.f, 1, 1);
    mgemm_k<<<dim3(4, 64), 256, 0, stream>>>(BIG, w_ffm2, ffm_b2, src, xB,
                                             8192, 512, 2048, 0.5f, 0, 0);

    // ---- attention: xA = xB + attn(ln(xB)) ----
    ln512_k<true><<<8192, 64, 0, stream>>>(xB, ln_mha_g, ln_mha_b, LNB);
    gemm_f32_k<<<dim3(8, 16), 256, 0, stream>>>(pos_emb, pos_w, PB, 1023, 512, 512);
    pbcast_k<<<2046, 256, 0, stream>>>(PB, Pbf);
    mgemm_k<<<dim3(12, 64), 256, 0, stream>>>(LNB, w_in, in_b, nullptr, BIG,
                                              8192, 1536, 512, 0.f, 0, 1);
    repack_k<<<16384, 256, 0, stream>>>(BIG, bu, bv, QU, QV, Kb, VT);
    for (int cc = 0; cc < 8; cc++) {
        int nhb = cc * 16;
        bscore_k<0><<<dim3(4, 4, 16), 256, 0, stream>>>(QU, Kb, SC, nhb);
        bscore_k<1><<<dim3(8, 4, 16), 256, 0, stream>>>(QV, Pbf, SC, nhb);
        softmax512_k<<<8192, 64, 0, stream>>>(SC, ATTN);
        bav_k<<<dim3(8, 16), 64, 0, stream>>>(ATTN, VT, CTX, nhb);
    }
    mgemm_k<<<dim3(4, 64), 256, 0, stream>>>(CTX, w_out, out_b, xB, xA,
                                             8192, 512, 512, 1.f, 0, 0);

    // ---- conv module: xB = xA + conv(ln(xA)) ----
    ln512_k<true><<<8192, 64, 0, stream>>>(xA, ln_cv_g, ln_cv_b, LNB);
    mgemm_k<<<dim3(8, 64), 256, 0, stream>>>(LNB, w_pw1, pw1_b, nullptr, BIG,
                                             8192, 1024, 512, 0.f, 0, 1);
    glu_k<<<16384, 256, 0, stream>>>(BIG, GLU);
    dwconv_k<<<1024, 256, 0, stream>>>(GLU, dw_w, dw_b, bng, bnb, bnm, bnv, CACT);
    mgemm_k<<<dim3(4, 64), 256, 0, stream>>>(CACT, w_pw2, pw2_b, xA, xB,
                                             8192, 512, 512, 1.f, 0, 0);

    // ---- FFN 2: xA = xB + 0.5*ffn(ln(xB)) ----
    ln512_k<true><<<8192, 64, 0, stream>>>(xB, ln_ff_g, ln_ff_b, LNB);
    mgemm_k<<<dim3(16, 64), 256, 0, stream>>>(LNB, w_ff1, ff_b1, nullptr, BIG,
                                              8192, 2048, 512, 0.f, 1, 1);
    mgemm_k<<<dim3(4, 64), 256, 0, stream>>>(BIG, w_ff2, ff_b2, xB, xA,
                                             8192, 512, 2048, 0.5f, 0, 0);

    // ---- final LN -> fp32 out ----
    ln512_k<false><<<8192, 64, 0, stream>>>(xA, ln_fin_g, ln_fin_b, (float*)d_out);
}

// Round 7
// 788.453 us; speedup vs baseline: 4.7043x; 1.2698x over previous
//
#include <hip/hip_runtime.h>
#include <cstdint>
#include <cstddef>

typedef unsigned short u16;
typedef __attribute__((ext_vector_type(4))) float f32x4;
typedef __attribute__((ext_vector_type(8))) short bf16x8;

// ---------- helpers ----------
__device__ __forceinline__ float sigm(float x) { return 1.f / (1.f + __expf(-x)); }
__device__ __forceinline__ float bf2f(u16 u) {
    union { unsigned int i; float f; } c; c.i = ((unsigned int)u) << 16; return c.f;
}
__device__ __forceinline__ u16 f2bf(float f) {
    union { float f; unsigned int i; } c; c.f = f;
    unsigned int x = c.i;
    x += 0x7fffu + ((x >> 16) & 1u);
    return (u16)(x >> 16);
}
// fragment row helper: row t*16+(lane&15), k-offset (lane>>4)*8, row stride 32 (u16)
__device__ __forceinline__ int frag_off(int lane, int t) {
    return (t * 16 + (lane & 15)) * 32 + (lane >> 4) * 8;
}

// dims: D=512, H=8, DH=64, F=2048, K=31, L=512, N=16, M=8192

// ---------- fused weight cast fp32 -> bf16 (all 8 weights, contiguous dst arena) ----------
__global__ void castall_k(const float* __restrict__ s0, const float* __restrict__ s1,
                          const float* __restrict__ s2, const float* __restrict__ s3,
                          const float* __restrict__ s4, const float* __restrict__ s5,
                          const float* __restrict__ s6, const float* __restrict__ s7,
                          u16* __restrict__ dst) {
    int i = blockIdx.x * 256 + threadIdx.x;
    if (i >= 6029312) return;
    const float* s; int off;
    if      (i < 1048576) { s = s0; off = 0; }
    else if (i < 2097152) { s = s1; off = 1048576; }
    else if (i < 3145728) { s = s2; off = 2097152; }
    else if (i < 4194304) { s = s3; off = 3145728; }
    else if (i < 4980736) { s = s4; off = 4194304; }
    else if (i < 5242880) { s = s5; off = 4980736; }
    else if (i < 5767168) { s = s6; off = 5242880; }
    else                  { s = s7; off = 5767168; }
    dst[i] = f2bf(s[i - off]);
}

// ---------- LayerNorm over 512 (fp32 in), one wave per row ----------
template <bool OUTBF>
__global__ void ln512_k(const float* __restrict__ x, const float* __restrict__ g,
                        const float* __restrict__ b, void* __restrict__ outv) {
    int row = blockIdx.x;
    int lane = threadIdx.x;  // 64
    const float* xr = x + (size_t)row * 512 + lane * 8;
    float4 v0 = *(const float4*)(xr);
    float4 v1 = *(const float4*)(xr + 4);
    float va[8] = {v0.x, v0.y, v0.z, v0.w, v1.x, v1.y, v1.z, v1.w};
    float s = 0.f;
#pragma unroll
    for (int t = 0; t < 8; t++) s += va[t];
#pragma unroll
    for (int o = 32; o > 0; o >>= 1) s += __shfl_xor(s, o);
    float m = s * (1.0f / 512.0f);
    float q = 0.f;
#pragma unroll
    for (int t = 0; t < 8; t++) { float d = va[t] - m; q += d * d; }
#pragma unroll
    for (int o = 32; o > 0; o >>= 1) q += __shfl_xor(q, o);
    float inv = rsqrtf(q * (1.0f / 512.0f) + 1e-5f);
    int cb = lane * 8;
    if (OUTBF) {
        u16* o = (u16*)outv + (size_t)row * 512 + cb;
#pragma unroll
        for (int t = 0; t < 8; t++)
            o[t] = f2bf((va[t] - m) * inv * g[cb + t] + b[cb + t]);
    } else {
        float* o = (float*)outv + (size_t)row * 512 + cb;
#pragma unroll
        for (int t = 0; t < 8; t++)
            o[t] = (va[t] - m) * inv * g[cb + t] + b[cb + t];
    }
}

// ---------- MFMA GEMM: C(M,N) = act(A(M,K)*B(N,K)^T + bias); C = add + coef*C ----------
__global__ __launch_bounds__(256) void mgemm_k(
    const u16* __restrict__ A, const u16* __restrict__ B, const float* __restrict__ bias,
    const float* __restrict__ add, void* __restrict__ Cv,
    int M, int Nn, int Kk, float coef, int act, int outbf) {
    __shared__ u16 lA[128 * 32];
    __shared__ u16 lB[128 * 32];
    int tid = threadIdx.x;
    int lane = tid & 63, w = tid >> 6;
    int wm = (w >> 1) * 64, wn = (w & 1) * 64;
    int m0 = blockIdx.y << 7, n0 = blockIdx.x << 7;

    f32x4 acc[4][4];
#pragma unroll
    for (int i = 0; i < 4; i++)
#pragma unroll
        for (int j = 0; j < 4; j++) acc[i][j] = (f32x4){0.f, 0.f, 0.f, 0.f};

    int srow = tid >> 2;
    int scol = (tid & 3) << 3;
    const u16* gA = A + (size_t)(m0 + srow) * Kk + scol;
    const u16* gB = B + (size_t)(n0 + srow) * Kk + scol;
    int lso = tid * 8;

    int lra = wm * 32 + (lane & 15) * 32 + (lane >> 4) * 8;
    int lrb = wn * 32 + (lane & 15) * 32 + (lane >> 4) * 8;

    for (int k0 = 0; k0 < Kk; k0 += 32) {
        __builtin_amdgcn_global_load_lds(
            (const __attribute__((address_space(1))) void*)(gA + k0),
            (__attribute__((address_space(3))) void*)(lA + lso), 16, 0, 0);
        __builtin_amdgcn_global_load_lds(
            (const __attribute__((address_space(1))) void*)(gA + (size_t)64 * Kk + k0),
            (__attribute__((address_space(3))) void*)(lA + 2048 + lso), 16, 0, 0);
        __builtin_amdgcn_global_load_lds(
            (const __attribute__((address_space(1))) void*)(gB + k0),
            (__attribute__((address_space(3))) void*)(lB + lso), 16, 0, 0);
        __builtin_amdgcn_global_load_lds(
            (const __attribute__((address_space(1))) void*)(gB + (size_t)64 * Kk + k0),
            (__attribute__((address_space(3))) void*)(lB + 2048 + lso), 16, 0, 0);
        __syncthreads();
        bf16x8 af[4], bf[4];
#pragma unroll
        for (int t = 0; t < 4; t++) {
            af[t] = *(const bf16x8*)(lA + lra + t * 16 * 32);
            bf[t] = *(const bf16x8*)(lB + lrb + t * 16 * 32);
        }
#pragma unroll
        for (int i = 0; i < 4; i++)
#pragma unroll
            for (int j = 0; j < 4; j++)
                acc[i][j] = __builtin_amdgcn_mfma_f32_16x16x32_bf16(af[i], bf[j], acc[i][j], 0, 0, 0);
        __syncthreads();
    }

    int rbase = (lane >> 4) * 4;
    int ncol = lane & 15;
#pragma unroll
    for (int i = 0; i < 4; i++) {
#pragma unroll
        for (int j = 0; j < 4; j++) {
            int n = n0 + wn + j * 16 + ncol;
            float bv = bias ? bias[n] : 0.f;
#pragma unroll
            for (int r = 0; r < 4; r++) {
                int m = m0 + wm + i * 16 + rbase + r;
                float c = acc[i][j][r] + bv;
                if (act == 1) c *= sigm(c);
                size_t o = (size_t)m * Nn + n;
                if (add) c = add[o] + coef * c;
                if (outbf) ((u16*)Cv)[o] = f2bf(c);
                else ((float*)Cv)[o] = c;
            }
        }
    }
}

// ---------- fused attention scores + softmax ----------
// block: 16 rows (m0..m0+15) x full 512 cols of SC for batch-head z.
// SC[m][j] = 0.125*(QU[m].K[j] + QV[m].P[j-m+511]); ATTN = softmax_j(SC) bf16.
__global__ __launch_bounds__(256) void acsm_k(
    const u16* __restrict__ QU, const u16* __restrict__ QV,
    const u16* __restrict__ Kb, const u16* __restrict__ Pbf,
    u16* __restrict__ ATTN, int nh_base) {
    __shared__ u16 sB[528 * 32];     // staging: P rows (528) or K rows (512), k-slice 32
    __shared__ u16 sRect[16 * 528];  // bd rect, bf16
    __shared__ u16 sQ[16 * 64];      // QV tile then QU tile
    __shared__ float sRed[16][4];    // cross-wave softmax partials
    int tid = threadIdx.x;
    int lane = tid & 63, w = tid >> 6;
    int quad = lane >> 4, col = lane & 15;
    int m0 = blockIdx.x << 4;   // 32 m-tiles
    int z = blockIdx.y;         // 64 per chunk
    int nh = nh_base + z, h = nh & 7;
    int nlo = 496 - m0;         // bd rect covers P rows [nlo, nlo+528)

    // ---- phase 1: bd rect = QV_tile(16x64) . P[nlo..+528)^T ----
    if (tid < 128)
        __builtin_amdgcn_global_load_lds(
            (const __attribute__((address_space(1))) void*)(QV + (((size_t)nh * 512 + m0 + (tid >> 3)) << 6) + ((tid & 7) << 3)),
            (__attribute__((address_space(3))) void*)(sQ + tid * 8), 16, 0, 0);
    f32x4 bdacc[9];
#pragma unroll
    for (int i = 0; i < 9; i++) bdacc[i] = (f32x4){0.f, 0.f, 0.f, 0.f};
    const u16* Pb = Pbf + ((size_t)h << 16);  // h*1024*64
    for (int ks = 0; ks < 2; ks++) {
#pragma unroll
        for (int s = 0; s < 8; s++) {
            int row = (s << 6) + (tid >> 2);
            __builtin_amdgcn_global_load_lds(
                (const __attribute__((address_space(1))) void*)(Pb + (((size_t)(nlo + row)) << 6) + (ks << 5) + ((tid & 3) << 3)),
                (__attribute__((address_space(3))) void*)(sB + (s << 11) + tid * 8), 16, 0, 0);
        }
        if (tid < 64) {
            int row = 512 + (tid >> 2);
            __builtin_amdgcn_global_load_lds(
                (const __attribute__((address_space(1))) void*)(Pb + (((size_t)(nlo + row)) << 6) + (ks << 5) + ((tid & 3) << 3)),
                (__attribute__((address_space(3))) void*)(sB + (8 << 11) + tid * 8), 16, 0, 0);
        }
        __syncthreads();
        bf16x8 a = *(const bf16x8*)(sQ + col * 64 + (ks << 5) + quad * 8);
        int idx = 0;
        for (int nt = w; nt < 33; nt += 4, idx++) {
            bf16x8 b = *(const bf16x8*)(sB + ((nt * 16 + col) << 5) + quad * 8);
            bdacc[idx] = __builtin_amdgcn_mfma_f32_16x16x32_bf16(a, b, bdacc[idx], 0, 0, 0);
        }
        __syncthreads();
    }
    {
        int idx = 0;
        for (int nt = w; nt < 33; nt += 4, idx++)
#pragma unroll
            for (int r = 0; r < 4; r++)
                sRect[(quad * 4 + r) * 528 + nt * 16 + col] = f2bf(bdacc[idx][r]);
    }
    __syncthreads();

    // ---- phase 2: ac = QU_tile(16x64) . K^T ----
    if (tid < 128)
        __builtin_amdgcn_global_load_lds(
            (const __attribute__((address_space(1))) void*)(QU + (((size_t)nh * 512 + m0 + (tid >> 3)) << 6) + ((tid & 7) << 3)),
            (__attribute__((address_space(3))) void*)(sQ + tid * 8), 16, 0, 0);
    f32x4 ac[8];
#pragma unroll
    for (int i = 0; i < 8; i++) ac[i] = (f32x4){0.f, 0.f, 0.f, 0.f};
    const u16* Kz = Kb + ((size_t)nh << 15);
    for (int ks = 0; ks < 2; ks++) {
#pragma unroll
        for (int s = 0; s < 8; s++) {
            int row = (s << 6) + (tid >> 2);
            __builtin_amdgcn_global_load_lds(
                (const __attribute__((address_space(1))) void*)(Kz + ((size_t)row << 6) + (ks << 5) + ((tid & 3) << 3)),
                (__attribute__((address_space(3))) void*)(sB + (s << 11) + tid * 8), 16, 0, 0);
        }
        __syncthreads();
        bf16x8 a = *(const bf16x8*)(sQ + col * 64 + (ks << 5) + quad * 8);
#pragma unroll
        for (int jt = 0; jt < 8; jt++) {
            bf16x8 b = *(const bf16x8*)(sB + (((w << 7) + jt * 16 + col) << 5) + quad * 8);
            ac[jt] = __builtin_amdgcn_mfma_f32_16x16x32_bf16(a, b, ac[jt], 0, 0, 0);
        }
        __syncthreads();
    }

    // ---- phase 3: add shifted bd, scale, softmax over j (full 512), write ATTN ----
    float rmax[4];
#pragma unroll
    for (int r = 0; r < 4; r++) rmax[r] = -1e30f;
#pragma unroll
    for (int jt = 0; jt < 8; jt++) {
        int j = (w << 7) + jt * 16 + col;
#pragma unroll
        for (int r = 0; r < 4; r++) {
            int ml = quad * 4 + r;
            float v = (ac[jt][r] + bf2f(sRect[ml * 528 + (j - ml + 15)])) * 0.125f;
            ac[jt][r] = v;
            rmax[r] = fmaxf(rmax[r], v);
        }
    }
#pragma unroll
    for (int o = 1; o <= 8; o <<= 1)
#pragma unroll
        for (int r = 0; r < 4; r++) rmax[r] = fmaxf(rmax[r], __shfl_xor(rmax[r], o));
    if (col == 0)
#pragma unroll
        for (int r = 0; r < 4; r++) sRed[quad * 4 + r][w] = rmax[r];
    __syncthreads();
    float gmax[4], psum[4];
#pragma unroll
    for (int r = 0; r < 4; r++) {
        int ml = quad * 4 + r;
        gmax[r] = fmaxf(fmaxf(sRed[ml][0], sRed[ml][1]), fmaxf(sRed[ml][2], sRed[ml][3]));
        psum[r] = 0.f;
    }
    __syncthreads();
#pragma unroll
    for (int jt = 0; jt < 8; jt++)
#pragma unroll
        for (int r = 0; r < 4; r++) {
            float e = __expf(ac[jt][r] - gmax[r]);
            ac[jt][r] = e;
            psum[r] += e;
        }
#pragma unroll
    for (int o = 1; o <= 8; o <<= 1)
#pragma unroll
        for (int r = 0; r < 4; r++) psum[r] += __shfl_xor(psum[r], o);
    if (col == 0)
#pragma unroll
        for (int r = 0; r < 4; r++) sRed[quad * 4 + r][w] = psum[r];
    __syncthreads();
    float rinv[4];
#pragma unroll
    for (int r = 0; r < 4; r++) {
        int ml = quad * 4 + r;
        rinv[r] = 1.f / (sRed[ml][0] + sRed[ml][1] + sRed[ml][2] + sRed[ml][3]);
    }
    u16* outp = ATTN + ((size_t)z * 512 + m0) * 512;
#pragma unroll
    for (int jt = 0; jt < 8; jt++) {
        int j = (w << 7) + jt * 16 + col;
#pragma unroll
        for (int r = 0; r < 4; r++)
            outp[(size_t)(quad * 4 + r) * 512 + j] = f2bf(ac[jt][r] * rinv[r]);
    }
}

// ---------- batched MFMA AV: ctx rows = attn[z](512x512) . VT[nh](64x512)^T ----------
__global__ __launch_bounds__(64) void bav_k(const u16* __restrict__ ATTN,
                                            const u16* __restrict__ VT,
                                            u16* __restrict__ ctx, int nh_base) {
    __shared__ u16 lA[64 * 32];
    __shared__ u16 lB[64 * 32];
    int lane = threadIdx.x;
    int m0 = blockIdx.x << 6;
    int z = blockIdx.y;
    int nh = nh_base + z, n = nh >> 3, h = nh & 7;
    const u16* A = ATTN + ((size_t)z << 18) + (size_t)m0 * 512;
    const u16* B = VT + ((size_t)nh << 15);

    f32x4 acc[4][4];
#pragma unroll
    for (int i = 0; i < 4; i++)
#pragma unroll
        for (int j = 0; j < 4; j++) acc[i][j] = (f32x4){0.f, 0.f, 0.f, 0.f};

    int srow = lane >> 2;
    int scol = (lane & 3) << 3;
    int lra = (lane & 15) * 32 + (lane >> 4) * 8;

    for (int k0 = 0; k0 < 512; k0 += 32) {
#pragma unroll
        for (int t = 0; t < 4; t++) {
            __builtin_amdgcn_global_load_lds(
                (const __attribute__((address_space(1))) void*)(A + (size_t)(t * 16 + srow) * 512 + k0 + scol),
                (__attribute__((address_space(3))) void*)(lA + t * 512 + lane * 8), 16, 0, 0);
            __builtin_amdgcn_global_load_lds(
                (const __attribute__((address_space(1))) void*)(B + (size_t)(t * 16 + srow) * 512 + k0 + scol),
                (__attribute__((address_space(3))) void*)(lB + t * 512 + lane * 8), 16, 0, 0);
        }
        __syncthreads();
        bf16x8 af[4], bf[4];
#pragma unroll
        for (int t = 0; t < 4; t++) {
            af[t] = *(const bf16x8*)(lA + lra + t * 16 * 32);
            bf[t] = *(const bf16x8*)(lB + frag_off(lane, t));
        }
#pragma unroll
        for (int i = 0; i < 4; i++)
#pragma unroll
            for (int j = 0; j < 4; j++)
                acc[i][j] = __builtin_amdgcn_mfma_f32_16x16x32_bf16(af[i], bf[j], acc[i][j], 0, 0, 0);
        __syncthreads();
    }

    int rbase = (lane >> 4) * 4;
    int ncol = lane & 15;
#pragma unroll
    for (int i = 0; i < 4; i++) {
#pragma unroll
        for (int j = 0; j < 4; j++) {
            int d = j * 16 + ncol;
#pragma unroll
            for (int r = 0; r < 4; r++) {
                int l = m0 + i * 16 + rbase + r;
                ctx[((size_t)(l * 16 + n)) * 512 + h * 64 + d] = f2bf(acc[i][j][r]);
            }
        }
    }
}

// ---------- fp32 GEMM (pos projection, M=1023): C = A*B^T ----------
__global__ __launch_bounds__(256) void gemm_f32_k(
    const float* __restrict__ A, const float* __restrict__ B, float* __restrict__ C,
    int M, int Nn, int Kk) {
    __shared__ float As[16][64];
    __shared__ float Bs[16][64];
    int tid = threadIdx.x;
    int tx = tid & 15, ty = tid >> 4;
    int m0 = blockIdx.y << 6, n0 = blockIdx.x << 6;
    int arow = tid >> 2, acol = (tid & 3) << 2;
    float acc[4][4] = {};
    for (int k0 = 0; k0 < Kk; k0 += 16) {
        int gr = m0 + arow;
        float4 av = make_float4(0.f, 0.f, 0.f, 0.f);
        if (gr < M) av = *(const float4*)(A + (size_t)gr * Kk + k0 + acol);
        As[acol + 0][arow] = av.x; As[acol + 1][arow] = av.y;
        As[acol + 2][arow] = av.z; As[acol + 3][arow] = av.w;
        float4 bv = *(const float4*)(B + (size_t)(n0 + arow) * Kk + k0 + acol);
        Bs[acol + 0][arow] = bv.x; Bs[acol + 1][arow] = bv.y;
        Bs[acol + 2][arow] = bv.z; Bs[acol + 3][arow] = bv.w;
        __syncthreads();
#pragma unroll
        for (int kk = 0; kk < 16; kk++) {
            float4 a4 = *(const float4*)&As[kk][ty << 2];
            float4 b4 = *(const float4*)&Bs[kk][tx << 2];
            float ar[4] = {a4.x, a4.y, a4.z, a4.w};
            float br[4] = {b4.x, b4.y, b4.z, b4.w};
#pragma unroll
            for (int i = 0; i < 4; i++)
#pragma unroll
                for (int j = 0; j < 4; j++) acc[i][j] += ar[i] * br[j];
        }
        __syncthreads();
    }
#pragma unroll
    for (int i = 0; i < 4; i++) {
        int gr = m0 + (ty << 2) + i;
        if (gr >= M) continue;
#pragma unroll
        for (int j = 0; j < 4; j++)
            C[(size_t)gr * Nn + n0 + (tx << 2) + j] = acc[i][j];
    }
}

// ---------- cast/reshape PB (1023,512) fp32 -> Pbf (h,1024,64) bf16 ----------
__global__ void pbcast_k(const float* __restrict__ pb, u16* __restrict__ pbbf) {
    int idx = blockIdx.x * 256 + threadIdx.x;
    if (idx >= 1023 * 512) return;
    int m = idx >> 9, c = idx & 511, h = c >> 6, d = c & 63;
    pbbf[((size_t)(h * 1024 + m) << 6) + d] = f2bf(pb[idx]);
}

// ---------- repack qkv (M,1536) bf16 -> QU/QV (nh,512,64)+bias, K (nh,512,64), VT (nh,64,512) ----------
__global__ void repack_k(const u16* __restrict__ qkv, const float* __restrict__ bu,
                         const float* __restrict__ bv, u16* __restrict__ QU,
                         u16* __restrict__ QV, u16* __restrict__ Kb, u16* __restrict__ VT) {
    int e = blockIdx.x * 256 + threadIdx.x;  // M*512
    int c = e & 511, t = e >> 9;
    int l = t >> 4, n = t & 15, h = c >> 6, d = c & 63;
    size_t base = (size_t)t * 1536 + c;
    float q = bf2f(qkv[base]);
    u16 k = qkv[base + 512], v = qkv[base + 1024];
    int nh = n * 8 + h;
    size_t o = ((size_t)nh * 512 + l) * 64 + d;
    QU[o] = f2bf(q + bu[h * 64 + d]);
    QV[o] = f2bf(q + bv[h * 64 + d]);
    Kb[o] = k;
    VT[((size_t)nh * 64 + d) * 512 + l] = v;
}

// ---------- GLU: (M,1024) bf16 -> (M,512) bf16 ----------
__global__ void glu_k(const u16* __restrict__ pw1o, u16* __restrict__ g) {
    int e = blockIdx.x * 256 + threadIdx.x;  // M*512
    int t = e >> 9, c = e & 511;
    float a = bf2f(pw1o[(size_t)t * 1024 + c]);
    float ga = bf2f(pw1o[(size_t)t * 1024 + 512 + c]);
    g[e] = f2bf(a * sigm(ga));
}

// ---------- depthwise conv: sliding window, 16 outputs per thread ----------
__global__ __launch_bounds__(256) void dwconv_k(
    const u16* __restrict__ g, const float* __restrict__ w, const float* __restrict__ wb,
    const float* __restrict__ bng, const float* __restrict__ bnb, const float* __restrict__ bnm,
    const float* __restrict__ bnv, u16* __restrict__ out) {
    int idx = blockIdx.x * 256 + threadIdx.x;  // 262144 threads
    int c = idx & 511;
    int t = idx >> 9;
    int n = t & 15, l0 = (t >> 4) << 4;
    float win[46];
#pragma unroll
    for (int q = 0; q < 46; q++) {
        int ll = l0 - 15 + q;
        win[q] = (ll >= 0 && ll < 512) ? bf2f(g[((size_t)(ll * 16 + n) << 9) + c]) : 0.f;
    }
    float wgt[31];
#pragma unroll
    for (int k = 0; k < 31; k++) wgt[k] = w[c * 31 + k];
    float ivg = rsqrtf(bnv[c] + 1e-5f) * bng[c];
    float mc = bnm[c], bc = bnb[c], wbc = wb[c];
#pragma unroll
    for (int r = 0; r < 16; r++) {
        float acc = 0.f;
#pragma unroll
        for (int k = 0; k < 31; k++) acc += wgt[k] * win[r + k];
        acc += wbc;
        float y = (acc - mc) * ivg + bc;
        y = y * sigm(y);
        out[((size_t)((l0 + r) * 16 + n) << 9) + c] = f2bf(y);
    }
}

// ---------- launch ----------
extern "C" void kernel_launch(void* const* d_in, const int* in_sizes, int n_in,
                              void* d_out, int out_size, void* d_ws, size_t ws_size,
                              hipStream_t stream) {
    const float* src      = (const float*)d_in[0];
    const float* pos_emb  = (const float*)d_in[1];
    const float* ffm_w1   = (const float*)d_in[2];
    const float* ffm_b1   = (const float*)d_in[3];
    const float* ffm_w2   = (const float*)d_in[4];
    const float* ffm_b2   = (const float*)d_in[5];
    const float* ff_w1    = (const float*)d_in[6];
    const float* ff_b1    = (const float*)d_in[7];
    const float* ff_w2    = (const float*)d_in[8];
    const float* ff_b2    = (const float*)d_in[9];
    const float* in_w     = (const float*)d_in[10];
    const float* in_b     = (const float*)d_in[11];
    const float* out_w    = (const float*)d_in[12];
    const float* out_b    = (const float*)d_in[13];
    const float* pos_w    = (const float*)d_in[14];
    const float* bu       = (const float*)d_in[15];
    const float* bv       = (const float*)d_in[16];
    const float* pw1_w    = (const float*)d_in[17];
    const float* pw1_b    = (const float*)d_in[18];
    const float* dw_w     = (const float*)d_in[19];
    const float* dw_b     = (const float*)d_in[20];
    const float* bng      = (const float*)d_in[21];
    const float* bnb      = (const float*)d_in[22];
    const float* bnm      = (const float*)d_in[23];
    const float* bnv      = (const float*)d_in[24];
    const float* pw2_w    = (const float*)d_in[25];
    const float* pw2_b    = (const float*)d_in[26];
    const float* ln_ffm_g = (const float*)d_in[27];
    const float* ln_ffm_b = (const float*)d_in[28];
    const float* ln_mha_g = (const float*)d_in[29];
    const float* ln_mha_b = (const float*)d_in[30];
    const float* ln_cv_g  = (const float*)d_in[31];
    const float* ln_cv_b  = (const float*)d_in[32];
    const float* ln_ff_g  = (const float*)d_in[33];
    const float* ln_ff_b  = (const float*)d_in[34];
    const float* ln_fin_g = (const float*)d_in[35];
    const float* ln_fin_b = (const float*)d_in[36];
    (void)in_sizes; (void)n_in; (void)out_size; (void)ws_size;

    // ---- workspace layout in u16 units; total 60,555,264 u16 = 115.5 MiB ----
    const size_t MEG = 1048576;
    u16* U = (u16*)d_ws;
    float* xA = (float*)U;                // 8M u16; Pbf aliases during attention
    u16* Pbf = U;                         // 524288 u16 (8 x 1024 x 64); dead before xA written
    float* xB = (float*)(U + 8 * MEG);    // 8M
    u16* LNB = U + 16 * MEG;              // 4M
    u16* BIG = U + 20 * MEG;              // 16M: h1 / PB / qkv / ATTN / pw1-out
    float* PB = (float*)BIG;              // 1023*512 fp32 (pre-qkv)
    u16* QU = U + 36 * MEG;               // 4M
    u16* QV = U + 40 * MEG;               // 4M
    u16* Kb = U + 44 * MEG;               // 4M
    u16* VT = U + 48 * MEG;               // 4M
    u16* WB = U + 52 * MEG;               // 6,029,312 weights bf16 (contiguous arena)
    u16* w_ffm1 = WB;
    u16* w_ffm2 = WB + 1 * MEG;
    u16* w_ff1  = WB + 2 * MEG;
    u16* w_ff2  = WB + 3 * MEG;
    u16* w_in   = WB + 4 * MEG;
    u16* w_out  = WB + 4 * MEG + 786432;
    u16* w_pw1  = WB + 5 * MEG;
    u16* w_pw2  = WB + 5 * MEG + 524288;
    u16* ATTN = BIG;                      // 64 z x 512 x 512 bf16 = 16M u16 exactly
    u16* CTX = LNB;
    u16* GLU = QU;
    u16* CACT = QV;

    // ---- cast all weights to bf16 (one dispatch) ----
    castall_k<<<23552, 256, 0, stream>>>(ffm_w1, ffm_w2, ff_w1, ff_w2, in_w, out_w,
                                         pw1_w, pw2_w, WB);

    // ---- FFN macaron: xB = src + 0.5*ffn(ln(src)) ----
    ln512_k<true><<<8192, 64, 0, stream>>>(src, ln_ffm_g, ln_ffm_b, LNB);
    mgemm_k<<<dim3(16, 64), 256, 0, stream>>>(LNB, w_ffm1, ffm_b1, nullptr, BIG,
                                              8192, 2048, 512, 0.f, 1, 1);
    mgemm_k<<<dim3(4, 64), 256, 0, stream>>>(BIG, w_ffm2, ffm_b2, src, xB,
                                             8192, 512, 2048, 0.5f, 0, 0);

    // ---- attention: xA = xB + attn(ln(xB)) ----
    ln512_k<true><<<8192, 64, 0, stream>>>(xB, ln_mha_g, ln_mha_b, LNB);
    gemm_f32_k<<<dim3(8, 16), 256, 0, stream>>>(pos_emb, pos_w, PB, 1023, 512, 512);
    pbcast_k<<<2046, 256, 0, stream>>>(PB, Pbf);
    mgemm_k<<<dim3(12, 64), 256, 0, stream>>>(LNB, w_in, in_b, nullptr, BIG,
                                              8192, 1536, 512, 0.f, 0, 1);
    repack_k<<<16384, 256, 0, stream>>>(BIG, bu, bv, QU, QV, Kb, VT);
    for (int cc = 0; cc < 2; cc++) {
        int nhb = cc * 64;
        acsm_k<<<dim3(32, 64), 256, 0, stream>>>(QU, QV, Kb, Pbf, ATTN, nhb);
        bav_k<<<dim3(8, 64), 64, 0, stream>>>(ATTN, VT, CTX, nhb);
    }
    mgemm_k<<<dim3(4, 64), 256, 0, stream>>>(CTX, w_out, out_b, xB, xA,
                                             8192, 512, 512, 1.f, 0, 0);

    // ---- conv module: xB = xA + conv(ln(xA)) ----
    ln512_k<true><<<8192, 64, 0, stream>>>(xA, ln_cv_g, ln_cv_b, LNB);
    mgemm_k<<<dim3(8, 64), 256, 0, stream>>>(LNB, w_pw1, pw1_b, nullptr, BIG,
                                             8192, 1024, 512, 0.f, 0, 1);
    glu_k<<<16384, 256, 0, stream>>>(BIG, GLU);
    dwconv_k<<<1024, 256, 0, stream>>>(GLU, dw_w, dw_b, bng, bnb, bnm, bnv, CACT);
    mgemm_k<<<dim3(4, 64), 256, 0, stream>>>(CACT, w_pw2, pw2_b, xA, xB,
                                             8192, 512, 512, 1.f, 0, 0);

    // ---- FFN 2: xA = xB + 0.5*ffn(ln(xB)) ----
    ln512_k<true><<<8192, 64, 0, stream>>>(xB, ln_ff_g, ln_ff_b, LNB);
    mgemm_k<<<dim3(16, 64), 256, 0, stream>>>(LNB, w_ff1, ff_b1, nullptr, BIG,
                                              8192, 2048, 512, 0.f, 1, 1);
    mgemm_k<<<dim3(4, 64), 256, 0, stream>>>(BIG, w_ff2, ff_b2, xB, xA,
                                             8192, 512, 2048, 0.5f, 0, 0);

    // ---- final LN -> fp32 out ----
    ln512_k<false><<<8192, 64, 0, stream>>>(xA, ln_fin_g, ln_fin_b, (float*)d_out);
}

// Round 8
// 763.027 us; speedup vs baseline: 4.8611x; 1.0333x over previous
//
#include <hip/hip_runtime.h>
#include <cstdint>
#include <cstddef>

typedef unsigned short u16;
typedef __attribute__((ext_vector_type(4))) float f32x4;
typedef __attribute__((ext_vector_type(8))) short bf16x8;

// ---------- helpers ----------
__device__ __forceinline__ float sigm(float x) { return 1.f / (1.f + __expf(-x)); }
__device__ __forceinline__ float bf2f(u16 u) {
    union { unsigned int i; float f; } c; c.i = ((unsigned int)u) << 16; return c.f;
}
__device__ __forceinline__ u16 f2bf(float f) {
    union { float f; unsigned int i; } c; c.f = f;
    unsigned int x = c.i;
    x += 0x7fffu + ((x >> 16) & 1u);
    return (u16)(x >> 16);
}

// dims: D=512, H=8, DH=64, F=2048, K=31, L=512, N=16, M=8192

// ---------- fused weight cast fp32 -> bf16 ----------
__global__ void castall_k(const float* __restrict__ s0, const float* __restrict__ s1,
                          const float* __restrict__ s2, const float* __restrict__ s3,
                          const float* __restrict__ s4, const float* __restrict__ s5,
                          const float* __restrict__ s6, const float* __restrict__ s7,
                          u16* __restrict__ dst) {
    int i = blockIdx.x * 256 + threadIdx.x;
    if (i >= 6029312) return;
    const float* s; int off;
    if      (i < 1048576) { s = s0; off = 0; }
    else if (i < 2097152) { s = s1; off = 1048576; }
    else if (i < 3145728) { s = s2; off = 2097152; }
    else if (i < 4194304) { s = s3; off = 3145728; }
    else if (i < 4980736) { s = s4; off = 4194304; }
    else if (i < 5242880) { s = s5; off = 4980736; }
    else if (i < 5767168) { s = s6; off = 5242880; }
    else                  { s = s7; off = 5767168; }
    dst[i] = f2bf(s[i - off]);
}

// ---------- LayerNorm over 512 (fp32 in), one wave per row ----------
template <bool OUTBF>
__global__ void ln512_k(const float* __restrict__ x, const float* __restrict__ g,
                        const float* __restrict__ b, void* __restrict__ outv) {
    int row = blockIdx.x;
    int lane = threadIdx.x;  // 64
    const float* xr = x + (size_t)row * 512 + lane * 8;
    float4 v0 = *(const float4*)(xr);
    float4 v1 = *(const float4*)(xr + 4);
    float va[8] = {v0.x, v0.y, v0.z, v0.w, v1.x, v1.y, v1.z, v1.w};
    float s = 0.f;
#pragma unroll
    for (int t = 0; t < 8; t++) s += va[t];
#pragma unroll
    for (int o = 32; o > 0; o >>= 1) s += __shfl_xor(s, o);
    float m = s * (1.0f / 512.0f);
    float q = 0.f;
#pragma unroll
    for (int t = 0; t < 8; t++) { float d = va[t] - m; q += d * d; }
#pragma unroll
    for (int o = 32; o > 0; o >>= 1) q += __shfl_xor(q, o);
    float inv = rsqrtf(q * (1.0f / 512.0f) + 1e-5f);
    int cb = lane * 8;
    if (OUTBF) {
        u16* o = (u16*)outv + (size_t)row * 512 + cb;
#pragma unroll
        for (int t = 0; t < 8; t++)
            o[t] = f2bf((va[t] - m) * inv * g[cb + t] + b[cb + t]);
    } else {
        float* o = (float*)outv + (size_t)row * 512 + cb;
#pragma unroll
        for (int t = 0; t < 8; t++)
            o[t] = (va[t] - m) * inv * g[cb + t] + b[cb + t];
    }
}

// ---------- MFMA GEMM: C(M,N) = act(A(M,K)*B(N,K)^T + bias); C = add + coef*C ----------
// grid: (M/128, N/128) — x = m-tile so same-A blocks share an XCD (linear%8 fixed).
__global__ __launch_bounds__(256) void mgemm_k(
    const u16* __restrict__ A, const u16* __restrict__ B, const float* __restrict__ bias,
    const float* __restrict__ add, void* __restrict__ Cv,
    int M, int Nn, int Kk, float coef, int act, int outbf) {
    __shared__ u16 lA[128 * 32];
    __shared__ u16 lB[128 * 32];
    int tid = threadIdx.x;
    int lane = tid & 63, w = tid >> 6;
    int wm = (w >> 1) * 64, wn = (w & 1) * 64;
    int m0 = blockIdx.x << 7, n0 = blockIdx.y << 7;

    f32x4 acc[4][4];
#pragma unroll
    for (int i = 0; i < 4; i++)
#pragma unroll
        for (int j = 0; j < 4; j++) acc[i][j] = (f32x4){0.f, 0.f, 0.f, 0.f};

    int srow = tid >> 2;
    int scol = (tid & 3) << 3;
    const u16* gA = A + (size_t)(m0 + srow) * Kk + scol;
    const u16* gB = B + (size_t)(n0 + srow) * Kk + scol;
    int lso = tid * 8;

    int lra = wm * 32 + (lane & 15) * 32 + (lane >> 4) * 8;
    int lrb = wn * 32 + (lane & 15) * 32 + (lane >> 4) * 8;

    for (int k0 = 0; k0 < Kk; k0 += 32) {
        __builtin_amdgcn_global_load_lds(
            (const __attribute__((address_space(1))) void*)(gA + k0),
            (__attribute__((address_space(3))) void*)(lA + lso), 16, 0, 0);
        __builtin_amdgcn_global_load_lds(
            (const __attribute__((address_space(1))) void*)(gA + (size_t)64 * Kk + k0),
            (__attribute__((address_space(3))) void*)(lA + 2048 + lso), 16, 0, 0);
        __builtin_amdgcn_global_load_lds(
            (const __attribute__((address_space(1))) void*)(gB + k0),
            (__attribute__((address_space(3))) void*)(lB + lso), 16, 0, 0);
        __builtin_amdgcn_global_load_lds(
            (const __attribute__((address_space(1))) void*)(gB + (size_t)64 * Kk + k0),
            (__attribute__((address_space(3))) void*)(lB + 2048 + lso), 16, 0, 0);
        __syncthreads();
        bf16x8 af[4], bf[4];
#pragma unroll
        for (int t = 0; t < 4; t++) {
            af[t] = *(const bf16x8*)(lA + lra + t * 16 * 32);
            bf[t] = *(const bf16x8*)(lB + lrb + t * 16 * 32);
        }
#pragma unroll
        for (int i = 0; i < 4; i++)
#pragma unroll
            for (int j = 0; j < 4; j++)
                acc[i][j] = __builtin_amdgcn_mfma_f32_16x16x32_bf16(af[i], bf[j], acc[i][j], 0, 0, 0);
        __syncthreads();
    }

    int rbase = (lane >> 4) * 4;
    int ncol = lane & 15;
#pragma unroll
    for (int i = 0; i < 4; i++) {
#pragma unroll
        for (int j = 0; j < 4; j++) {
            int n = n0 + wn + j * 16 + ncol;
            float bv = bias ? bias[n] : 0.f;
#pragma unroll
            for (int r = 0; r < 4; r++) {
                int m = m0 + wm + i * 16 + rbase + r;
                float c = acc[i][j][r] + bv;
                if (act == 1) c *= sigm(c);
                size_t o = (size_t)m * Nn + n;
                if (add) c = add[o] + coef * c;
                if (outbf) ((u16*)Cv)[o] = f2bf(c);
                else ((float*)Cv)[o] = c;
            }
        }
    }
}

// ---------- fused flash attention: scores + softmax + PV, one block = 16 q-rows x z ----------
// grid (128 z, 32 m): same-z blocks share an XCD for K/V/P L2 locality.
__global__ __launch_bounds__(256) void fattn_k(
    const u16* __restrict__ QU, const u16* __restrict__ QV,
    const u16* __restrict__ Kb, const u16* __restrict__ Pbf,
    const u16* __restrict__ VT, u16* __restrict__ ctx) {
    __shared__ u16 arr[26496];  // 52,992 B
    u16* sB = arr;                        // [0,16896): P/K 528x32 staging; V 64x32 in [0,2048)
    u16* sP = arr + 4096;                 // [4096,12416): probs 16 x 520 (pad), aliases sB tail
    u16* sRect = arr + 16896;             // [16896,25344): bd rect 16 x 528
    u16* sCtx = arr + 16896;              // alias sRect head: 16 x 64
    u16* sQ = arr + 25344;                // [25344,26368): 16 x 64
    float* sRed = (float*)(arr + 26368);  // 16 x 4 floats

    int tid = threadIdx.x;
    int lane = tid & 63, w = tid >> 6;
    int quad = lane >> 4, col = lane & 15;
    int nh = blockIdx.x, h = nh & 7, nb = nh >> 3;
    int m0 = blockIdx.y << 4;
    int nlo = 496 - m0;  // bd rect covers P rows [nlo, nlo+528)

    // ---- phase 1: bd rect = QV_tile(16x64) . P[nlo..+528)^T ----
    if (tid < 128)
        __builtin_amdgcn_global_load_lds(
            (const __attribute__((address_space(1))) void*)(QV + (((size_t)nh * 512 + m0 + (tid >> 3)) << 6) + ((tid & 7) << 3)),
            (__attribute__((address_space(3))) void*)(sQ + tid * 8), 16, 0, 0);
    f32x4 bdacc[9];
#pragma unroll
    for (int i = 0; i < 9; i++) bdacc[i] = (f32x4){0.f, 0.f, 0.f, 0.f};
    const u16* Pb = Pbf + ((size_t)h << 16);
    for (int ks = 0; ks < 2; ks++) {
#pragma unroll
        for (int s = 0; s < 8; s++) {
            int row = (s << 6) + (tid >> 2);
            __builtin_amdgcn_global_load_lds(
                (const __attribute__((address_space(1))) void*)(Pb + (((size_t)(nlo + row)) << 6) + (ks << 5) + ((tid & 3) << 3)),
                (__attribute__((address_space(3))) void*)(sB + (s << 11) + tid * 8), 16, 0, 0);
        }
        if (tid < 64) {
            int row = 512 + (tid >> 2);
            __builtin_amdgcn_global_load_lds(
                (const __attribute__((address_space(1))) void*)(Pb + (((size_t)(nlo + row)) << 6) + (ks << 5) + ((tid & 3) << 3)),
                (__attribute__((address_space(3))) void*)(sB + (8 << 11) + tid * 8), 16, 0, 0);
        }
        __syncthreads();
        bf16x8 a = *(const bf16x8*)(sQ + col * 64 + (ks << 5) + quad * 8);
        int idx = 0;
        for (int nt = w; nt < 33; nt += 4, idx++) {
            bf16x8 b = *(const bf16x8*)(sB + ((nt * 16 + col) << 5) + quad * 8);
            bdacc[idx] = __builtin_amdgcn_mfma_f32_16x16x32_bf16(a, b, bdacc[idx], 0, 0, 0);
        }
        __syncthreads();
    }
    {
        int idx = 0;
        for (int nt = w; nt < 33; nt += 4, idx++)
#pragma unroll
            for (int r = 0; r < 4; r++)
                sRect[(quad * 4 + r) * 528 + nt * 16 + col] = f2bf(bdacc[idx][r]);
    }
    __syncthreads();

    // ---- phase 2: ac = QU_tile(16x64) . K^T ----
    if (tid < 128)
        __builtin_amdgcn_global_load_lds(
            (const __attribute__((address_space(1))) void*)(QU + (((size_t)nh * 512 + m0 + (tid >> 3)) << 6) + ((tid & 7) << 3)),
            (__attribute__((address_space(3))) void*)(sQ + tid * 8), 16, 0, 0);
    f32x4 ac[8];
#pragma unroll
    for (int i = 0; i < 8; i++) ac[i] = (f32x4){0.f, 0.f, 0.f, 0.f};
    const u16* Kz = Kb + ((size_t)nh << 15);
    for (int ks = 0; ks < 2; ks++) {
#pragma unroll
        for (int s = 0; s < 8; s++) {
            int row = (s << 6) + (tid >> 2);
            __builtin_amdgcn_global_load_lds(
                (const __attribute__((address_space(1))) void*)(Kz + ((size_t)row << 6) + (ks << 5) + ((tid & 3) << 3)),
                (__attribute__((address_space(3))) void*)(sB + (s << 11) + tid * 8), 16, 0, 0);
        }
        __syncthreads();
        bf16x8 a = *(const bf16x8*)(sQ + col * 64 + (ks << 5) + quad * 8);
#pragma unroll
        for (int jt = 0; jt < 8; jt++) {
            bf16x8 b = *(const bf16x8*)(sB + (((w << 7) + jt * 16 + col) << 5) + quad * 8);
            ac[jt] = __builtin_amdgcn_mfma_f32_16x16x32_bf16(a, b, ac[jt], 0, 0, 0);
        }
        __syncthreads();
    }

    // ---- phase 3: shifted add + scale + softmax over j ----
    float rmax[4];
#pragma unroll
    for (int r = 0; r < 4; r++) rmax[r] = -1e30f;
#pragma unroll
    for (int jt = 0; jt < 8; jt++) {
        int j = (w << 7) + jt * 16 + col;
#pragma unroll
        for (int r = 0; r < 4; r++) {
            int ml = quad * 4 + r;
            float v = (ac[jt][r] + bf2f(sRect[ml * 528 + (j - ml + 15)])) * 0.125f;
            ac[jt][r] = v;
            rmax[r] = fmaxf(rmax[r], v);
        }
    }
#pragma unroll
    for (int o = 1; o <= 8; o <<= 1)
#pragma unroll
        for (int r = 0; r < 4; r++) rmax[r] = fmaxf(rmax[r], __shfl_xor(rmax[r], o));
    if (col == 0)
#pragma unroll
        for (int r = 0; r < 4; r++) sRed[(quad * 4 + r) * 4 + w] = rmax[r];
    __syncthreads();
    float gmax[4], psum[4];
#pragma unroll
    for (int r = 0; r < 4; r++) {
        int ml = quad * 4 + r;
        gmax[r] = fmaxf(fmaxf(sRed[ml * 4 + 0], sRed[ml * 4 + 1]),
                        fmaxf(sRed[ml * 4 + 2], sRed[ml * 4 + 3]));
        psum[r] = 0.f;
    }
    __syncthreads();
#pragma unroll
    for (int jt = 0; jt < 8; jt++)
#pragma unroll
        for (int r = 0; r < 4; r++) {
            float e = __expf(ac[jt][r] - gmax[r]);
            ac[jt][r] = e;
            psum[r] += e;
        }
#pragma unroll
    for (int o = 1; o <= 8; o <<= 1)
#pragma unroll
        for (int r = 0; r < 4; r++) psum[r] += __shfl_xor(psum[r], o);
    if (col == 0)
#pragma unroll
        for (int r = 0; r < 4; r++) sRed[(quad * 4 + r) * 4 + w] = psum[r];
    __syncthreads();
    float rinv[4];
#pragma unroll
    for (int r = 0; r < 4; r++) {
        int ml = quad * 4 + r;
        rinv[r] = 1.f / (sRed[ml * 4 + 0] + sRed[ml * 4 + 1] + sRed[ml * 4 + 2] + sRed[ml * 4 + 3]);
    }
    // ---- phase 4: probs -> sP (bf16, stride 520) ----
#pragma unroll
    for (int jt = 0; jt < 8; jt++) {
        int j = (w << 7) + jt * 16 + col;
#pragma unroll
        for (int r = 0; r < 4; r++)
            sP[(quad * 4 + r) * 520 + j] = f2bf(ac[jt][r] * rinv[r]);
    }
    __syncthreads();

    // ---- phase 5: ctx_tile(16x64) = P(16x512) . V^T; wave w owns d-cols [16w,16w+16) ----
    const u16* Vz = VT + ((size_t)nh << 15);
    f32x4 cacc = (f32x4){0.f, 0.f, 0.f, 0.f};
    for (int k0 = 0; k0 < 512; k0 += 32) {
        __builtin_amdgcn_global_load_lds(
            (const __attribute__((address_space(1))) void*)(Vz + (size_t)(tid >> 2) * 512 + k0 + ((tid & 3) << 3)),
            (__attribute__((address_space(3))) void*)(sB + tid * 8), 16, 0, 0);
        __syncthreads();
        bf16x8 a = *(const bf16x8*)(sP + col * 520 + k0 + quad * 8);
        bf16x8 b = *(const bf16x8*)(sB + (((w << 4) + col) << 5) + quad * 8);
        cacc = __builtin_amdgcn_mfma_f32_16x16x32_bf16(a, b, cacc, 0, 0, 0);
        __syncthreads();
    }

    // ---- phase 6: ctx tile -> LDS -> coalesced 16B stores ----
#pragma unroll
    for (int r = 0; r < 4; r++)
        sCtx[(quad * 4 + r) * 64 + (w << 4) + col] = f2bf(cacc[r]);
    __syncthreads();
    if (tid < 128) {
        int row = tid >> 3, seg = tid & 7;
        u16* dst = ctx + (((size_t)((m0 + row) * 16 + nb)) << 9) + (h << 6) + seg * 8;
        *(uint4*)dst = *(const uint4*)(sCtx + row * 64 + seg * 8);
    }
}

// ---------- fp32 GEMM (pos projection, M=1023): C = A*B^T ----------
__global__ __launch_bounds__(256) void gemm_f32_k(
    const float* __restrict__ A, const float* __restrict__ B, float* __restrict__ C,
    int M, int Nn, int Kk) {
    __shared__ float As[16][64];
    __shared__ float Bs[16][64];
    int tid = threadIdx.x;
    int tx = tid & 15, ty = tid >> 4;
    int m0 = blockIdx.y << 6, n0 = blockIdx.x << 6;
    int arow = tid >> 2, acol = (tid & 3) << 2;
    float acc[4][4] = {};
    for (int k0 = 0; k0 < Kk; k0 += 16) {
        int gr = m0 + arow;
        float4 av = make_float4(0.f, 0.f, 0.f, 0.f);
        if (gr < M) av = *(const float4*)(A + (size_t)gr * Kk + k0 + acol);
        As[acol + 0][arow] = av.x; As[acol + 1][arow] = av.y;
        As[acol + 2][arow] = av.z; As[acol + 3][arow] = av.w;
        float4 bv = *(const float4*)(B + (size_t)(n0 + arow) * Kk + k0 + acol);
        Bs[acol + 0][arow] = bv.x; Bs[acol + 1][arow] = bv.y;
        Bs[acol + 2][arow] = bv.z; Bs[acol + 3][arow] = bv.w;
        __syncthreads();
#pragma unroll
        for (int kk = 0; kk < 16; kk++) {
            float4 a4 = *(const float4*)&As[kk][ty << 2];
            float4 b4 = *(const float4*)&Bs[kk][tx << 2];
            float ar[4] = {a4.x, a4.y, a4.z, a4.w};
            float br[4] = {b4.x, b4.y, b4.z, b4.w};
#pragma unroll
            for (int i = 0; i < 4; i++)
#pragma unroll
                for (int j = 0; j < 4; j++) acc[i][j] += ar[i] * br[j];
        }
        __syncthreads();
    }
#pragma unroll
    for (int i = 0; i < 4; i++) {
        int gr = m0 + (ty << 2) + i;
        if (gr >= M) continue;
#pragma unroll
        for (int j = 0; j < 4; j++)
            C[(size_t)gr * Nn + n0 + (tx << 2) + j] = acc[i][j];
    }
}

// ---------- cast/reshape PB (1023,512) fp32 -> Pbf (h,1024,64) bf16 ----------
__global__ void pbcast_k(const float* __restrict__ pb, u16* __restrict__ pbbf) {
    int idx = blockIdx.x * 256 + threadIdx.x;
    if (idx >= 1023 * 512) return;
    int m = idx >> 9, c = idx & 511, h = c >> 6, d = c & 63;
    pbbf[((size_t)(h * 1024 + m) << 6) + d] = f2bf(pb[idx]);
}

// ---------- repack qkv (M,1536) bf16 -> QU/QV (nh,512,64)+bias, K (nh,512,64), VT (nh,64,512) ----------
__global__ void repack_k(const u16* __restrict__ qkv, const float* __restrict__ bu,
                         const float* __restrict__ bv, u16* __restrict__ QU,
                         u16* __restrict__ QV, u16* __restrict__ Kb, u16* __restrict__ VT) {
    int e = blockIdx.x * 256 + threadIdx.x;  // M*512
    int c = e & 511, t = e >> 9;
    int l = t >> 4, n = t & 15, h = c >> 6, d = c & 63;
    size_t base = (size_t)t * 1536 + c;
    float q = bf2f(qkv[base]);
    u16 k = qkv[base + 512], v = qkv[base + 1024];
    int nh = n * 8 + h;
    size_t o = ((size_t)nh * 512 + l) * 64 + d;
    QU[o] = f2bf(q + bu[h * 64 + d]);
    QV[o] = f2bf(q + bv[h * 64 + d]);
    Kb[o] = k;
    VT[((size_t)nh * 64 + d) * 512 + l] = v;
}

// ---------- GLU: (M,1024) bf16 -> (M,512) bf16 ----------
__global__ void glu_k(const u16* __restrict__ pw1o, u16* __restrict__ g) {
    int e = blockIdx.x * 256 + threadIdx.x;  // M*512
    int t = e >> 9, c = e & 511;
    float a = bf2f(pw1o[(size_t)t * 1024 + c]);
    float ga = bf2f(pw1o[(size_t)t * 1024 + 512 + c]);
    g[e] = f2bf(a * sigm(ga));
}

// ---------- depthwise conv: sliding window, 16 outputs per thread ----------
__global__ __launch_bounds__(256) void dwconv_k(
    const u16* __restrict__ g, const float* __restrict__ w, const float* __restrict__ wb,
    const float* __restrict__ bng, const float* __restrict__ bnb, const float* __restrict__ bnm,
    const float* __restrict__ bnv, u16* __restrict__ out) {
    int idx = blockIdx.x * 256 + threadIdx.x;  // 262144 threads
    int c = idx & 511;
    int t = idx >> 9;
    int n = t & 15, l0 = (t >> 4) << 4;
    float win[46];
#pragma unroll
    for (int q = 0; q < 46; q++) {
        int ll = l0 - 15 + q;
        win[q] = (ll >= 0 && ll < 512) ? bf2f(g[((size_t)(ll * 16 + n) << 9) + c]) : 0.f;
    }
    float wgt[31];
#pragma unroll
    for (int k = 0; k < 31; k++) wgt[k] = w[c * 31 + k];
    float ivg = rsqrtf(bnv[c] + 1e-5f) * bng[c];
    float mc = bnm[c], bc = bnb[c], wbc = wb[c];
#pragma unroll
    for (int r = 0; r < 16; r++) {
        float acc = 0.f;
#pragma unroll
        for (int k = 0; k < 31; k++) acc += wgt[k] * win[r + k];
        acc += wbc;
        float y = (acc - mc) * ivg + bc;
        y = y * sigm(y);
        out[((size_t)((l0 + r) * 16 + n) << 9) + c] = f2bf(y);
    }
}

// ---------- launch ----------
extern "C" void kernel_launch(void* const* d_in, const int* in_sizes, int n_in,
                              void* d_out, int out_size, void* d_ws, size_t ws_size,
                              hipStream_t stream) {
    const float* src      = (const float*)d_in[0];
    const float* pos_emb  = (const float*)d_in[1];
    const float* ffm_w1   = (const float*)d_in[2];
    const float* ffm_b1   = (const float*)d_in[3];
    const float* ffm_w2   = (const float*)d_in[4];
    const float* ffm_b2   = (const float*)d_in[5];
    const float* ff_w1    = (const float*)d_in[6];
    const float* ff_b1    = (const float*)d_in[7];
    const float* ff_w2    = (const float*)d_in[8];
    const float* ff_b2    = (const float*)d_in[9];
    const float* in_w     = (const float*)d_in[10];
    const float* in_b     = (const float*)d_in[11];
    const float* out_w    = (const float*)d_in[12];
    const float* out_b    = (const float*)d_in[13];
    const float* pos_w    = (const float*)d_in[14];
    const float* bu       = (const float*)d_in[15];
    const float* bv       = (const float*)d_in[16];
    const float* pw1_w    = (const float*)d_in[17];
    const float* pw1_b    = (const float*)d_in[18];
    const float* dw_w     = (const float*)d_in[19];
    const float* dw_b     = (const float*)d_in[20];
    const float* bng      = (const float*)d_in[21];
    const float* bnb      = (const float*)d_in[22];
    const float* bnm      = (const float*)d_in[23];
    const float* bnv      = (const float*)d_in[24];
    const float* pw2_w    = (const float*)d_in[25];
    const float* pw2_b    = (const float*)d_in[26];
    const float* ln_ffm_g = (const float*)d_in[27];
    const float* ln_ffm_b = (const float*)d_in[28];
    const float* ln_mha_g = (const float*)d_in[29];
    const float* ln_mha_b = (const float*)d_in[30];
    const float* ln_cv_g  = (const float*)d_in[31];
    const float* ln_cv_b  = (const float*)d_in[32];
    const float* ln_ff_g  = (const float*)d_in[33];
    const float* ln_ff_b  = (const float*)d_in[34];
    const float* ln_fin_g = (const float*)d_in[35];
    const float* ln_fin_b = (const float*)d_in[36];
    (void)in_sizes; (void)n_in; (void)out_size; (void)ws_size;

    // ---- workspace layout in u16 units; total ~115.5 MiB ----
    const size_t MEG = 1048576;
    u16* U = (u16*)d_ws;
    float* xA = (float*)U;                // 8M u16; Pbf aliases during attention
    u16* Pbf = U;                         // 524288 u16 (8 x 1024 x 64); dead before xA written
    float* xB = (float*)(U + 8 * MEG);    // 8M
    u16* LNB = U + 16 * MEG;              // 4M
    u16* BIG = U + 20 * MEG;              // 16M: h1 / PB / qkv / pw1-out
    float* PB = (float*)BIG;              // 1023*512 fp32 (pre-qkv)
    u16* QU = U + 36 * MEG;               // 4M
    u16* QV = U + 40 * MEG;               // 4M
    u16* Kb = U + 44 * MEG;               // 4M
    u16* VT = U + 48 * MEG;               // 4M
    u16* WB = U + 52 * MEG;               // 6,029,312 weights bf16
    u16* w_ffm1 = WB;
    u16* w_ffm2 = WB + 1 * MEG;
    u16* w_ff1  = WB + 2 * MEG;
    u16* w_ff2  = WB + 3 * MEG;
    u16* w_in   = WB + 4 * MEG;
    u16* w_out  = WB + 4 * MEG + 786432;
    u16* w_pw1  = WB + 5 * MEG;
    u16* w_pw2  = WB + 5 * MEG + 524288;
    u16* CTX = LNB;
    u16* GLU = QU;
    u16* CACT = QV;

    // ---- cast all weights to bf16 (one dispatch) ----
    castall_k<<<23552, 256, 0, stream>>>(ffm_w1, ffm_w2, ff_w1, ff_w2, in_w, out_w,
                                         pw1_w, pw2_w, WB);

    // ---- FFN macaron: xB = src + 0.5*ffn(ln(src)) ----
    ln512_k<true><<<8192, 64, 0, stream>>>(src, ln_ffm_g, ln_ffm_b, LNB);
    mgemm_k<<<dim3(64, 16), 256, 0, stream>>>(LNB, w_ffm1, ffm_b1, nullptr, BIG,
                                              8192, 2048, 512, 0.f, 1, 1);
    mgemm_k<<<dim3(64, 4), 256, 0, stream>>>(BIG, w_ffm2, ffm_b2, src, xB,
                                             8192, 512, 2048, 0.5f, 0, 0);

    // ---- attention: xA = xB + attn(ln(xB)) ----
    ln512_k<true><<<8192, 64, 0, stream>>>(xB, ln_mha_g, ln_mha_b, LNB);
    gemm_f32_k<<<dim3(8, 16), 256, 0, stream>>>(pos_emb, pos_w, PB, 1023, 512, 512);
    pbcast_k<<<2046, 256, 0, stream>>>(PB, Pbf);
    mgemm_k<<<dim3(64, 12), 256, 0, stream>>>(LNB, w_in, in_b, nullptr, BIG,
                                              8192, 1536, 512, 0.f, 0, 1);
    repack_k<<<16384, 256, 0, stream>>>(BIG, bu, bv, QU, QV, Kb, VT);
    fattn_k<<<dim3(128, 32), 256, 0, stream>>>(QU, QV, Kb, Pbf, VT, CTX);
    mgemm_k<<<dim3(64, 4), 256, 0, stream>>>(CTX, w_out, out_b, xB, xA,
                                             8192, 512, 512, 1.f, 0, 0);

    // ---- conv module: xB = xA + conv(ln(xA)) ----
    ln512_k<true><<<8192, 64, 0, stream>>>(xA, ln_cv_g, ln_cv_b, LNB);
    mgemm_k<<<dim3(64, 8), 256, 0, stream>>>(LNB, w_pw1, pw1_b, nullptr, BIG,
                                             8192, 1024, 512, 0.f, 0, 1);
    glu_k<<<16384, 256, 0, stream>>>(BIG, GLU);
    dwconv_k<<<1024, 256, 0, stream>>>(GLU, dw_w, dw_b, bng, bnb, bnm, bnv, CACT);
    mgemm_k<<<dim3(64, 4), 256, 0, stream>>>(CACT, w_pw2, pw2_b, xA, xB,
                                             8192, 512, 512, 1.f, 0, 0);

    // ---- FFN 2: xA = xB + 0.5*ffn(ln(xB)) ----
    ln512_k<true><<<8192, 64, 0, stream>>>(xB, ln_ff_g, ln_ff_b, LNB);
    mgemm_k<<<dim3(64, 16), 256, 0, stream>>>(LNB, w_ff1, ff_b1, nullptr, BIG,
                                              8192, 2048, 512, 0.f, 1, 1);
    mgemm_k<<<dim3(64, 4), 256, 0, stream>>>(BIG, w_ff2, ff_b2, xB, xA,
                                             8192, 512, 2048, 0.5f, 0, 0);

    // ---- final LN -> fp32 out ----
    ln512_k<false><<<8192, 64, 0, stream>>>(xA, ln_fin_g, ln_fin_b, (float*)d_out);
}

// Round 9
// 667.145 us; speedup vs baseline: 5.5597x; 1.1437x over previous
//
#include <hip/hip_runtime.h>
#include <cstdint>
#include <cstddef>

typedef unsigned short u16;
typedef __attribute__((ext_vector_type(4))) float f32x4;
typedef __attribute__((ext_vector_type(8))) short bf16x8;

// ---------- helpers ----------
__device__ __forceinline__ float sigm(float x) { return 1.f / (1.f + __expf(-x)); }
__device__ __forceinline__ float bf2f(u16 u) {
    union { unsigned int i; float f; } c; c.i = ((unsigned int)u) << 16; return c.f;
}
__device__ __forceinline__ u16 f2bf(float f) {
    union { float f; unsigned int i; } c; c.f = f;
    unsigned int x = c.i;
    x += 0x7fffu + ((x >> 16) & 1u);
    return (u16)(x >> 16);
}

// dims: D=512, H=8, DH=64, F=2048, K=31, L=512, N=16, M=8192

// ---------- fused weight cast fp32 -> bf16 ----------
__global__ void castall_k(const float* __restrict__ s0, const float* __restrict__ s1,
                          const float* __restrict__ s2, const float* __restrict__ s3,
                          const float* __restrict__ s4, const float* __restrict__ s5,
                          const float* __restrict__ s6, const float* __restrict__ s7,
                          u16* __restrict__ dst) {
    int i = blockIdx.x * 256 + threadIdx.x;
    if (i >= 6029312) return;
    const float* s; int off;
    if      (i < 1048576) { s = s0; off = 0; }
    else if (i < 2097152) { s = s1; off = 1048576; }
    else if (i < 3145728) { s = s2; off = 2097152; }
    else if (i < 4194304) { s = s3; off = 3145728; }
    else if (i < 4980736) { s = s4; off = 4194304; }
    else if (i < 5242880) { s = s5; off = 4980736; }
    else if (i < 5767168) { s = s6; off = 5242880; }
    else                  { s = s7; off = 5767168; }
    dst[i] = f2bf(s[i - off]);
}

// ---------- LayerNorm over 512 (fp32 in), one wave per row ----------
template <bool OUTBF>
__global__ void ln512_k(const float* __restrict__ x, const float* __restrict__ g,
                        const float* __restrict__ b, void* __restrict__ outv) {
    int row = blockIdx.x;
    int lane = threadIdx.x;  // 64
    const float* xr = x + (size_t)row * 512 + lane * 8;
    float4 v0 = *(const float4*)(xr);
    float4 v1 = *(const float4*)(xr + 4);
    float va[8] = {v0.x, v0.y, v0.z, v0.w, v1.x, v1.y, v1.z, v1.w};
    float s = 0.f;
#pragma unroll
    for (int t = 0; t < 8; t++) s += va[t];
#pragma unroll
    for (int o = 32; o > 0; o >>= 1) s += __shfl_xor(s, o);
    float m = s * (1.0f / 512.0f);
    float q = 0.f;
#pragma unroll
    for (int t = 0; t < 8; t++) { float d = va[t] - m; q += d * d; }
#pragma unroll
    for (int o = 32; o > 0; o >>= 1) q += __shfl_xor(q, o);
    float inv = rsqrtf(q * (1.0f / 512.0f) + 1e-5f);
    int cb = lane * 8;
    if (OUTBF) {
        u16* o = (u16*)outv + (size_t)row * 512 + cb;
#pragma unroll
        for (int t = 0; t < 8; t++)
            o[t] = f2bf((va[t] - m) * inv * g[cb + t] + b[cb + t]);
    } else {
        float* o = (float*)outv + (size_t)row * 512 + cb;
#pragma unroll
        for (int t = 0; t < 8; t++)
            o[t] = (va[t] - m) * inv * g[cb + t] + b[cb + t];
    }
}

// ---------- MFMA GEMM: C(M,N) = act(A(M,K)*B(N,K)^T + bias); C = add + coef*C ----------
__global__ __launch_bounds__(256) void mgemm_k(
    const u16* __restrict__ A, const u16* __restrict__ B, const float* __restrict__ bias,
    const float* __restrict__ add, void* __restrict__ Cv,
    int M, int Nn, int Kk, float coef, int act, int outbf) {
    __shared__ u16 lA[128 * 32];
    __shared__ u16 lB[128 * 32];
    int tid = threadIdx.x;
    int lane = tid & 63, w = tid >> 6;
    int wm = (w >> 1) * 64, wn = (w & 1) * 64;
    int m0 = blockIdx.x << 7, n0 = blockIdx.y << 7;

    f32x4 acc[4][4];
#pragma unroll
    for (int i = 0; i < 4; i++)
#pragma unroll
        for (int j = 0; j < 4; j++) acc[i][j] = (f32x4){0.f, 0.f, 0.f, 0.f};

    int srow = tid >> 2;
    int scol = (tid & 3) << 3;
    const u16* gA = A + (size_t)(m0 + srow) * Kk + scol;
    const u16* gB = B + (size_t)(n0 + srow) * Kk + scol;
    int lso = tid * 8;

    int lra = wm * 32 + (lane & 15) * 32 + (lane >> 4) * 8;
    int lrb = wn * 32 + (lane & 15) * 32 + (lane >> 4) * 8;

    for (int k0 = 0; k0 < Kk; k0 += 32) {
        __builtin_amdgcn_global_load_lds(
            (const __attribute__((address_space(1))) void*)(gA + k0),
            (__attribute__((address_space(3))) void*)(lA + lso), 16, 0, 0);
        __builtin_amdgcn_global_load_lds(
            (const __attribute__((address_space(1))) void*)(gA + (size_t)64 * Kk + k0),
            (__attribute__((address_space(3))) void*)(lA + 2048 + lso), 16, 0, 0);
        __builtin_amdgcn_global_load_lds(
            (const __attribute__((address_space(1))) void*)(gB + k0),
            (__attribute__((address_space(3))) void*)(lB + lso), 16, 0, 0);
        __builtin_amdgcn_global_load_lds(
            (const __attribute__((address_space(1))) void*)(gB + (size_t)64 * Kk + k0),
            (__attribute__((address_space(3))) void*)(lB + 2048 + lso), 16, 0, 0);
        __syncthreads();
        bf16x8 af[4], bf[4];
#pragma unroll
        for (int t = 0; t < 4; t++) {
            af[t] = *(const bf16x8*)(lA + lra + t * 16 * 32);
            bf[t] = *(const bf16x8*)(lB + lrb + t * 16 * 32);
        }
#pragma unroll
        for (int i = 0; i < 4; i++)
#pragma unroll
            for (int j = 0; j < 4; j++)
                acc[i][j] = __builtin_amdgcn_mfma_f32_16x16x32_bf16(af[i], bf[j], acc[i][j], 0, 0, 0);
        __syncthreads();
    }

    int rbase = (lane >> 4) * 4;
    int ncol = lane & 15;
#pragma unroll
    for (int i = 0; i < 4; i++) {
#pragma unroll
        for (int j = 0; j < 4; j++) {
            int n = n0 + wn + j * 16 + ncol;
            float bv = bias ? bias[n] : 0.f;
#pragma unroll
            for (int r = 0; r < 4; r++) {
                int m = m0 + wm + i * 16 + rbase + r;
                float c = acc[i][j][r] + bv;
                if (act == 1) c *= sigm(c);
                size_t o = (size_t)m * Nn + n;
                if (add) c = add[o] + coef * c;
                if (outbf) ((u16*)Cv)[o] = f2bf(c);
                else ((float*)Cv)[o] = c;
            }
        }
    }
}

// ---------- fused flash attention: scores + softmax + PV, one block = 16 q-rows x z ----------
// grid (128 z, 32 m): same-z blocks share an XCD for K/V/P L2 locality.
__global__ __launch_bounds__(256) void fattn_k(
    const u16* __restrict__ QU, const u16* __restrict__ QV,
    const u16* __restrict__ Kb, const u16* __restrict__ Pbf,
    const u16* __restrict__ VT, u16* __restrict__ ctx) {
    __shared__ u16 arr[26496];  // 52,992 B
    u16* sB = arr;                        // [0,16896): P/K 528x32 staging; V 64x32 in [0,2048)
    u16* sP = arr + 4096;                 // [4096,12416): probs 16 x 520 (pad), aliases sB tail
    u16* sRect = arr + 16896;             // [16896,25344): bd rect 16 x 528
    u16* sCtx = arr + 16896;              // alias sRect head: 16 x 64
    u16* sQ = arr + 25344;                // [25344,26368): 16 x 64
    float* sRed = (float*)(arr + 26368);  // 16 x 4 floats

    int tid = threadIdx.x;
    int lane = tid & 63, w = tid >> 6;
    int quad = lane >> 4, col = lane & 15;
    int nh = blockIdx.x, h = nh & 7, nb = nh >> 3;
    int m0 = blockIdx.y << 4;
    int nlo = 496 - m0;  // bd rect covers P rows [nlo, nlo+528)

    // ---- phase 1: bd rect = QV_tile(16x64) . P[nlo..+528)^T ----
    // wave w handles tiles nt = w + 4*idx (static unroll; idx=8 only valid for w==0)
    if (tid < 128)
        __builtin_amdgcn_global_load_lds(
            (const __attribute__((address_space(1))) void*)(QV + (((size_t)nh * 512 + m0 + (tid >> 3)) << 6) + ((tid & 7) << 3)),
            (__attribute__((address_space(3))) void*)(sQ + tid * 8), 16, 0, 0);
    f32x4 bdacc[9];
#pragma unroll
    for (int i = 0; i < 9; i++) bdacc[i] = (f32x4){0.f, 0.f, 0.f, 0.f};
    const u16* Pb = Pbf + ((size_t)h << 16);
    for (int ks = 0; ks < 2; ks++) {
#pragma unroll
        for (int s = 0; s < 8; s++) {
            int row = (s << 6) + (tid >> 2);
            __builtin_amdgcn_global_load_lds(
                (const __attribute__((address_space(1))) void*)(Pb + (((size_t)(nlo + row)) << 6) + (ks << 5) + ((tid & 3) << 3)),
                (__attribute__((address_space(3))) void*)(sB + (s << 11) + tid * 8), 16, 0, 0);
        }
        if (tid < 64) {
            int row = 512 + (tid >> 2);
            __builtin_amdgcn_global_load_lds(
                (const __attribute__((address_space(1))) void*)(Pb + (((size_t)(nlo + row)) << 6) + (ks << 5) + ((tid & 3) << 3)),
                (__attribute__((address_space(3))) void*)(sB + (8 << 11) + tid * 8), 16, 0, 0);
        }
        __syncthreads();
        bf16x8 a = *(const bf16x8*)(sQ + col * 64 + (ks << 5) + quad * 8);
#pragma unroll
        for (int idx = 0; idx < 9; idx++) {
            int nt = w + (idx << 2);
            if (nt < 33) {
                bf16x8 b = *(const bf16x8*)(sB + ((nt * 16 + col) << 5) + quad * 8);
                bdacc[idx] = __builtin_amdgcn_mfma_f32_16x16x32_bf16(a, b, bdacc[idx], 0, 0, 0);
            }
        }
        __syncthreads();
    }
#pragma unroll
    for (int idx = 0; idx < 9; idx++) {
        int nt = w + (idx << 2);
        if (nt < 33) {
#pragma unroll
            for (int r = 0; r < 4; r++)
                sRect[(quad * 4 + r) * 528 + nt * 16 + col] = f2bf(bdacc[idx][r]);
        }
    }
    __syncthreads();

    // ---- phase 2: ac = QU_tile(16x64) . K^T ----
    if (tid < 128)
        __builtin_amdgcn_global_load_lds(
            (const __attribute__((address_space(1))) void*)(QU + (((size_t)nh * 512 + m0 + (tid >> 3)) << 6) + ((tid & 7) << 3)),
            (__attribute__((address_space(3))) void*)(sQ + tid * 8), 16, 0, 0);
    f32x4 ac[8];
#pragma unroll
    for (int i = 0; i < 8; i++) ac[i] = (f32x4){0.f, 0.f, 0.f, 0.f};
    const u16* Kz = Kb + ((size_t)nh << 15);
    for (int ks = 0; ks < 2; ks++) {
#pragma unroll
        for (int s = 0; s < 8; s++) {
            int row = (s << 6) + (tid >> 2);
            __builtin_amdgcn_global_load_lds(
                (const __attribute__((address_space(1))) void*)(Kz + ((size_t)row << 6) + (ks << 5) + ((tid & 3) << 3)),
                (__attribute__((address_space(3))) void*)(sB + (s << 11) + tid * 8), 16, 0, 0);
        }
        __syncthreads();
        bf16x8 a = *(const bf16x8*)(sQ + col * 64 + (ks << 5) + quad * 8);
#pragma unroll
        for (int jt = 0; jt < 8; jt++) {
            bf16x8 b = *(const bf16x8*)(sB + (((w << 7) + jt * 16 + col) << 5) + quad * 8);
            ac[jt] = __builtin_amdgcn_mfma_f32_16x16x32_bf16(a, b, ac[jt], 0, 0, 0);
        }
        __syncthreads();
    }

    // ---- phase 3: shifted add + scale + softmax over j ----
    float rmax[4];
#pragma unroll
    for (int r = 0; r < 4; r++) rmax[r] = -1e30f;
#pragma unroll
    for (int jt = 0; jt < 8; jt++) {
        int j = (w << 7) + jt * 16 + col;
#pragma unroll
        for (int r = 0; r < 4; r++) {
            int ml = quad * 4 + r;
            float v = (ac[jt][r] + bf2f(sRect[ml * 528 + (j - ml + 15)])) * 0.125f;
            ac[jt][r] = v;
            rmax[r] = fmaxf(rmax[r], v);
        }
    }
#pragma unroll
    for (int o = 1; o <= 8; o <<= 1)
#pragma unroll
        for (int r = 0; r < 4; r++) rmax[r] = fmaxf(rmax[r], __shfl_xor(rmax[r], o));
    if (col == 0)
#pragma unroll
        for (int r = 0; r < 4; r++) sRed[(quad * 4 + r) * 4 + w] = rmax[r];
    __syncthreads();
    float gmax[4], psum[4];
#pragma unroll
    for (int r = 0; r < 4; r++) {
        int ml = quad * 4 + r;
        gmax[r] = fmaxf(fmaxf(sRed[ml * 4 + 0], sRed[ml * 4 + 1]),
                        fmaxf(sRed[ml * 4 + 2], sRed[ml * 4 + 3]));
        psum[r] = 0.f;
    }
    __syncthreads();
#pragma unroll
    for (int jt = 0; jt < 8; jt++)
#pragma unroll
        for (int r = 0; r < 4; r++) {
            float e = __expf(ac[jt][r] - gmax[r]);
            ac[jt][r] = e;
            psum[r] += e;
        }
#pragma unroll
    for (int o = 1; o <= 8; o <<= 1)
#pragma unroll
        for (int r = 0; r < 4; r++) psum[r] += __shfl_xor(psum[r], o);
    if (col == 0)
#pragma unroll
        for (int r = 0; r < 4; r++) sRed[(quad * 4 + r) * 4 + w] = psum[r];
    __syncthreads();
    float rinv[4];
#pragma unroll
    for (int r = 0; r < 4; r++) {
        int ml = quad * 4 + r;
        rinv[r] = 1.f / (sRed[ml * 4 + 0] + sRed[ml * 4 + 1] + sRed[ml * 4 + 2] + sRed[ml * 4 + 3]);
    }
    // ---- phase 4: probs -> sP (bf16, stride 520) ----
#pragma unroll
    for (int jt = 0; jt < 8; jt++) {
        int j = (w << 7) + jt * 16 + col;
#pragma unroll
        for (int r = 0; r < 4; r++)
            sP[(quad * 4 + r) * 520 + j] = f2bf(ac[jt][r] * rinv[r]);
    }
    __syncthreads();

    // ---- phase 5: ctx_tile(16x64) = P(16x512) . V^T; wave w owns d-cols [16w,16w+16) ----
    const u16* Vz = VT + ((size_t)nh << 15);
    f32x4 cacc = (f32x4){0.f, 0.f, 0.f, 0.f};
    for (int k0 = 0; k0 < 512; k0 += 32) {
        __builtin_amdgcn_global_load_lds(
            (const __attribute__((address_space(1))) void*)(Vz + (size_t)(tid >> 2) * 512 + k0 + ((tid & 3) << 3)),
            (__attribute__((address_space(3))) void*)(sB + tid * 8), 16, 0, 0);
        __syncthreads();
        bf16x8 a = *(const bf16x8*)(sP + col * 520 + k0 + quad * 8);
        bf16x8 b = *(const bf16x8*)(sB + (((w << 4) + col) << 5) + quad * 8);
        cacc = __builtin_amdgcn_mfma_f32_16x16x32_bf16(a, b, cacc, 0, 0, 0);
        __syncthreads();
    }

    // ---- phase 6: ctx tile -> LDS -> coalesced 16B stores ----
#pragma unroll
    for (int r = 0; r < 4; r++)
        sCtx[(quad * 4 + r) * 64 + (w << 4) + col] = f2bf(cacc[r]);
    __syncthreads();
    if (tid < 128) {
        int row = tid >> 3, seg = tid & 7;
        u16* dst = ctx + (((size_t)((m0 + row) * 16 + nb)) << 9) + (h << 6) + seg * 8;
        *(uint4*)dst = *(const uint4*)(sCtx + row * 64 + seg * 8);
    }
}

// ---------- fp32 GEMM (pos projection, M=1023): C = A*B^T ----------
__global__ __launch_bounds__(256) void gemm_f32_k(
    const float* __restrict__ A, const float* __restrict__ B, float* __restrict__ C,
    int M, int Nn, int Kk) {
    __shared__ float As[16][64];
    __shared__ float Bs[16][64];
    int tid = threadIdx.x;
    int tx = tid & 15, ty = tid >> 4;
    int m0 = blockIdx.y << 6, n0 = blockIdx.x << 6;
    int arow = tid >> 2, acol = (tid & 3) << 2;
    float acc[4][4] = {};
    for (int k0 = 0; k0 < Kk; k0 += 16) {
        int gr = m0 + arow;
        float4 av = make_float4(0.f, 0.f, 0.f, 0.f);
        if (gr < M) av = *(const float4*)(A + (size_t)gr * Kk + k0 + acol);
        As[acol + 0][arow] = av.x; As[acol + 1][arow] = av.y;
        As[acol + 2][arow] = av.z; As[acol + 3][arow] = av.w;
        float4 bv = *(const float4*)(B + (size_t)(n0 + arow) * Kk + k0 + acol);
        Bs[acol + 0][arow] = bv.x; Bs[acol + 1][arow] = bv.y;
        Bs[acol + 2][arow] = bv.z; Bs[acol + 3][arow] = bv.w;
        __syncthreads();
#pragma unroll
        for (int kk = 0; kk < 16; kk++) {
            float4 a4 = *(const float4*)&As[kk][ty << 2];
            float4 b4 = *(const float4*)&Bs[kk][tx << 2];
            float ar[4] = {a4.x, a4.y, a4.z, a4.w};
            float br[4] = {b4.x, b4.y, b4.z, b4.w};
#pragma unroll
            for (int i = 0; i < 4; i++)
#pragma unroll
                for (int j = 0; j < 4; j++) acc[i][j] += ar[i] * br[j];
        }
        __syncthreads();
    }
#pragma unroll
    for (int i = 0; i < 4; i++) {
        int gr = m0 + (ty << 2) + i;
        if (gr >= M) continue;
#pragma unroll
        for (int j = 0; j < 4; j++)
            C[(size_t)gr * Nn + n0 + (tx << 2) + j] = acc[i][j];
    }
}

// ---------- cast/reshape PB (1023,512) fp32 -> Pbf (h,1024,64) bf16 ----------
__global__ void pbcast_k(const float* __restrict__ pb, u16* __restrict__ pbbf) {
    int idx = blockIdx.x * 256 + threadIdx.x;
    if (idx >= 1023 * 512) return;
    int m = idx >> 9, c = idx & 511, h = c >> 6, d = c & 63;
    pbbf[((size_t)(h * 1024 + m) << 6) + d] = f2bf(pb[idx]);
}

// ---------- repack qkv (M,1536) bf16 -> QU/QV (nh,512,64)+bias, K (nh,512,64), VT (nh,64,512) ----------
__global__ void repack_k(const u16* __restrict__ qkv, const float* __restrict__ bu,
                         const float* __restrict__ bv, u16* __restrict__ QU,
                         u16* __restrict__ QV, u16* __restrict__ Kb, u16* __restrict__ VT) {
    int e = blockIdx.x * 256 + threadIdx.x;  // M*512
    int c = e & 511, t = e >> 9;
    int l = t >> 4, n = t & 15, h = c >> 6, d = c & 63;
    size_t base = (size_t)t * 1536 + c;
    float q = bf2f(qkv[base]);
    u16 k = qkv[base + 512], v = qkv[base + 1024];
    int nh = n * 8 + h;
    size_t o = ((size_t)nh * 512 + l) * 64 + d;
    QU[o] = f2bf(q + bu[h * 64 + d]);
    QV[o] = f2bf(q + bv[h * 64 + d]);
    Kb[o] = k;
    VT[((size_t)nh * 64 + d) * 512 + l] = v;
}

// ---------- GLU: (M,1024) bf16 -> (M,512) bf16 ----------
__global__ void glu_k(const u16* __restrict__ pw1o, u16* __restrict__ g) {
    int e = blockIdx.x * 256 + threadIdx.x;  // M*512
    int t = e >> 9, c = e & 511;
    float a = bf2f(pw1o[(size_t)t * 1024 + c]);
    float ga = bf2f(pw1o[(size_t)t * 1024 + 512 + c]);
    g[e] = f2bf(a * sigm(ga));
}

// ---------- depthwise conv: sliding window, 16 outputs per thread ----------
__global__ __launch_bounds__(256) void dwconv_k(
    const u16* __restrict__ g, const float* __restrict__ w, const float* __restrict__ wb,
    const float* __restrict__ bng, const float* __restrict__ bnb, const float* __restrict__ bnm,
    const float* __restrict__ bnv, u16* __restrict__ out) {
    int idx = blockIdx.x * 256 + threadIdx.x;  // 262144 threads
    int c = idx & 511;
    int t = idx >> 9;
    int n = t & 15, l0 = (t >> 4) << 4;
    float win[46];
#pragma unroll
    for (int q = 0; q < 46; q++) {
        int ll = l0 - 15 + q;
        win[q] = (ll >= 0 && ll < 512) ? bf2f(g[((size_t)(ll * 16 + n) << 9) + c]) : 0.f;
    }
    float wgt[31];
#pragma unroll
    for (int k = 0; k < 31; k++) wgt[k] = w[c * 31 + k];
    float ivg = rsqrtf(bnv[c] + 1e-5f) * bng[c];
    float mc = bnm[c], bc = bnb[c], wbc = wb[c];
#pragma unroll
    for (int r = 0; r < 16; r++) {
        float acc = 0.f;
#pragma unroll
        for (int k = 0; k < 31; k++) acc += wgt[k] * win[r + k];
        acc += wbc;
        float y = (acc - mc) * ivg + bc;
        y = y * sigm(y);
        out[((size_t)((l0 + r) * 16 + n) << 9) + c] = f2bf(y);
    }
}

// ---------- launch ----------
extern "C" void kernel_launch(void* const* d_in, const int* in_sizes, int n_in,
                              void* d_out, int out_size, void* d_ws, size_t ws_size,
                              hipStream_t stream) {
    const float* src      = (const float*)d_in[0];
    const float* pos_emb  = (const float*)d_in[1];
    const float* ffm_w1   = (const float*)d_in[2];
    const float* ffm_b1   = (const float*)d_in[3];
    const float* ffm_w2   = (const float*)d_in[4];
    const float* ffm_b2   = (const float*)d_in[5];
    const float* ff_w1    = (const float*)d_in[6];
    const float* ff_b1    = (const float*)d_in[7];
    const float* ff_w2    = (const float*)d_in[8];
    const float* ff_b2    = (const float*)d_in[9];
    const float* in_w     = (const float*)d_in[10];
    const float* in_b     = (const float*)d_in[11];
    const float* out_w    = (const float*)d_in[12];
    const float* out_b    = (const float*)d_in[13];
    const float* pos_w    = (const float*)d_in[14];
    const float* bu       = (const float*)d_in[15];
    const float* bv       = (const float*)d_in[16];
    const float* pw1_w    = (const float*)d_in[17];
    const float* pw1_b    = (const float*)d_in[18];
    const float* dw_w     = (const float*)d_in[19];
    const float* dw_b     = (const float*)d_in[20];
    const float* bng      = (const float*)d_in[21];
    const float* bnb      = (const float*)d_in[22];
    const float* bnm      = (const float*)d_in[23];
    const float* bnv      = (const float*)d_in[24];
    const float* pw2_w    = (const float*)d_in[25];
    const float* pw2_b    = (const float*)d_in[26];
    const float* ln_ffm_g = (const float*)d_in[27];
    const float* ln_ffm_b = (const float*)d_in[28];
    const float* ln_mha_g = (const float*)d_in[29];
    const float* ln_mha_b = (const float*)d_in[30];
    const float* ln_cv_g  = (const float*)d_in[31];
    const float* ln_cv_b  = (const float*)d_in[32];
    const float* ln_ff_g  = (const float*)d_in[33];
    const float* ln_ff_b  = (const float*)d_in[34];
    const float* ln_fin_g = (const float*)d_in[35];
    const float* ln_fin_b = (const float*)d_in[36];
    (void)in_sizes; (void)n_in; (void)out_size; (void)ws_size;

    // ---- workspace layout in u16 units; total ~115.5 MiB ----
    const size_t MEG = 1048576;
    u16* U = (u16*)d_ws;
    float* xA = (float*)U;                // 8M u16; Pbf aliases during attention
    u16* Pbf = U;                         // 524288 u16 (8 x 1024 x 64); dead before xA written
    float* xB = (float*)(U + 8 * MEG);    // 8M
    u16* LNB = U + 16 * MEG;              // 4M
    u16* BIG = U + 20 * MEG;              // 16M: h1 / PB / qkv / pw1-out
    float* PB = (float*)BIG;              // 1023*512 fp32 (pre-qkv)
    u16* QU = U + 36 * MEG;               // 4M
    u16* QV = U + 40 * MEG;               // 4M
    u16* Kb = U + 44 * MEG;               // 4M
    u16* VT = U + 48 * MEG;               // 4M
    u16* WB = U + 52 * MEG;               // 6,029,312 weights bf16
    u16* w_ffm1 = WB;
    u16* w_ffm2 = WB + 1 * MEG;
    u16* w_ff1  = WB + 2 * MEG;
    u16* w_ff2  = WB + 3 * MEG;
    u16* w_in   = WB + 4 * MEG;
    u16* w_out  = WB + 4 * MEG + 786432;
    u16* w_pw1  = WB + 5 * MEG;
    u16* w_pw2  = WB + 5 * MEG + 524288;
    u16* CTX = LNB;
    u16* GLU = QU;
    u16* CACT = QV;

    // ---- cast all weights to bf16 (one dispatch) ----
    castall_k<<<23552, 256, 0, stream>>>(ffm_w1, ffm_w2, ff_w1, ff_w2, in_w, out_w,
                                         pw1_w, pw2_w, WB);

    // ---- FFN macaron: xB = src + 0.5*ffn(ln(src)) ----
    ln512_k<true><<<8192, 64, 0, stream>>>(src, ln_ffm_g, ln_ffm_b, LNB);
    mgemm_k<<<dim3(64, 16), 256, 0, stream>>>(LNB, w_ffm1, ffm_b1, nullptr, BIG,
                                              8192, 2048, 512, 0.f, 1, 1);
    mgemm_k<<<dim3(64, 4), 256, 0, stream>>>(BIG, w_ffm2, ffm_b2, src, xB,
                                             8192, 512, 2048, 0.5f, 0, 0);

    // ---- attention: xA = xB + attn(ln(xB)) ----
    ln512_k<true><<<8192, 64, 0, stream>>>(xB, ln_mha_g, ln_mha_b, LNB);
    gemm_f32_k<<<dim3(8, 16), 256, 0, stream>>>(pos_emb, pos_w, PB, 1023, 512, 512);
    pbcast_k<<<2046, 256, 0, stream>>>(PB, Pbf);
    mgemm_k<<<dim3(64, 12), 256, 0, stream>>>(LNB, w_in, in_b, nullptr, BIG,
                                              8192, 1536, 512, 0.f, 0, 1);
    repack_k<<<16384, 256, 0, stream>>>(BIG, bu, bv, QU, QV, Kb, VT);
    fattn_k<<<dim3(128, 32), 256, 0, stream>>>(QU, QV, Kb, Pbf, VT, CTX);
    mgemm_k<<<dim3(64, 4), 256, 0, stream>>>(CTX, w_out, out_b, xB, xA,
                                             8192, 512, 512, 1.f, 0, 0);

    // ---- conv module: xB = xA + conv(ln(xA)) ----
    ln512_k<true><<<8192, 64, 0, stream>>>(xA, ln_cv_g, ln_cv_b, LNB);
    mgemm_k<<<dim3(64, 8), 256, 0, stream>>>(LNB, w_pw1, pw1_b, nullptr, BIG,
                                             8192, 1024, 512, 0.f, 0, 1);
    glu_k<<<16384, 256, 0, stream>>>(BIG, GLU);
    dwconv_k<<<1024, 256, 0, stream>>>(GLU, dw_w, dw_b, bng, bnb, bnm, bnv, CACT);
    mgemm_k<<<dim3(64, 4), 256, 0, stream>>>(CACT, w_pw2, pw2_b, xA, xB,
                                             8192, 512, 512, 1.f, 0, 0);

    // ---- FFN 2: xA = xB + 0.5*ffn(ln(xB)) ----
    ln512_k<true><<<8192, 64, 0, stream>>>(xB, ln_ff_g, ln_ff_b, LNB);
    mgemm_k<<<dim3(64, 16), 256, 0, stream>>>(LNB, w_ff1, ff_b1, nullptr, BIG,
                                              8192, 2048, 512, 0.f, 1, 1);
    mgemm_k<<<dim3(64, 4), 256, 0, stream>>>(BIG, w_ff2, ff_b2, xB, xA,
                                             8192, 512, 2048, 0.5f, 0, 0);

    // ---- final LN -> fp32 out ----
    ln512_k<false><<<8192, 64, 0, stream>>>(xA, ln_fin_g, ln_fin_b, (float*)d_out);
}

// Round 10
// 649.606 us; speedup vs baseline: 5.7099x; 1.0270x over previous
//
#include <hip/hip_runtime.h>
#include <cstdint>
#include <cstddef>

typedef unsigned short u16;
typedef __attribute__((ext_vector_type(4))) float f32x4;
typedef __attribute__((ext_vector_type(8))) short bf16x8;

// ---------- helpers ----------
__device__ __forceinline__ float sigm(float x) { return 1.f / (1.f + __expf(-x)); }
__device__ __forceinline__ float bf2f(u16 u) {
    union { unsigned int i; float f; } c; c.i = ((unsigned int)u) << 16; return c.f;
}
__device__ __forceinline__ u16 f2bf(float f) {
    union { float f; unsigned int i; } c; c.f = f;
    unsigned int x = c.i;
    x += 0x7fffu + ((x >> 16) & 1u);
    return (u16)(x >> 16);
}

// dims: D=512, H=8, DH=64, F=2048, K=31, L=512, N=16, M=8192

// ---------- fused weight cast fp32 -> bf16 ----------
__global__ void castall_k(const float* __restrict__ s0, const float* __restrict__ s1,
                          const float* __restrict__ s2, const float* __restrict__ s3,
                          const float* __restrict__ s4, const float* __restrict__ s5,
                          const float* __restrict__ s6, const float* __restrict__ s7,
                          u16* __restrict__ dst) {
    int i = blockIdx.x * 256 + threadIdx.x;
    if (i >= 6029312) return;
    const float* s; int off;
    if      (i < 1048576) { s = s0; off = 0; }
    else if (i < 2097152) { s = s1; off = 1048576; }
    else if (i < 3145728) { s = s2; off = 2097152; }
    else if (i < 4194304) { s = s3; off = 3145728; }
    else if (i < 4980736) { s = s4; off = 4194304; }
    else if (i < 5242880) { s = s5; off = 4980736; }
    else if (i < 5767168) { s = s6; off = 5242880; }
    else                  { s = s7; off = 5767168; }
    dst[i] = f2bf(s[i - off]);
}

// ---------- LayerNorm over 512 (fp32 in), 4 rows per 256-thread block ----------
template <bool OUTBF>
__global__ __launch_bounds__(256) void ln512_k(const float* __restrict__ x,
                                               const float* __restrict__ g,
                                               const float* __restrict__ b,
                                               void* __restrict__ outv) {
    int row = blockIdx.x * 4 + (threadIdx.x >> 6);
    int lane = threadIdx.x & 63;
    const float* xr = x + (size_t)row * 512 + lane * 8;
    float4 v0 = *(const float4*)(xr);
    float4 v1 = *(const float4*)(xr + 4);
    float va[8] = {v0.x, v0.y, v0.z, v0.w, v1.x, v1.y, v1.z, v1.w};
    float s = 0.f;
#pragma unroll
    for (int t = 0; t < 8; t++) s += va[t];
#pragma unroll
    for (int o = 32; o > 0; o >>= 1) s += __shfl_xor(s, o);
    float m = s * (1.0f / 512.0f);
    float q = 0.f;
#pragma unroll
    for (int t = 0; t < 8; t++) { float d = va[t] - m; q += d * d; }
#pragma unroll
    for (int o = 32; o > 0; o >>= 1) q += __shfl_xor(q, o);
    float inv = rsqrtf(q * (1.0f / 512.0f) + 1e-5f);
    int cb = lane * 8;
    if (OUTBF) {
        u16* o = (u16*)outv + (size_t)row * 512 + cb;
#pragma unroll
        for (int t = 0; t < 8; t++)
            o[t] = f2bf((va[t] - m) * inv * g[cb + t] + b[cb + t]);
    } else {
        float* o = (float*)outv + (size_t)row * 512 + cb;
#pragma unroll
        for (int t = 0; t < 8; t++)
            o[t] = (va[t] - m) * inv * g[cb + t] + b[cb + t];
    }
}

// ---------- MFMA GEMM, 512 threads, in-block split-K=2 ----------
// waves 0-3 (half 0) do K[0,K/2), waves 4-7 (half 1) do K[K/2,K); LDS f32 reduce.
// C(M,N) = act(A(M,K)*B(N,K)^T + bias); C = add + coef*C. M%128==0, N%128==0, K%64==0.
__global__ __launch_bounds__(512) void mgemm_k(
    const u16* __restrict__ A, const u16* __restrict__ B, const float* __restrict__ bias,
    const float* __restrict__ add, void* __restrict__ Cv,
    int M, int Nn, int Kk, float coef, int act, int outbf) {
    __shared__ u16 lA[2][4096];  // per-half 128x32
    __shared__ u16 lB[2][4096];
    int tid = threadIdx.x;          // 0..511
    int half = tid >> 8;
    int t128 = tid & 255;
    int lane = tid & 63;
    int w = (tid >> 6) & 3;
    int wm = (w >> 1) * 64, wn = (w & 1) * 64;
    int m0 = blockIdx.x << 7, n0 = blockIdx.y << 7;
    int Kh = Kk >> 1;
    int kbase = half * Kh;

    f32x4 acc[4][4];
#pragma unroll
    for (int i = 0; i < 4; i++)
#pragma unroll
        for (int j = 0; j < 4; j++) acc[i][j] = (f32x4){0.f, 0.f, 0.f, 0.f};

    int srow = t128 >> 2;
    int scol = (t128 & 3) << 3;
    const u16* gA = A + (size_t)(m0 + srow) * Kk + kbase + scol;
    const u16* gB = B + (size_t)(n0 + srow) * Kk + kbase + scol;
    int lso = t128 * 8;

    int lra = wm * 32 + (lane & 15) * 32 + (lane >> 4) * 8;
    int lrb = wn * 32 + (lane & 15) * 32 + (lane >> 4) * 8;

    for (int k0 = 0; k0 < Kh; k0 += 32) {
        __builtin_amdgcn_global_load_lds(
            (const __attribute__((address_space(1))) void*)(gA + k0),
            (__attribute__((address_space(3))) void*)(lA[half] + lso), 16, 0, 0);
        __builtin_amdgcn_global_load_lds(
            (const __attribute__((address_space(1))) void*)(gA + (size_t)64 * Kk + k0),
            (__attribute__((address_space(3))) void*)(lA[half] + 2048 + lso), 16, 0, 0);
        __builtin_amdgcn_global_load_lds(
            (const __attribute__((address_space(1))) void*)(gB + k0),
            (__attribute__((address_space(3))) void*)(lB[half] + lso), 16, 0, 0);
        __builtin_amdgcn_global_load_lds(
            (const __attribute__((address_space(1))) void*)(gB + (size_t)64 * Kk + k0),
            (__attribute__((address_space(3))) void*)(lB[half] + 2048 + lso), 16, 0, 0);
        __syncthreads();
        bf16x8 af[4], bf[4];
#pragma unroll
        for (int t = 0; t < 4; t++) {
            af[t] = *(const bf16x8*)(lA[half] + lra + t * 512);
            bf[t] = *(const bf16x8*)(lB[half] + lrb + t * 512);
        }
#pragma unroll
        for (int i = 0; i < 4; i++)
#pragma unroll
            for (int j = 0; j < 4; j++)
                acc[i][j] = __builtin_amdgcn_mfma_f32_16x16x32_bf16(af[i], bf[j], acc[i][j], 0, 0, 0);
        __syncthreads();
    }

    // cross-half reduce through LDS (reuse lA as 4096-float buffer)
    float* red = (float*)lA;
#pragma unroll
    for (int rr = 0; rr < 4; rr++) {
        if (half == 1) {
#pragma unroll
            for (int j = 0; j < 4; j++)
                *(f32x4*)(red + ((w * 64 + lane) * 16 + j * 4)) = acc[rr][j];
        }
        __syncthreads();
        if (half == 0) {
#pragma unroll
            for (int j = 0; j < 4; j++) {
                f32x4 o = *(const f32x4*)(red + ((w * 64 + lane) * 16 + j * 4));
                acc[rr][j] += o;
            }
        }
        __syncthreads();
    }

    if (half == 0) {
        int rbase = (lane >> 4) * 4;
        int ncol = lane & 15;
#pragma unroll
        for (int i = 0; i < 4; i++) {
#pragma unroll
            for (int j = 0; j < 4; j++) {
                int n = n0 + wn + j * 16 + ncol;
                float bv = bias ? bias[n] : 0.f;
#pragma unroll
                for (int r = 0; r < 4; r++) {
                    int m = m0 + wm + i * 16 + rbase + r;
                    float c = acc[i][j][r] + bv;
                    if (act == 1) c *= sigm(c);
                    size_t o = (size_t)m * Nn + n;
                    if (add) c = add[o] + coef * c;
                    if (outbf) ((u16*)Cv)[o] = f2bf(c);
                    else ((float*)Cv)[o] = c;
                }
            }
        }
    }
}

// ---------- fused flash attention: scores + softmax + PV, one block = 16 q-rows x nh ----------
// grid (128 nh, 32 m): same-nh blocks share an XCD for K/V/P L2 locality.
__global__ __launch_bounds__(256) void fattn_k(
    const u16* __restrict__ QU, const u16* __restrict__ QV,
    const u16* __restrict__ Kb, const u16* __restrict__ Pbf,
    const u16* __restrict__ VT, u16* __restrict__ ctx) {
    __shared__ u16 arr[26496];  // 52,992 B
    u16* sB = arr;                        // [0,16896): P/K 528x32 staging (phases 1-2)
    u16* sV = arr;                        // [0,16384): V 64x256 staging (phase 5)
    u16* sRect = arr + 16896;             // [16896,25344): bd rect 16x528 (phases 1-3)
    u16* sP = arr + 16896;                // alias sRect: probs 16x520 (phases 4-5)
    u16* sQ = arr + 25344;                // [25344,26368): 16x64 (phases 1-2)
    u16* sCtx = arr + 25344;              // alias sQ: ctx tile 16x64 (phase 6)
    float* sRed = (float*)(arr + 26368);  // 16x4 floats

    int tid = threadIdx.x;
    int lane = tid & 63, w = tid >> 6;
    int quad = lane >> 4, col = lane & 15;
    int nh = blockIdx.x, h = nh & 7, nb = nh >> 3;
    int m0 = blockIdx.y << 4;
    int nlo = 496 - m0;  // bd rect covers P rows [nlo, nlo+528)

    // ---- phase 1: bd rect = QV_tile(16x64) . P[nlo..+528)^T ----
    if (tid < 128)
        __builtin_amdgcn_global_load_lds(
            (const __attribute__((address_space(1))) void*)(QV + (((size_t)nh * 512 + m0 + (tid >> 3)) << 6) + ((tid & 7) << 3)),
            (__attribute__((address_space(3))) void*)(sQ + tid * 8), 16, 0, 0);
    f32x4 bdacc[9];
#pragma unroll
    for (int i = 0; i < 9; i++) bdacc[i] = (f32x4){0.f, 0.f, 0.f, 0.f};
    const u16* Pb = Pbf + ((size_t)h << 16);
    for (int ks = 0; ks < 2; ks++) {
#pragma unroll
        for (int s = 0; s < 8; s++) {
            int row = (s << 6) + (tid >> 2);
            __builtin_amdgcn_global_load_lds(
                (const __attribute__((address_space(1))) void*)(Pb + (((size_t)(nlo + row)) << 6) + (ks << 5) + ((tid & 3) << 3)),
                (__attribute__((address_space(3))) void*)(sB + (s << 11) + tid * 8), 16, 0, 0);
        }
        if (tid < 64) {
            int row = 512 + (tid >> 2);
            __builtin_amdgcn_global_load_lds(
                (const __attribute__((address_space(1))) void*)(Pb + (((size_t)(nlo + row)) << 6) + (ks << 5) + ((tid & 3) << 3)),
                (__attribute__((address_space(3))) void*)(sB + (8 << 11) + tid * 8), 16, 0, 0);
        }
        __syncthreads();
        bf16x8 a = *(const bf16x8*)(sQ + col * 64 + (ks << 5) + quad * 8);
#pragma unroll
        for (int idx = 0; idx < 9; idx++) {
            int nt = w + (idx << 2);
            if (nt < 33) {
                bf16x8 b = *(const bf16x8*)(sB + ((nt * 16 + col) << 5) + quad * 8);
                bdacc[idx] = __builtin_amdgcn_mfma_f32_16x16x32_bf16(a, b, bdacc[idx], 0, 0, 0);
            }
        }
        __syncthreads();
    }
#pragma unroll
    for (int idx = 0; idx < 9; idx++) {
        int nt = w + (idx << 2);
        if (nt < 33) {
#pragma unroll
            for (int r = 0; r < 4; r++)
                sRect[(quad * 4 + r) * 528 + nt * 16 + col] = f2bf(bdacc[idx][r]);
        }
    }
    __syncthreads();

    // ---- phase 2: ac = QU_tile(16x64) . K^T ----
    if (tid < 128)
        __builtin_amdgcn_global_load_lds(
            (const __attribute__((address_space(1))) void*)(QU + (((size_t)nh * 512 + m0 + (tid >> 3)) << 6) + ((tid & 7) << 3)),
            (__attribute__((address_space(3))) void*)(sQ + tid * 8), 16, 0, 0);
    f32x4 ac[8];
#pragma unroll
    for (int i = 0; i < 8; i++) ac[i] = (f32x4){0.f, 0.f, 0.f, 0.f};
    const u16* Kz = Kb + ((size_t)nh << 15);
    for (int ks = 0; ks < 2; ks++) {
#pragma unroll
        for (int s = 0; s < 8; s++) {
            int row = (s << 6) + (tid >> 2);
            __builtin_amdgcn_global_load_lds(
                (const __attribute__((address_space(1))) void*)(Kz + ((size_t)row << 6) + (ks << 5) + ((tid & 3) << 3)),
                (__attribute__((address_space(3))) void*)(sB + (s << 11) + tid * 8), 16, 0, 0);
        }
        __syncthreads();
        bf16x8 a = *(const bf16x8*)(sQ + col * 64 + (ks << 5) + quad * 8);
#pragma unroll
        for (int jt = 0; jt < 8; jt++) {
            bf16x8 b = *(const bf16x8*)(sB + (((w << 7) + jt * 16 + col) << 5) + quad * 8);
            ac[jt] = __builtin_amdgcn_mfma_f32_16x16x32_bf16(a, b, ac[jt], 0, 0, 0);
        }
        __syncthreads();
    }

    // ---- phase 3: shifted add + scale + softmax over j ----
    float rmax[4];
#pragma unroll
    for (int r = 0; r < 4; r++) rmax[r] = -1e30f;
#pragma unroll
    for (int jt = 0; jt < 8; jt++) {
        int j = (w << 7) + jt * 16 + col;
#pragma unroll
        for (int r = 0; r < 4; r++) {
            int ml = quad * 4 + r;
            float v = (ac[jt][r] + bf2f(sRect[ml * 528 + (j - ml + 15)])) * 0.125f;
            ac[jt][r] = v;
            rmax[r] = fmaxf(rmax[r], v);
        }
    }
#pragma unroll
    for (int o = 1; o <= 8; o <<= 1)
#pragma unroll
        for (int r = 0; r < 4; r++) rmax[r] = fmaxf(rmax[r], __shfl_xor(rmax[r], o));
    if (col == 0)
#pragma unroll
        for (int r = 0; r < 4; r++) sRed[(quad * 4 + r) * 4 + w] = rmax[r];
    __syncthreads();
    float gmax[4], psum[4];
#pragma unroll
    for (int r = 0; r < 4; r++) {
        int ml = quad * 4 + r;
        gmax[r] = fmaxf(fmaxf(sRed[ml * 4 + 0], sRed[ml * 4 + 1]),
                        fmaxf(sRed[ml * 4 + 2], sRed[ml * 4 + 3]));
        psum[r] = 0.f;
    }
    __syncthreads();
#pragma unroll
    for (int jt = 0; jt < 8; jt++)
#pragma unroll
        for (int r = 0; r < 4; r++) {
            float e = __expf(ac[jt][r] - gmax[r]);
            ac[jt][r] = e;
            psum[r] += e;
        }
#pragma unroll
    for (int o = 1; o <= 8; o <<= 1)
#pragma unroll
        for (int r = 0; r < 4; r++) psum[r] += __shfl_xor(psum[r], o);
    if (col == 0)
#pragma unroll
        for (int r = 0; r < 4; r++) sRed[(quad * 4 + r) * 4 + w] = psum[r];
    __syncthreads();
    float rinv[4];
#pragma unroll
    for (int r = 0; r < 4; r++) {
        int ml = quad * 4 + r;
        rinv[r] = 1.f / (sRed[ml * 4 + 0] + sRed[ml * 4 + 1] + sRed[ml * 4 + 2] + sRed[ml * 4 + 3]);
    }

    // ---- phase 4: probs -> sP (bf16, stride 520, aliases dead sRect) ----
    // sRect reads finished in phase 3 (>=2 barriers ago); all waves past them.
#pragma unroll
    for (int jt = 0; jt < 8; jt++) {
        int j = (w << 7) + jt * 16 + col;
#pragma unroll
        for (int r = 0; r < 4; r++)
            sP[(quad * 4 + r) * 520 + j] = f2bf(ac[jt][r] * rinv[r]);
    }

    // ---- phase 5: ctx_tile(16x64) = P(16x512) . V^T; V staged 64x256 per chunk ----
    // global-side XOR swizzle (chunk ^ d&7) keeps lane-order LDS writes conflict-free.
    const u16* Vz = VT + ((size_t)nh << 15);
    f32x4 cacc = (f32x4){0.f, 0.f, 0.f, 0.f};
    for (int kc = 0; kc < 2; kc++) {
#pragma unroll
        for (int s = 0; s < 8; s++) {
            int d = (s << 3) + (tid >> 5);
            int chunk = (tid & 31) ^ (d & 7);
            __builtin_amdgcn_global_load_lds(
                (const __attribute__((address_space(1))) void*)(Vz + ((size_t)d << 9) + (kc << 8) + (chunk << 3)),
                (__attribute__((address_space(3))) void*)(sV + (s << 11) + tid * 8), 16, 0, 0);
        }
        __syncthreads();  // also covers phase-4 sP writes on first pass
#pragma unroll
        for (int s2 = 0; s2 < 8; s2++) {
            bf16x8 a = *(const bf16x8*)(sP + col * 520 + (kc << 8) + (s2 << 5) + quad * 8);
            int row = (w << 4) + col;
            int ch = ((s2 << 2) + quad) ^ (col & 7);
            bf16x8 b = *(const bf16x8*)(sV + (row << 8) + (ch << 3));
            cacc = __builtin_amdgcn_mfma_f32_16x16x32_bf16(a, b, cacc, 0, 0, 0);
        }
        __syncthreads();
    }

    // ---- phase 6: ctx tile -> LDS (aliases dead sQ) -> coalesced 16B stores ----
#pragma unroll
    for (int r = 0; r < 4; r++)
        sCtx[(quad * 4 + r) * 64 + (w << 4) + col] = f2bf(cacc[r]);
    __syncthreads();
    if (tid < 128) {
        int row = tid >> 3, seg = tid & 7;
        u16* dst = ctx + (((size_t)((m0 + row) * 16 + nb)) << 9) + (h << 6) + seg * 8;
        *(uint4*)dst = *(const uint4*)(sCtx + row * 64 + seg * 8);
    }
}

// ---------- fp32 GEMM (pos projection, M=1023): C = A*B^T ----------
__global__ __launch_bounds__(256) void gemm_f32_k(
    const float* __restrict__ A, const float* __restrict__ B, float* __restrict__ C,
    int M, int Nn, int Kk) {
    __shared__ float As[16][64];
    __shared__ float Bs[16][64];
    int tid = threadIdx.x;
    int tx = tid & 15, ty = tid >> 4;
    int m0 = blockIdx.y << 6, n0 = blockIdx.x << 6;
    int arow = tid >> 2, acol = (tid & 3) << 2;
    float acc[4][4] = {};
    for (int k0 = 0; k0 < Kk; k0 += 16) {
        int gr = m0 + arow;
        float4 av = make_float4(0.f, 0.f, 0.f, 0.f);
        if (gr < M) av = *(const float4*)(A + (size_t)gr * Kk + k0 + acol);
        As[acol + 0][arow] = av.x; As[acol + 1][arow] = av.y;
        As[acol + 2][arow] = av.z; As[acol + 3][arow] = av.w;
        float4 bv = *(const float4*)(B + (size_t)(n0 + arow) * Kk + k0 + acol);
        Bs[acol + 0][arow] = bv.x; Bs[acol + 1][arow] = bv.y;
        Bs[acol + 2][arow] = bv.z; Bs[acol + 3][arow] = bv.w;
        __syncthreads();
#pragma unroll
        for (int kk = 0; kk < 16; kk++) {
            float4 a4 = *(const float4*)&As[kk][ty << 2];
            float4 b4 = *(const float4*)&Bs[kk][tx << 2];
            float ar[4] = {a4.x, a4.y, a4.z, a4.w};
            float br[4] = {b4.x, b4.y, b4.z, b4.w};
#pragma unroll
            for (int i = 0; i < 4; i++)
#pragma unroll
                for (int j = 0; j < 4; j++) acc[i][j] += ar[i] * br[j];
        }
        __syncthreads();
    }
#pragma unroll
    for (int i = 0; i < 4; i++) {
        int gr = m0 + (ty << 2) + i;
        if (gr >= M) continue;
#pragma unroll
        for (int j = 0; j < 4; j++)
            C[(size_t)gr * Nn + n0 + (tx << 2) + j] = acc[i][j];
    }
}

// ---------- cast/reshape PB (1023,512) fp32 -> Pbf (h,1024,64) bf16 ----------
__global__ void pbcast_k(const float* __restrict__ pb, u16* __restrict__ pbbf) {
    int idx = blockIdx.x * 256 + threadIdx.x;
    if (idx >= 1023 * 512) return;
    int m = idx >> 9, c = idx & 511, h = c >> 6, d = c & 63;
    pbbf[((size_t)(h * 1024 + m) << 6) + d] = f2bf(pb[idx]);
}

// ---------- repack qkv (M,1536) bf16 -> QU/QV (nh,512,64)+bias, K (nh,512,64), VT (nh,64,512) ----------
__global__ void repack_k(const u16* __restrict__ qkv, const float* __restrict__ bu,
                         const float* __restrict__ bv, u16* __restrict__ QU,
                         u16* __restrict__ QV, u16* __restrict__ Kb, u16* __restrict__ VT) {
    int e = blockIdx.x * 256 + threadIdx.x;  // M*512
    int c = e & 511, t = e >> 9;
    int l = t >> 4, n = t & 15, h = c >> 6, d = c & 63;
    size_t base = (size_t)t * 1536 + c;
    float q = bf2f(qkv[base]);
    u16 k = qkv[base + 512], v = qkv[base + 1024];
    int nh = n * 8 + h;
    size_t o = ((size_t)nh * 512 + l) * 64 + d;
    QU[o] = f2bf(q + bu[h * 64 + d]);
    QV[o] = f2bf(q + bv[h * 64 + d]);
    Kb[o] = k;
    VT[((size_t)nh * 64 + d) * 512 + l] = v;
}

// ---------- GLU: (M,1024) bf16 -> (M,512) bf16 ----------
__global__ void glu_k(const u16* __restrict__ pw1o, u16* __restrict__ g) {
    int e = blockIdx.x * 256 + threadIdx.x;  // M*512
    int t = e >> 9, c = e & 511;
    float a = bf2f(pw1o[(size_t)t * 1024 + c]);
    float ga = bf2f(pw1o[(size_t)t * 1024 + 512 + c]);
    g[e] = f2bf(a * sigm(ga));
}

// ---------- depthwise conv: sliding window, 16 outputs per thread ----------
__global__ __launch_bounds__(256) void dwconv_k(
    const u16* __restrict__ g, const float* __restrict__ w, const float* __restrict__ wb,
    const float* __restrict__ bng, const float* __restrict__ bnb, const float* __restrict__ bnm,
    const float* __restrict__ bnv, u16* __restrict__ out) {
    int idx = blockIdx.x * 256 + threadIdx.x;  // 262144 threads
    int c = idx & 511;
    int t = idx >> 9;
    int n = t & 15, l0 = (t >> 4) << 4;
    float win[46];
#pragma unroll
    for (int q = 0; q < 46; q++) {
        int ll = l0 - 15 + q;
        win[q] = (ll >= 0 && ll < 512) ? bf2f(g[((size_t)(ll * 16 + n) << 9) + c]) : 0.f;
    }
    float wgt[31];
#pragma unroll
    for (int k = 0; k < 31; k++) wgt[k] = w[c * 31 + k];
    float ivg = rsqrtf(bnv[c] + 1e-5f) * bng[c];
    float mc = bnm[c], bc = bnb[c], wbc = wb[c];
#pragma unroll
    for (int r = 0; r < 16; r++) {
        float acc = 0.f;
#pragma unroll
        for (int k = 0; k < 31; k++) acc += wgt[k] * win[r + k];
        acc += wbc;
        float y = (acc - mc) * ivg + bc;
        y = y * sigm(y);
        out[((size_t)((l0 + r) * 16 + n) << 9) + c] = f2bf(y);
    }
}

// ---------- launch ----------
extern "C" void kernel_launch(void* const* d_in, const int* in_sizes, int n_in,
                              void* d_out, int out_size, void* d_ws, size_t ws_size,
                              hipStream_t stream) {
    const float* src      = (const float*)d_in[0];
    const float* pos_emb  = (const float*)d_in[1];
    const float* ffm_w1   = (const float*)d_in[2];
    const float* ffm_b1   = (const float*)d_in[3];
    const float* ffm_w2   = (const float*)d_in[4];
    const float* ffm_b2   = (const float*)d_in[5];
    const float* ff_w1    = (const float*)d_in[6];
    const float* ff_b1    = (const float*)d_in[7];
    const float* ff_w2    = (const float*)d_in[8];
    const float* ff_b2    = (const float*)d_in[9];
    const float* in_w     = (const float*)d_in[10];
    const float* in_b     = (const float*)d_in[11];
    const float* out_w    = (const float*)d_in[12];
    const float* out_b    = (const float*)d_in[13];
    const float* pos_w    = (const float*)d_in[14];
    const float* bu       = (const float*)d_in[15];
    const float* bv       = (const float*)d_in[16];
    const float* pw1_w    = (const float*)d_in[17];
    const float* pw1_b    = (const float*)d_in[18];
    const float* dw_w     = (const float*)d_in[19];
    const float* dw_b     = (const float*)d_in[20];
    const float* bng      = (const float*)d_in[21];
    const float* bnb      = (const float*)d_in[22];
    const float* bnm      = (const float*)d_in[23];
    const float* bnv      = (const float*)d_in[24];
    const float* pw2_w    = (const float*)d_in[25];
    const float* pw2_b    = (const float*)d_in[26];
    const float* ln_ffm_g = (const float*)d_in[27];
    const float* ln_ffm_b = (const float*)d_in[28];
    const float* ln_mha_g = (const float*)d_in[29];
    const float* ln_mha_b = (const float*)d_in[30];
    const float* ln_cv_g  = (const float*)d_in[31];
    const float* ln_cv_b  = (const float*)d_in[32];
    const float* ln_ff_g  = (const float*)d_in[33];
    const float* ln_ff_b  = (const float*)d_in[34];
    const float* ln_fin_g = (const float*)d_in[35];
    const float* ln_fin_b = (const float*)d_in[36];
    (void)in_sizes; (void)n_in; (void)out_size; (void)ws_size;

    // ---- workspace layout in u16 units; total ~115.5 MiB ----
    const size_t MEG = 1048576;
    u16* U = (u16*)d_ws;
    float* xA = (float*)U;                // 8M u16; Pbf aliases during attention
    u16* Pbf = U;                         // 524288 u16 (8 x 1024 x 64); dead before xA written
    float* xB = (float*)(U + 8 * MEG);    // 8M
    u16* LNB = U + 16 * MEG;              // 4M
    u16* BIG = U + 20 * MEG;              // 16M: h1 / PB / qkv / pw1-out
    float* PB = (float*)BIG;              // 1023*512 fp32 (pre-qkv)
    u16* QU = U + 36 * MEG;               // 4M
    u16* QV = U + 40 * MEG;               // 4M
    u16* Kb = U + 44 * MEG;               // 4M
    u16* VT = U + 48 * MEG;               // 4M
    u16* WB = U + 52 * MEG;               // 6,029,312 weights bf16
    u16* w_ffm1 = WB;
    u16* w_ffm2 = WB + 1 * MEG;
    u16* w_ff1  = WB + 2 * MEG;
    u16* w_ff2  = WB + 3 * MEG;
    u16* w_in   = WB + 4 * MEG;
    u16* w_out  = WB + 4 * MEG + 786432;
    u16* w_pw1  = WB + 5 * MEG;
    u16* w_pw2  = WB + 5 * MEG + 524288;
    u16* CTX = LNB;
    u16* GLU = QU;
    u16* CACT = QV;

    // ---- cast all weights to bf16 (one dispatch) ----
    castall_k<<<23552, 256, 0, stream>>>(ffm_w1, ffm_w2, ff_w1, ff_w2, in_w, out_w,
                                         pw1_w, pw2_w, WB);

    // ---- FFN macaron: xB = src + 0.5*ffn(ln(src)) ----
    ln512_k<true><<<2048, 256, 0, stream>>>(src, ln_ffm_g, ln_ffm_b, LNB);
    mgemm_k<<<dim3(64, 16), 512, 0, stream>>>(LNB, w_ffm1, ffm_b1, nullptr, BIG,
                                              8192, 2048, 512, 0.f, 1, 1);
    mgemm_k<<<dim3(64, 4), 512, 0, stream>>>(BIG, w_ffm2, ffm_b2, src, xB,
                                             8192, 512, 2048, 0.5f, 0, 0);

    // ---- attention: xA = xB + attn(ln(xB)) ----
    ln512_k<true><<<2048, 256, 0, stream>>>(xB, ln_mha_g, ln_mha_b, LNB);
    gemm_f32_k<<<dim3(8, 16), 256, 0, stream>>>(pos_emb, pos_w, PB, 1023, 512, 512);
    pbcast_k<<<2046, 256, 0, stream>>>(PB, Pbf);
    mgemm_k<<<dim3(64, 12), 512, 0, stream>>>(LNB, w_in, in_b, nullptr, BIG,
                                              8192, 1536, 512, 0.f, 0, 1);
    repack_k<<<16384, 256, 0, stream>>>(BIG, bu, bv, QU, QV, Kb, VT);
    fattn_k<<<dim3(128, 32), 256, 0, stream>>>(QU, QV, Kb, Pbf, VT, CTX);
    mgemm_k<<<dim3(64, 4), 512, 0, stream>>>(CTX, w_out, out_b, xB, xA,
                                             8192, 512, 512, 1.f, 0, 0);

    // ---- conv module: xB = xA + conv(ln(xA)) ----
    ln512_k<true><<<2048, 256, 0, stream>>>(xA, ln_cv_g, ln_cv_b, LNB);
    mgemm_k<<<dim3(64, 8), 512, 0, stream>>>(LNB, w_pw1, pw1_b, nullptr, BIG,
                                             8192, 1024, 512, 0.f, 0, 1);
    glu_k<<<16384, 256, 0, stream>>>(BIG, GLU);
    dwconv_k<<<1024, 256, 0, stream>>>(GLU, dw_w, dw_b, bng, bnb, bnm, bnv, CACT);
    mgemm_k<<<dim3(64, 4), 512, 0, stream>>>(CACT, w_pw2, pw2_b, xA, xB,
                                             8192, 512, 512, 1.f, 0, 0);

    // ---- FFN 2: xA = xB + 0.5*ffn(ln(xB)) ----
    ln512_k<true><<<2048, 256, 0, stream>>>(xB, ln_ff_g, ln_ff_b, LNB);
    mgemm_k<<<dim3(64, 16), 512, 0, stream>>>(LNB, w_ff1, ff_b1, nullptr, BIG,
                                              8192, 2048, 512, 0.f, 1, 1);
    mgemm_k<<<dim3(64, 4), 512, 0, stream>>>(BIG, w_ff2, ff_b2, xB, xA,
                                             8192, 512, 2048, 0.5f, 0, 0);

    // ---- final LN -> fp32 out ----
    ln512_k<false><<<2048, 256, 0, stream>>>(xA, ln_fin_g, ln_fin_b, (float*)d_out);
}

// Round 11
// 621.128 us; speedup vs baseline: 5.9716x; 1.0458x over previous
//
#include <hip/hip_runtime.h>
#include <cstdint>
#include <cstddef>

typedef unsigned short u16;
typedef __attribute__((ext_vector_type(4))) float f32x4;
typedef __attribute__((ext_vector_type(8))) short bf16x8;
typedef __attribute__((ext_vector_type(8))) unsigned short u16x8;

// ---------- helpers ----------
__device__ __forceinline__ float sigm(float x) { return 1.f / (1.f + __expf(-x)); }
__device__ __forceinline__ float bf2f(u16 u) {
    union { unsigned int i; float f; } c; c.i = ((unsigned int)u) << 16; return c.f;
}
__device__ __forceinline__ u16 f2bf(float f) {
    union { float f; unsigned int i; } c; c.f = f;
    unsigned int x = c.i;
    x += 0x7fffu + ((x >> 16) & 1u);
    return (u16)(x >> 16);
}

// dims: D=512, H=8, DH=64, F=2048, K=31, L=512, N=16, M=8192

// ---------- fused weight cast fp32 -> bf16 (10 arrays incl. pos_w, pos_emb) ----------
__global__ void castall_k(const float* __restrict__ s0, const float* __restrict__ s1,
                          const float* __restrict__ s2, const float* __restrict__ s3,
                          const float* __restrict__ s4, const float* __restrict__ s5,
                          const float* __restrict__ s6, const float* __restrict__ s7,
                          const float* __restrict__ s8, const float* __restrict__ s9,
                          u16* __restrict__ dst) {
    int i = blockIdx.x * 256 + threadIdx.x;
    if (i >= 6815232) return;
    const float* s; int off;
    if      (i < 1048576) { s = s0; off = 0; }
    else if (i < 2097152) { s = s1; off = 1048576; }
    else if (i < 3145728) { s = s2; off = 2097152; }
    else if (i < 4194304) { s = s3; off = 3145728; }
    else if (i < 4980736) { s = s4; off = 4194304; }
    else if (i < 5242880) { s = s5; off = 4980736; }
    else if (i < 5767168) { s = s6; off = 5242880; }
    else if (i < 6029312) { s = s7; off = 5767168; }
    else if (i < 6291456) { s = s8; off = 6029312; }
    else                  { s = s9; off = 6291456; }
    dst[i] = f2bf(s[i - off]);
}

// ---------- LayerNorm over 512 (fp32 in), 4 rows per 256-thread block ----------
template <bool OUTBF>
__global__ __launch_bounds__(256) void ln512_k(const float* __restrict__ x,
                                               const float* __restrict__ g,
                                               const float* __restrict__ b,
                                               void* __restrict__ outv) {
    int row = blockIdx.x * 4 + (threadIdx.x >> 6);
    int lane = threadIdx.x & 63;
    const float* xr = x + (size_t)row * 512 + lane * 8;
    float4 v0 = *(const float4*)(xr);
    float4 v1 = *(const float4*)(xr + 4);
    float va[8] = {v0.x, v0.y, v0.z, v0.w, v1.x, v1.y, v1.z, v1.w};
    float s = 0.f;
#pragma unroll
    for (int t = 0; t < 8; t++) s += va[t];
#pragma unroll
    for (int o = 32; o > 0; o >>= 1) s += __shfl_xor(s, o);
    float m = s * (1.0f / 512.0f);
    float q = 0.f;
#pragma unroll
    for (int t = 0; t < 8; t++) { float d = va[t] - m; q += d * d; }
#pragma unroll
    for (int o = 32; o > 0; o >>= 1) q += __shfl_xor(q, o);
    float inv = rsqrtf(q * (1.0f / 512.0f) + 1e-5f);
    int cb = lane * 8;
    if (OUTBF) {
        u16* o = (u16*)outv + (size_t)row * 512 + cb;
#pragma unroll
        for (int t = 0; t < 8; t++)
            o[t] = f2bf((va[t] - m) * inv * g[cb + t] + b[cb + t]);
    } else {
        float* o = (float*)outv + (size_t)row * 512 + cb;
#pragma unroll
        for (int t = 0; t < 8; t++)
            o[t] = (va[t] - m) * inv * g[cb + t] + b[cb + t];
    }
}

// ---------- MFMA GEMM, 512 threads, in-block split-K=2 ----------
__global__ __launch_bounds__(512) void mgemm_k(
    const u16* __restrict__ A, const u16* __restrict__ B, const float* __restrict__ bias,
    const float* __restrict__ add, void* __restrict__ Cv,
    int M, int Nn, int Kk, float coef, int act, int outbf) {
    __shared__ u16 lA[2][4096];
    __shared__ u16 lB[2][4096];
    int tid = threadIdx.x;
    int half = tid >> 8;
    int t128 = tid & 255;
    int lane = tid & 63;
    int w = (tid >> 6) & 3;
    int wm = (w >> 1) * 64, wn = (w & 1) * 64;
    int m0 = blockIdx.x << 7, n0 = blockIdx.y << 7;
    int Kh = Kk >> 1;
    int kbase = half * Kh;

    f32x4 acc[4][4];
#pragma unroll
    for (int i = 0; i < 4; i++)
#pragma unroll
        for (int j = 0; j < 4; j++) acc[i][j] = (f32x4){0.f, 0.f, 0.f, 0.f};

    int srow = t128 >> 2;
    int scol = (t128 & 3) << 3;
    const u16* gA = A + (size_t)(m0 + srow) * Kk + kbase + scol;
    const u16* gB = B + (size_t)(n0 + srow) * Kk + kbase + scol;
    int lso = t128 * 8;

    int lra = wm * 32 + (lane & 15) * 32 + (lane >> 4) * 8;
    int lrb = wn * 32 + (lane & 15) * 32 + (lane >> 4) * 8;

    for (int k0 = 0; k0 < Kh; k0 += 32) {
        __builtin_amdgcn_global_load_lds(
            (const __attribute__((address_space(1))) void*)(gA + k0),
            (__attribute__((address_space(3))) void*)(lA[half] + lso), 16, 0, 0);
        __builtin_amdgcn_global_load_lds(
            (const __attribute__((address_space(1))) void*)(gA + (size_t)64 * Kk + k0),
            (__attribute__((address_space(3))) void*)(lA[half] + 2048 + lso), 16, 0, 0);
        __builtin_amdgcn_global_load_lds(
            (const __attribute__((address_space(1))) void*)(gB + k0),
            (__attribute__((address_space(3))) void*)(lB[half] + lso), 16, 0, 0);
        __builtin_amdgcn_global_load_lds(
            (const __attribute__((address_space(1))) void*)(gB + (size_t)64 * Kk + k0),
            (__attribute__((address_space(3))) void*)(lB[half] + 2048 + lso), 16, 0, 0);
        __syncthreads();
        bf16x8 af[4], bf[4];
#pragma unroll
        for (int t = 0; t < 4; t++) {
            af[t] = *(const bf16x8*)(lA[half] + lra + t * 512);
            bf[t] = *(const bf16x8*)(lB[half] + lrb + t * 512);
        }
#pragma unroll
        for (int i = 0; i < 4; i++)
#pragma unroll
            for (int j = 0; j < 4; j++)
                acc[i][j] = __builtin_amdgcn_mfma_f32_16x16x32_bf16(af[i], bf[j], acc[i][j], 0, 0, 0);
        __syncthreads();
    }

    float* red = (float*)lA;
#pragma unroll
    for (int rr = 0; rr < 4; rr++) {
        if (half == 1) {
#pragma unroll
            for (int j = 0; j < 4; j++)
                *(f32x4*)(red + ((w * 64 + lane) * 16 + j * 4)) = acc[rr][j];
        }
        __syncthreads();
        if (half == 0) {
#pragma unroll
            for (int j = 0; j < 4; j++) {
                f32x4 o = *(const f32x4*)(red + ((w * 64 + lane) * 16 + j * 4));
                acc[rr][j] += o;
            }
        }
        __syncthreads();
    }

    if (half == 0) {
        int rbase = (lane >> 4) * 4;
        int ncol = lane & 15;
#pragma unroll
        for (int i = 0; i < 4; i++) {
#pragma unroll
            for (int j = 0; j < 4; j++) {
                int n = n0 + wn + j * 16 + ncol;
                float bv = bias ? bias[n] : 0.f;
#pragma unroll
                for (int r = 0; r < 4; r++) {
                    int m = m0 + wm + i * 16 + rbase + r;
                    float c = acc[i][j][r] + bv;
                    if (act == 1) c *= sigm(c);
                    size_t o = (size_t)m * Nn + n;
                    if (add) c = add[o] + coef * c;
                    if (outbf) ((u16*)Cv)[o] = f2bf(c);
                    else ((float*)Cv)[o] = c;
                }
            }
        }
    }
}

// ---------- pos GEMM (bf16): Pbf[h][m][d] = pos_emb(1023x512) @ pos_w(512x512)^T ----------
// 256 threads, 128x128 tile, grid (8 m, 4 n). A rows clamped at 1022; m=1023 -> 0.
__global__ __launch_bounds__(256) void posb_k(const u16* __restrict__ A,
                                              const u16* __restrict__ B,
                                              u16* __restrict__ Pbf) {
    __shared__ u16 lA[4096];
    __shared__ u16 lB[4096];
    const int Kk = 512;
    int tid = threadIdx.x;
    int lane = tid & 63, w = tid >> 6;
    int wm = (w >> 1) * 64, wn = (w & 1) * 64;
    int m0 = blockIdx.x << 7, n0 = blockIdx.y << 7;

    f32x4 acc[4][4];
#pragma unroll
    for (int i = 0; i < 4; i++)
#pragma unroll
        for (int j = 0; j < 4; j++) acc[i][j] = (f32x4){0.f, 0.f, 0.f, 0.f};

    int srow = tid >> 2;
    int scol = (tid & 3) << 3;
    int ar0 = m0 + srow;       if (ar0 > 1022) ar0 = 1022;
    int ar1 = m0 + 64 + srow;  if (ar1 > 1022) ar1 = 1022;
    const u16* gA0 = A + (size_t)ar0 * Kk + scol;
    const u16* gA1 = A + (size_t)ar1 * Kk + scol;
    const u16* gB = B + (size_t)(n0 + srow) * Kk + scol;
    int lso = tid * 8;
    int lra = wm * 32 + (lane & 15) * 32 + (lane >> 4) * 8;
    int lrb = wn * 32 + (lane & 15) * 32 + (lane >> 4) * 8;

    for (int k0 = 0; k0 < Kk; k0 += 32) {
        __builtin_amdgcn_global_load_lds(
            (const __attribute__((address_space(1))) void*)(gA0 + k0),
            (__attribute__((address_space(3))) void*)(lA + lso), 16, 0, 0);
        __builtin_amdgcn_global_load_lds(
            (const __attribute__((address_space(1))) void*)(gA1 + k0),
            (__attribute__((address_space(3))) void*)(lA + 2048 + lso), 16, 0, 0);
        __builtin_amdgcn_global_load_lds(
            (const __attribute__((address_space(1))) void*)(gB + k0),
            (__attribute__((address_space(3))) void*)(lB + lso), 16, 0, 0);
        __builtin_amdgcn_global_load_lds(
            (const __attribute__((address_space(1))) void*)(gB + (size_t)64 * Kk + k0),
            (__attribute__((address_space(3))) void*)(lB + 2048 + lso), 16, 0, 0);
        __syncthreads();
        bf16x8 af[4], bf[4];
#pragma unroll
        for (int t = 0; t < 4; t++) {
            af[t] = *(const bf16x8*)(lA + lra + t * 512);
            bf[t] = *(const bf16x8*)(lB + lrb + t * 512);
        }
#pragma unroll
        for (int i = 0; i < 4; i++)
#pragma unroll
            for (int j = 0; j < 4; j++)
                acc[i][j] = __builtin_amdgcn_mfma_f32_16x16x32_bf16(af[i], bf[j], acc[i][j], 0, 0, 0);
        __syncthreads();
    }

    int rbase = (lane >> 4) * 4;
    int ncol = lane & 15;
#pragma unroll
    for (int i = 0; i < 4; i++) {
#pragma unroll
        for (int j = 0; j < 4; j++) {
            int n = n0 + wn + j * 16 + ncol;
            int h = n >> 6, d = n & 63;
#pragma unroll
            for (int r = 0; r < 4; r++) {
                int m = m0 + wm + i * 16 + rbase + r;
                u16 val = (m < 1023) ? f2bf(acc[i][j][r]) : (u16)0;
                Pbf[(((size_t)(h * 1024 + m)) << 6) + d] = val;
            }
        }
    }
}

// ---------- fused flash attention: scores + softmax + PV, one block = 16 q-rows x nh ----------
__global__ __launch_bounds__(256) void fattn_k(
    const u16* __restrict__ QU, const u16* __restrict__ QV,
    const u16* __restrict__ Kb, const u16* __restrict__ Pbf,
    const u16* __restrict__ VT, u16* __restrict__ ctx) {
    __shared__ u16 arr[26496];  // 52,992 B
    u16* sB = arr;                        // [0,16896): P/K 528x32 staging; V 64x256 (ph5)
    u16* sV = arr;
    u16* sRect = arr + 16896;             // bd SHIFTED: 16 rows x stride 524 (scalar access)
    u16* sP = arr + 16896;                // alias: probs 16 x stride 520 (b128 access)
    u16* sQ = arr + 25344;                // 16 x 64
    u16* sCtx = arr + 25344;              // alias sQ (phase 6)
    float* sRed = (float*)(arr + 26368);  // 16 x 4 floats

    int tid = threadIdx.x;
    int lane = tid & 63, w = tid >> 6;
    int quad = lane >> 4, col = lane & 15;
    int nh = blockIdx.x, h = nh & 7, nb = nh >> 3;
    int m0 = blockIdx.y << 4;
    int nlo = 496 - m0;

    // ---- phase 1: bd = QV_tile(16x64) . P[nlo..+528)^T, stored pre-shifted ----
    if (tid < 128)
        __builtin_amdgcn_global_load_lds(
            (const __attribute__((address_space(1))) void*)(QV + (((size_t)nh * 512 + m0 + (tid >> 3)) << 6) + ((tid & 7) << 3)),
            (__attribute__((address_space(3))) void*)(sQ + tid * 8), 16, 0, 0);
    f32x4 bdacc[9];
#pragma unroll
    for (int i = 0; i < 9; i++) bdacc[i] = (f32x4){0.f, 0.f, 0.f, 0.f};
    const u16* Pb = Pbf + ((size_t)h << 16);
    for (int ks = 0; ks < 2; ks++) {
#pragma unroll
        for (int s = 0; s < 8; s++) {
            int row = (s << 6) + (tid >> 2);
            __builtin_amdgcn_global_load_lds(
                (const __attribute__((address_space(1))) void*)(Pb + (((size_t)(nlo + row)) << 6) + (ks << 5) + ((tid & 3) << 3)),
                (__attribute__((address_space(3))) void*)(sB + (s << 11) + tid * 8), 16, 0, 0);
        }
        if (tid < 64) {
            int row = 512 + (tid >> 2);
            __builtin_amdgcn_global_load_lds(
                (const __attribute__((address_space(1))) void*)(Pb + (((size_t)(nlo + row)) << 6) + (ks << 5) + ((tid & 3) << 3)),
                (__attribute__((address_space(3))) void*)(sB + (8 << 11) + tid * 8), 16, 0, 0);
        }
        __syncthreads();
        bf16x8 a = *(const bf16x8*)(sQ + col * 64 + (ks << 5) + quad * 8);
#pragma unroll
        for (int idx = 0; idx < 9; idx++) {
            int nt = w + (idx << 2);
            if (nt < 33) {
                bf16x8 b = *(const bf16x8*)(sB + ((nt * 16 + col) << 5) + quad * 8);
                bdacc[idx] = __builtin_amdgcn_mfma_f32_16x16x32_bf16(a, b, bdacc[idx], 0, 0, 0);
            }
        }
        __syncthreads();
    }
    // shifted write: rect col c -> j = c + ml - 15; row stride 524 (bank-clean for scalars)
#pragma unroll
    for (int idx = 0; idx < 9; idx++) {
        int nt = w + (idx << 2);
        if (nt < 33) {
            int c = nt * 16 + col;
#pragma unroll
            for (int r = 0; r < 4; r++) {
                int ml = quad * 4 + r;
                int j = c + ml - 15;
                if (j >= 0 && j < 512)
                    sRect[ml * 524 + j] = f2bf(bdacc[idx][r]);
            }
        }
    }
    __syncthreads();

    // ---- phase 2: ac = QU_tile(16x64) . K^T ----
    if (tid < 128)
        __builtin_amdgcn_global_load_lds(
            (const __attribute__((address_space(1))) void*)(QU + (((size_t)nh * 512 + m0 + (tid >> 3)) << 6) + ((tid & 7) << 3)),
            (__attribute__((address_space(3))) void*)(sQ + tid * 8), 16, 0, 0);
    f32x4 ac[8];
#pragma unroll
    for (int i = 0; i < 8; i++) ac[i] = (f32x4){0.f, 0.f, 0.f, 0.f};
    const u16* Kz = Kb + ((size_t)nh << 15);
    for (int ks = 0; ks < 2; ks++) {
#pragma unroll
        for (int s = 0; s < 8; s++) {
            int row = (s << 6) + (tid >> 2);
            __builtin_amdgcn_global_load_lds(
                (const __attribute__((address_space(1))) void*)(Kz + ((size_t)row << 6) + (ks << 5) + ((tid & 3) << 3)),
                (__attribute__((address_space(3))) void*)(sB + (s << 11) + tid * 8), 16, 0, 0);
        }
        __syncthreads();
        bf16x8 a = *(const bf16x8*)(sQ + col * 64 + (ks << 5) + quad * 8);
#pragma unroll
        for (int jt = 0; jt < 8; jt++) {
            bf16x8 b = *(const bf16x8*)(sB + (((w << 7) + jt * 16 + col) << 5) + quad * 8);
            ac[jt] = __builtin_amdgcn_mfma_f32_16x16x32_bf16(a, b, ac[jt], 0, 0, 0);
        }
        __syncthreads();
    }

    // ---- phase 3: shifted add (direct index j) + scale + softmax over j ----
    float rmax[4];
#pragma unroll
    for (int r = 0; r < 4; r++) rmax[r] = -1e30f;
#pragma unroll
    for (int jt = 0; jt < 8; jt++) {
        int j = (w << 7) + jt * 16 + col;
#pragma unroll
        for (int r = 0; r < 4; r++) {
            int ml = quad * 4 + r;
            float v = (ac[jt][r] + bf2f(sRect[ml * 524 + j])) * 0.125f;
            ac[jt][r] = v;
            rmax[r] = fmaxf(rmax[r], v);
        }
    }
#pragma unroll
    for (int o = 1; o <= 8; o <<= 1)
#pragma unroll
        for (int r = 0; r < 4; r++) rmax[r] = fmaxf(rmax[r], __shfl_xor(rmax[r], o));
    if (col == 0)
#pragma unroll
        for (int r = 0; r < 4; r++) sRed[(quad * 4 + r) * 4 + w] = rmax[r];
    __syncthreads();
    float gmax[4], psum[4];
#pragma unroll
    for (int r = 0; r < 4; r++) {
        int ml = quad * 4 + r;
        gmax[r] = fmaxf(fmaxf(sRed[ml * 4 + 0], sRed[ml * 4 + 1]),
                        fmaxf(sRed[ml * 4 + 2], sRed[ml * 4 + 3]));
        psum[r] = 0.f;
    }
    __syncthreads();
#pragma unroll
    for (int jt = 0; jt < 8; jt++)
#pragma unroll
        for (int r = 0; r < 4; r++) {
            float e = __expf(ac[jt][r] - gmax[r]);
            ac[jt][r] = e;
            psum[r] += e;
        }
#pragma unroll
    for (int o = 1; o <= 8; o <<= 1)
#pragma unroll
        for (int r = 0; r < 4; r++) psum[r] += __shfl_xor(psum[r], o);
    if (col == 0)
#pragma unroll
        for (int r = 0; r < 4; r++) sRed[(quad * 4 + r) * 4 + w] = psum[r];
    __syncthreads();
    float rinv[4];
#pragma unroll
    for (int r = 0; r < 4; r++) {
        int ml = quad * 4 + r;
        rinv[r] = 1.f / (sRed[ml * 4 + 0] + sRed[ml * 4 + 1] + sRed[ml * 4 + 2] + sRed[ml * 4 + 3]);
    }

    // ---- phase 4: probs -> sP (stride 520; all sRect reads are >=2 barriers past) ----
#pragma unroll
    for (int jt = 0; jt < 8; jt++) {
        int j = (w << 7) + jt * 16 + col;
#pragma unroll
        for (int r = 0; r < 4; r++)
            sP[(quad * 4 + r) * 520 + j] = f2bf(ac[jt][r] * rinv[r]);
    }

    // ---- phase 5: ctx_tile(16x64) = P(16x512) . V^T; V staged 64x256 per chunk ----
    const u16* Vz = VT + ((size_t)nh << 15);
    f32x4 cacc = (f32x4){0.f, 0.f, 0.f, 0.f};
    for (int kc = 0; kc < 2; kc++) {
#pragma unroll
        for (int s = 0; s < 8; s++) {
            int d = (s << 3) + (tid >> 5);
            int chunk = (tid & 31) ^ (d & 7);
            __builtin_amdgcn_global_load_lds(
                (const __attribute__((address_space(1))) void*)(Vz + ((size_t)d << 9) + (kc << 8) + (chunk << 3)),
                (__attribute__((address_space(3))) void*)(sV + (s << 11) + tid * 8), 16, 0, 0);
        }
        __syncthreads();
#pragma unroll
        for (int s2 = 0; s2 < 8; s2++) {
            bf16x8 a = *(const bf16x8*)(sP + col * 520 + (kc << 8) + (s2 << 5) + quad * 8);
            int row = (w << 4) + col;
            int ch = ((s2 << 2) + quad) ^ (col & 7);
            bf16x8 b = *(const bf16x8*)(sV + (row << 8) + (ch << 3));
            cacc = __builtin_amdgcn_mfma_f32_16x16x32_bf16(a, b, cacc, 0, 0, 0);
        }
        __syncthreads();
    }

    // ---- phase 6: ctx tile -> LDS -> coalesced 16B stores ----
#pragma unroll
    for (int r = 0; r < 4; r++)
        sCtx[(quad * 4 + r) * 64 + (w << 4) + col] = f2bf(cacc[r]);
    __syncthreads();
    if (tid < 128) {
        int row = tid >> 3, seg = tid & 7;
        u16* dst = ctx + (((size_t)((m0 + row) * 16 + nb)) << 9) + (h << 6) + seg * 8;
        *(uint4*)dst = *(const uint4*)(sCtx + row * 64 + seg * 8);
    }
}

// ---------- repack qkv: vectorized, VT via LDS transpose (coalesced writes) ----------
// grid (128 nh, 8 l-tiles), 256 threads; block handles 64 l rows of one head.
__global__ __launch_bounds__(256) void repack_k(const u16* __restrict__ qkv,
                                                const float* __restrict__ bu,
                                                const float* __restrict__ bv,
                                                u16* __restrict__ QU, u16* __restrict__ QV,
                                                u16* __restrict__ Kb, u16* __restrict__ VT) {
    __shared__ u16 sV[64 * 72];  // 9216 B, stride 72 (8-aligned, bank step 4)
    int nh = blockIdx.x, h = nh & 7, n = nh >> 3;
    int l0 = blockIdx.y << 6;
    int tid = threadIdx.x;
    int d8 = (tid & 7) << 3;
    float bub[8], bvb[8];
#pragma unroll
    for (int e = 0; e < 8; e++) {
        bub[e] = bu[h * 64 + d8 + e];
        bvb[e] = bv[h * 64 + d8 + e];
    }
#pragma unroll
    for (int rep = 0; rep < 2; rep++) {
        int ll = (tid >> 3) + rep * 32;
        int l = l0 + ll;
        size_t base = (size_t)(l * 16 + n) * 1536 + h * 64 + d8;
        u16x8 q = *(const u16x8*)(qkv + base);
        u16x8 k = *(const u16x8*)(qkv + base + 512);
        u16x8 v = *(const u16x8*)(qkv + base + 1024);
        u16x8 qu, qv;
#pragma unroll
        for (int e = 0; e < 8; e++) {
            float qf = bf2f(q[e]);
            qu[e] = f2bf(qf + bub[e]);
            qv[e] = f2bf(qf + bvb[e]);
        }
        size_t o = ((size_t)nh * 512 + l) * 64 + d8;
        *(u16x8*)(QU + o) = qu;
        *(u16x8*)(QV + o) = qv;
        *(u16x8*)(Kb + o) = k;
        *(u16x8*)(sV + ll * 72 + d8) = v;
    }
    __syncthreads();
    int d = tid >> 2, ls = (tid & 3) << 4;
    u16 tmp[16];
#pragma unroll
    for (int e = 0; e < 16; e++) tmp[e] = sV[(ls + e) * 72 + d];
    u16* dst = VT + ((size_t)nh * 64 + d) * 512 + l0 + ls;
    *(u16x8*)(dst) = *(const u16x8*)(tmp);
    *(u16x8*)(dst + 8) = *(const u16x8*)(tmp + 8);
}

// ---------- GLU: (M,1024) bf16 -> (M,512) bf16 ----------
__global__ void glu_k(const u16* __restrict__ pw1o, u16* __restrict__ g) {
    int e = blockIdx.x * 256 + threadIdx.x;  // M*512
    int t = e >> 9, c = e & 511;
    float a = bf2f(pw1o[(size_t)t * 1024 + c]);
    float ga = bf2f(pw1o[(size_t)t * 1024 + 512 + c]);
    g[e] = f2bf(a * sigm(ga));
}

// ---------- depthwise conv: sliding window, 16 outputs per thread ----------
__global__ __launch_bounds__(256) void dwconv_k(
    const u16* __restrict__ g, const float* __restrict__ w, const float* __restrict__ wb,
    const float* __restrict__ bng, const float* __restrict__ bnb, const float* __restrict__ bnm,
    const float* __restrict__ bnv, u16* __restrict__ out) {
    int idx = blockIdx.x * 256 + threadIdx.x;  // 262144 threads
    int c = idx & 511;
    int t = idx >> 9;
    int n = t & 15, l0 = (t >> 4) << 4;
    float win[46];
#pragma unroll
    for (int q = 0; q < 46; q++) {
        int ll = l0 - 15 + q;
        win[q] = (ll >= 0 && ll < 512) ? bf2f(g[((size_t)(ll * 16 + n) << 9) + c]) : 0.f;
    }
    float wgt[31];
#pragma unroll
    for (int k = 0; k < 31; k++) wgt[k] = w[c * 31 + k];
    float ivg = rsqrtf(bnv[c] + 1e-5f) * bng[c];
    float mc = bnm[c], bc = bnb[c], wbc = wb[c];
#pragma unroll
    for (int r = 0; r < 16; r++) {
        float acc = 0.f;
#pragma unroll
        for (int k = 0; k < 31; k++) acc += wgt[k] * win[r + k];
        acc += wbc;
        float y = (acc - mc) * ivg + bc;
        y = y * sigm(y);
        out[((size_t)((l0 + r) * 16 + n) << 9) + c] = f2bf(y);
    }
}

// ---------- launch ----------
extern "C" void kernel_launch(void* const* d_in, const int* in_sizes, int n_in,
                              void* d_out, int out_size, void* d_ws, size_t ws_size,
                              hipStream_t stream) {
    const float* src      = (const float*)d_in[0];
    const float* pos_emb  = (const float*)d_in[1];
    const float* ffm_w1   = (const float*)d_in[2];
    const float* ffm_b1   = (const float*)d_in[3];
    const float* ffm_w2   = (const float*)d_in[4];
    const float* ffm_b2   = (const float*)d_in[5];
    const float* ff_w1    = (const float*)d_in[6];
    const float* ff_b1    = (const float*)d_in[7];
    const float* ff_w2    = (const float*)d_in[8];
    const float* ff_b2    = (const float*)d_in[9];
    const float* in_w     = (const float*)d_in[10];
    const float* in_b     = (const float*)d_in[11];
    const float* out_w    = (const float*)d_in[12];
    const float* out_b    = (const float*)d_in[13];
    const float* pos_w    = (const float*)d_in[14];
    const float* bu       = (const float*)d_in[15];
    const float* bv       = (const float*)d_in[16];
    const float* pw1_w    = (const float*)d_in[17];
    const float* pw1_b    = (const float*)d_in[18];
    const float* dw_w     = (const float*)d_in[19];
    const float* dw_b     = (const float*)d_in[20];
    const float* bng      = (const float*)d_in[21];
    const float* bnb      = (const float*)d_in[22];
    const float* bnm      = (const float*)d_in[23];
    const float* bnv      = (const float*)d_in[24];
    const float* pw2_w    = (const float*)d_in[25];
    const float* pw2_b    = (const float*)d_in[26];
    const float* ln_ffm_g = (const float*)d_in[27];
    const float* ln_ffm_b = (const float*)d_in[28];
    const float* ln_mha_g = (const float*)d_in[29];
    const float* ln_mha_b = (const float*)d_in[30];
    const float* ln_cv_g  = (const float*)d_in[31];
    const float* ln_cv_b  = (const float*)d_in[32];
    const float* ln_ff_g  = (const float*)d_in[33];
    const float* ln_ff_b  = (const float*)d_in[34];
    const float* ln_fin_g = (const float*)d_in[35];
    const float* ln_fin_b = (const float*)d_in[36];
    (void)in_sizes; (void)n_in; (void)out_size; (void)ws_size;

    // ---- workspace layout in u16 units; total ~117 MiB ----
    const size_t MEG = 1048576;
    u16* U = (u16*)d_ws;
    float* xA = (float*)U;                // 8M u16; Pbf aliases during attention
    u16* Pbf = U;                         // 524288 u16 (8 x 1024 x 64)
    float* xB = (float*)(U + 8 * MEG);    // 8M
    u16* LNB = U + 16 * MEG;              // 4M
    u16* BIG = U + 20 * MEG;              // 16M: h1 / qkv / pw1-out
    u16* QU = U + 36 * MEG;               // 4M
    u16* QV = U + 40 * MEG;               // 4M
    u16* Kb = U + 44 * MEG;               // 4M
    u16* VT = U + 48 * MEG;               // 4M
    u16* WB = U + 52 * MEG;               // 6,815,232 weights bf16
    u16* w_ffm1 = WB;
    u16* w_ffm2 = WB + 1 * MEG;
    u16* w_ff1  = WB + 2 * MEG;
    u16* w_ff2  = WB + 3 * MEG;
    u16* w_in   = WB + 4 * MEG;
    u16* w_out  = WB + 4 * MEG + 786432;
    u16* w_pw1  = WB + 5 * MEG;
    u16* w_pw2  = WB + 5 * MEG + 524288;
    u16* w_pos  = WB + 6029312;           // 512x512
    u16* w_pe   = WB + 6291456;           // 1023x512
    u16* CTX = LNB;
    u16* GLU = QU;
    u16* CACT = QV;

    // ---- cast all weights + pos inputs to bf16 (one dispatch) ----
    castall_k<<<26622, 256, 0, stream>>>(ffm_w1, ffm_w2, ff_w1, ff_w2, in_w, out_w,
                                         pw1_w, pw2_w, pos_w, pos_emb, WB);

    // ---- FFN macaron: xB = src + 0.5*ffn(ln(src)) ----
    ln512_k<true><<<2048, 256, 0, stream>>>(src, ln_ffm_g, ln_ffm_b, LNB);
    mgemm_k<<<dim3(64, 16), 512, 0, stream>>>(LNB, w_ffm1, ffm_b1, nullptr, BIG,
                                              8192, 2048, 512, 0.f, 1, 1);
    mgemm_k<<<dim3(64, 4), 512, 0, stream>>>(BIG, w_ffm2, ffm_b2, src, xB,
                                             8192, 512, 2048, 0.5f, 0, 0);

    // ---- attention: xA = xB + attn(ln(xB)) ----
    ln512_k<true><<<2048, 256, 0, stream>>>(xB, ln_mha_g, ln_mha_b, LNB);
    posb_k<<<dim3(8, 4), 256, 0, stream>>>(w_pe, w_pos, Pbf);
    mgemm_k<<<dim3(64, 12), 512, 0, stream>>>(LNB, w_in, in_b, nullptr, BIG,
                                              8192, 1536, 512, 0.f, 0, 1);
    repack_k<<<dim3(128, 8), 256, 0, stream>>>(BIG, bu, bv, QU, QV, Kb, VT);
    fattn_k<<<dim3(128, 32), 256, 0, stream>>>(QU, QV, Kb, Pbf, VT, CTX);
    mgemm_k<<<dim3(64, 4), 512, 0, stream>>>(CTX, w_out, out_b, xB, xA,
                                             8192, 512, 512, 1.f, 0, 0);

    // ---- conv module: xB = xA + conv(ln(xA)) ----
    ln512_k<true><<<2048, 256, 0, stream>>>(xA, ln_cv_g, ln_cv_b, LNB);
    mgemm_k<<<dim3(64, 8), 512, 0, stream>>>(LNB, w_pw1, pw1_b, nullptr, BIG,
                                             8192, 1024, 512, 0.f, 0, 1);
    glu_k<<<16384, 256, 0, stream>>>(BIG, GLU);
    dwconv_k<<<1024, 256, 0, stream>>>(GLU, dw_w, dw_b, bng, bnb, bnm, bnv, CACT);
    mgemm_k<<<dim3(64, 4), 512, 0, stream>>>(CACT, w_pw2, pw2_b, xA, xB,
                                             8192, 512, 512, 1.f, 0, 0);

    // ---- FFN 2: xA = xB + 0.5*ffn(ln(xB)) ----
    ln512_k<true><<<2048, 256, 0, stream>>>(xB, ln_ff_g, ln_ff_b, LNB);
    mgemm_k<<<dim3(64, 16), 512, 0, stream>>>(LNB, w_ff1, ff_b1, nullptr, BIG,
                                              8192, 2048, 512, 0.f, 1, 1);
    mgemm_k<<<dim3(64, 4), 512, 0, stream>>>(BIG, w_ff2, ff_b2, xB, xA,
                                             8192, 512, 2048, 0.5f, 0, 0);

    // ---- final LN -> fp32 out ----
    ln512_k<false><<<2048, 256, 0, stream>>>(xA, ln_fin_g, ln_fin_b, (float*)d_out);
}